// Round 5
// baseline (535.122 us; speedup 1.0000x reference)
//
#include <hip/hip_runtime.h>
#include <hip/hip_bf16.h>

typedef __bf16  bf16x8 __attribute__((ext_vector_type(8)));
typedef __bf16  bf16x4 __attribute__((ext_vector_type(4)));
typedef float   f32x4  __attribute__((ext_vector_type(4)));
typedef __hip_bfloat16 bf;

__device__ __forceinline__ float clamp256(float v) {
    return fminf(fmaxf(v, -256.f), 256.f);
}
__device__ __forceinline__ float sane(float v) {
    return fminf(fmaxf(v, -1e4f), 1e4f);
}
// 16B-chunk XOR swizzle baked into weight layout: spreads B-tile rows over
// 8 LDS bank-groups (2-way = free) while keeping global_load_lds linear.
__device__ __forceinline__ int swzk(int k, int col) {
    return (k & ~31) | ((((k >> 3) & 3) ^ ((col >> 1) & 3)) << 3) | (k & 7);
}

// ---------------------------------------------------------------------------
// Tap-fused, register-prefetch 64x64 bf16 MFMA GEMM (GAT + FC head + fallback).
// mode 0: store (+bias,relu) -> outb bf16 or outf f32
// mode 2: register-resident LayerNorm(nn)+relu+residual (accR/Wd or res[])
// mode 3: split-K bf16 partials: outb[z*M*ostride + row*ostride + col]
// mode 5: dual output (HASWD): outb=accC+bias, res(cast bf*)=accR+biasd
//         relu!=0 => out2 rows padded per-graph: orow=(row/nn)*32+row%nn
// NOTE: expects UNSWIZZLED weights.
// ---------------------------------------------------------------------------
template<int TAPS, bool HASWD>
__global__ __launch_bounds__(256) void gemm_tf(
    const bf* __restrict__ A, const bf* __restrict__ Wt, const bf* __restrict__ Wd,
    const float* __restrict__ bias, const float* __restrict__ biasd,
    const float* __restrict__ lnw, const float* __restrict__ lnb,
    const bf* __restrict__ res, int res_stride,
    bf* __restrict__ outb, float* __restrict__ outf, int out_stride,
    int M, int N, int K, int dil, int mode, int relu, int padded, int nn, int kLen)
{
    constexpr int NT = TAPS + (HASWD ? 1 : 0);
    __shared__ __align__(16) unsigned short sA[66 * 40];      // 64 rows + zero row 64
    __shared__ __align__(16) unsigned short sB[NT][64 * 40];
    __shared__ float sS[4][64], sS2[4][64];

    const int tid  = threadIdx.x;
    const int wv   = tid >> 6;
    const int lane = tid & 63;
    const int m0   = blockIdx.y * 64;
    const int n0   = blockIdx.x * 64;
    const int frow = lane & 15;
    const int fq   = lane >> 4;
    const int kOff = blockIdx.z * kLen;
    const int kEnd = (kOff + kLen < K) ? (kOff + kLen) : K;

    if (tid < 40) sA[64 * 40 + tid] = (unsigned short)0;

    int aoff[NT];
    {
        int token = wv * 16 + frow;
        int b = token >> 5, l = token & 31;
        #pragma unroll
        for (int t = 0; t < NT; ++t) {
            int s = (t < TAPS) ? (t - TAPS / 2) * dil : 0;
            int ar;
            if (padded) {
                int ls = l + s;
                ar = ((unsigned)ls < 32u) ? (b * 32 + ls) : 64;
            } else {
                ar = token;
            }
            aoff[t] = ar * 40 + fq * 8;
        }
    }

    const int srow = tid >> 2;
    const int schk = (tid & 3) << 3;
    int raG = m0 + srow;
    if (!padded && raG >= M) raG = -1;
    const int rbG  = n0 + srow;
    const bool bval = rbG < N;
    const bf* Ap = (raG >= 0) ? (A + (size_t)raG * K) : nullptr;
    const bf* Bp[NT];
    #pragma unroll
    for (int t = 0; t < NT; ++t)
        Bp[t] = (HASWD && t == TAPS) ? (Wd + (size_t)rbG * K)
                                     : (Wt + ((size_t)t * N + rbG) * K);

    f32x4 accC[4], accR[4];
    #pragma unroll
    for (int i = 0; i < 4; ++i) { accC[i] = 0.f; accR[i] = 0.f; }

    const uint4 zu = make_uint4(0u, 0u, 0u, 0u);
    uint4 pa, pb[NT];
    pa = Ap ? *(const uint4*)(Ap + kOff + schk) : zu;
    #pragma unroll
    for (int t = 0; t < NT; ++t)
        pb[t] = bval ? *(const uint4*)(Bp[t] + kOff + schk) : zu;

    for (int kb = kOff; kb < kEnd; kb += 32) {
        __syncthreads();
        *(uint4*)(sA + srow * 40 + schk) = pa;
        #pragma unroll
        for (int t = 0; t < NT; ++t)
            *(uint4*)(&sB[t][srow * 40 + schk]) = pb[t];
        __syncthreads();
        int kn = kb + 32;
        if (kn < kEnd) {
            pa = Ap ? *(const uint4*)(Ap + kn + schk) : zu;
            #pragma unroll
            for (int t = 0; t < NT; ++t)
                pb[t] = bval ? *(const uint4*)(Bp[t] + kn + schk) : zu;
        }
        #pragma unroll
        for (int t = 0; t < TAPS; ++t) {
            bf16x8 af = *(const bf16x8*)(sA + aoff[t]);
            #pragma unroll
            for (int nt = 0; nt < 4; ++nt) {
                bf16x8 bg = *(const bf16x8*)(&sB[t][(nt * 16 + frow) * 40 + fq * 8]);
                accC[nt] = __builtin_amdgcn_mfma_f32_16x16x32_bf16(af, bg, accC[nt], 0, 0, 0);
            }
        }
        if constexpr (HASWD) {
            bf16x8 af = *(const bf16x8*)(sA + aoff[TAPS]);
            #pragma unroll
            for (int nt = 0; nt < 4; ++nt) {
                bf16x8 bg = *(const bf16x8*)(&sB[TAPS][(nt * 16 + frow) * 40 + fq * 8]);
                accR[nt] = __builtin_amdgcn_mfma_f32_16x16x32_bf16(af, bg, accR[nt], 0, 0, 0);
            }
        }
    }

    if (mode == 0) {
        #pragma unroll
        for (int nt = 0; nt < 4; ++nt) {
            int col = n0 + nt * 16 + frow;
            if (col >= N) continue;
            float bv = bias ? bias[col] : 0.f;
            #pragma unroll
            for (int r = 0; r < 4; ++r) {
                int row = m0 + wv * 16 + fq * 4 + r;
                if (row >= M) continue;
                float v = accC[nt][r] + bv;
                if (relu) v = fmaxf(v, 0.f);
                if (outb) outb[(size_t)row * out_stride + col] = __float2bfloat16(clamp256(v));
                else      outf[(size_t)row * out_stride + col] = sane(v);
            }
        }
    } else if (mode == 3) {
        bf* po = outb + (size_t)blockIdx.z * M * out_stride;
        #pragma unroll
        for (int nt = 0; nt < 4; ++nt) {
            int col = n0 + nt * 16 + frow;
            if (col >= N) continue;
            #pragma unroll
            for (int r = 0; r < 4; ++r) {
                int row = m0 + wv * 16 + fq * 4 + r;
                if (row >= M) continue;
                po[(size_t)row * out_stride + col] = __float2bfloat16(accC[nt][r]);
            }
        }
    } else if (mode == 5) {
        if constexpr (HASWD) {
            bf* out2 = (bf*)res;
            #pragma unroll
            for (int nt = 0; nt < 4; ++nt) {
                int col = n0 + nt * 16 + frow;
                if (col >= N) continue;
                float bv = bias[col], bd = biasd[col];
                #pragma unroll
                for (int r = 0; r < 4; ++r) {
                    int row = m0 + wv * 16 + fq * 4 + r;
                    if (row >= M) continue;
                    int orow = row;
                    if (relu) orow = (row / nn) * 32 + (row % nn);   // padded per-graph
                    outb[(size_t)row * out_stride + col] = __float2bfloat16(clamp256(accC[nt][r] + bv));
                    out2[(size_t)orow * res_stride + col] = __float2bfloat16(clamp256(accR[nt][r] + bd));
                }
            }
        }
    } else {  // mode 2
        float bvc[4], bdc[4];
        #pragma unroll
        for (int nt = 0; nt < 4; ++nt) {
            int col = n0 + nt * 16 + frow;
            bvc[nt] = bias[col];
            bdc[nt] = (HASWD && biasd) ? biasd[col] : 0.f;
        }
        float s[4], s2[4];
        #pragma unroll
        for (int nt = 0; nt < 4; ++nt) { s[nt] = 0.f; s2[nt] = 0.f; }
        #pragma unroll
        for (int nt = 0; nt < 4; ++nt)
            #pragma unroll
            for (int r = 0; r < 4; ++r) {
                int row = wv * 16 + fq * 4 + r;
                int l = row & 31;
                float v = sane(accC[nt][r] + bvc[nt]);
                if (l < nn) { s[nt] += v; s2[nt] += v * v; }
            }
        #pragma unroll
        for (int nt = 0; nt < 4; ++nt) {
            s[nt]  += __shfl_xor(s[nt], 16);  s[nt]  += __shfl_xor(s[nt], 32);
            s2[nt] += __shfl_xor(s2[nt], 16); s2[nt] += __shfl_xor(s2[nt], 32);
        }
        if (fq == 0) {
            #pragma unroll
            for (int nt = 0; nt < 4; ++nt) {
                sS[wv][nt * 16 + frow]  = s[nt];
                sS2[wv][nt * 16 + frow] = s2[nt];
            }
        }
        __syncthreads();
        const int gi = wv >> 1;
        const float inv = 1.f / (float)nn;
        #pragma unroll
        for (int nt = 0; nt < 4; ++nt) {
            int c = nt * 16 + frow;
            int colg = n0 + c;
            float S  = sS[2 * gi][c]  + sS[2 * gi + 1][c];
            float S2 = sS2[2 * gi][c] + sS2[2 * gi + 1][c];
            float mu = S * inv;
            float var = S2 * inv - mu * mu;
            float rs = rsqrtf(fmaxf(var, 0.f) + 1e-5f);
            #pragma unroll
            for (int r = 0; r < 4; ++r) {
                int row = wv * 16 + fq * 4 + r;
                int l = row & 31;
                int grow = m0 + row;
                float outv = 0.f;
                if (l < nn) {
                    float v = (sane(accC[nt][r] + bvc[nt]) - mu) * rs * lnw[l] + lnb[l];
                    v = fmaxf(v, 0.f);
                    float rr;
                    if constexpr (HASWD) rr = sane(accR[nt][r] + bdc[nt]);
                    else rr = __bfloat162float(res[(size_t)grow * res_stride + colg]);
                    outv = clamp256(v + rr);
                }
                outb[(size_t)grow * out_stride + colg] = __float2bfloat16(outv);
            }
        }
    }
}

// ---------------------------------------------------------------------------
// TCN tap-fused GEMM v3 (round-4 winner, unchanged): 256x64 macro-tile,
// 64x64 per wave, B via dbuf global_load_lds DMA of pre-swizzled weights.
// ---------------------------------------------------------------------------
template<int TAPS, bool HASWD>
__global__ __launch_bounds__(256, 2) void gemm_tcn(
    const bf* __restrict__ A, const bf* __restrict__ Wt, const bf* __restrict__ Wd,
    const float* __restrict__ bias, const float* __restrict__ biasd,
    const float* __restrict__ lnw, const float* __restrict__ lnb,
    const bf* __restrict__ res, int res_stride,
    bf* __restrict__ outb, int out_stride,
    int M, int N, int K, int dil, int nn)
{
    constexpr int NT = TAPS + (HASWD ? 1 : 0);
    __shared__ __align__(16) unsigned short sA[257 * 40];
    __shared__ __align__(16) unsigned short sBall[2 * NT * 64 * 32];

    const int tid  = threadIdx.x;
    const int wv   = tid >> 6;
    const int lane = tid & 63;
    const int frow = lane & 15;
    const int fq   = lane >> 4;

    const int gx  = gridDim.x;
    const int nwg = gx * gridDim.y;
    int wg = blockIdx.y * gx + blockIdx.x;
    if ((nwg & 7) == 0) wg = (wg & 7) * (nwg >> 3) + (wg >> 3);
    const int n0 = (wg % gx) * 64;
    const int m0 = (wg / gx) * 256;

    if (tid < 40) sA[256 * 40 + tid] = (unsigned short)0;

    int aoff[TAPS][4];
    #pragma unroll
    for (int mr = 0; mr < 4; ++mr) {
        int token = wv * 64 + mr * 16 + frow;
        int b5 = token >> 5, l = token & 31;
        #pragma unroll
        for (int t = 0; t < TAPS; ++t) {
            int ls = l + (t - TAPS / 2) * dil;
            int ar = ((unsigned)ls < 32u) ? (b5 * 32 + ls) : 256;
            aoff[t][mr] = ar * 40 + fq * 8;
        }
    }
    const int bco = (fq ^ ((frow >> 1) & 3)) << 3;

    const int srow = tid >> 2;
    const int chS  = (tid & 3) << 3;
    const bf* Ap = A + (size_t)(m0 + srow) * K + chS;

    const bf* bsrc[4];
    {
        int lr = lane >> 2, lc = lane & 3;
        #pragma unroll
        for (int i = 0; i < 4; ++i) {
            int colb = n0 + i * 16 + lr;
            const bf* Wb;
            if (HASWD && wv == TAPS) Wb = Wd + (size_t)colb * K;
            else if (wv < TAPS)      Wb = Wt + ((size_t)wv * N + colb) * K;
            else                     Wb = Wt + (size_t)colb * K;
            bsrc[i] = Wb + lc * 8;
        }
    }

    f32x4 accC[4][4], accR[4][4];
    #pragma unroll
    for (int i = 0; i < 4; ++i)
        #pragma unroll
        for (int j = 0; j < 4; ++j) { accC[i][j] = 0.f; if (HASWD) accR[i][j] = 0.f; }

    #define ISSUE_B(BUFB, KBS)                                                      \
        if (wv < NT) {                                                              \
            unsigned short* bas = sBall + ((size_t)((BUFB) * NT + wv) * 64) * 32;   \
            _Pragma("unroll")                                                       \
            for (int i = 0; i < 4; ++i) {                                           \
                __builtin_amdgcn_global_load_lds(                                   \
                    (const __attribute__((address_space(1))) void*)(bsrc[i] + (KBS)), \
                    (__attribute__((address_space(3))) void*)(bas + i * 512),       \
                    16, 0, 0);                                                      \
            }                                                                       \
        }

    uint4 pa[4];
    #pragma unroll
    for (int i = 0; i < 4; ++i) pa[i] = *(const uint4*)(Ap + (size_t)i * 64 * K);
    ISSUE_B(0, 0);

    int buf = 0;
    for (int kb = 0; kb < K; kb += 32) {
        __syncthreads();
        #pragma unroll
        for (int i = 0; i < 4; ++i)
            *(uint4*)(sA + (srow + i * 64) * 40 + chS) = pa[i];
        __syncthreads();
        int kn = kb + 32;
        if (kn < K) {
            ISSUE_B(buf ^ 1, kn);
            #pragma unroll
            for (int i = 0; i < 4; ++i)
                pa[i] = *(const uint4*)(Ap + (size_t)i * 64 * K + kn);
        }
        const unsigned short* sBb = sBall + (size_t)buf * NT * 2048;
        bf16x8 aMid[4];
        #pragma unroll
        for (int mr = 0; mr < 4; ++mr)
            aMid[mr] = *(const bf16x8*)(sA + aoff[TAPS / 2][mr]);
        #pragma unroll
        for (int t = 0; t < TAPS; ++t) {
            bf16x8 af[4];
            #pragma unroll
            for (int mr = 0; mr < 4; ++mr)
                af[mr] = (t == TAPS / 2) ? aMid[mr]
                                         : *(const bf16x8*)(sA + aoff[t][mr]);
            #pragma unroll
            for (int nt = 0; nt < 4; ++nt) {
                bf16x8 bg = *(const bf16x8*)(sBb + (size_t)t * 2048 + (nt * 16 + frow) * 32 + bco);
                #pragma unroll
                for (int mr = 0; mr < 4; ++mr)
                    accC[mr][nt] = __builtin_amdgcn_mfma_f32_16x16x32_bf16(af[mr], bg, accC[mr][nt], 0, 0, 0);
            }
        }
        if constexpr (HASWD) {
            #pragma unroll
            for (int nt = 0; nt < 4; ++nt) {
                bf16x8 bg = *(const bf16x8*)(sBb + (size_t)TAPS * 2048 + (nt * 16 + frow) * 32 + bco);
                #pragma unroll
                for (int mr = 0; mr < 4; ++mr)
                    accR[mr][nt] = __builtin_amdgcn_mfma_f32_16x16x32_bf16(aMid[mr], bg, accR[mr][nt], 0, 0, 0);
            }
        }
        buf ^= 1;
    }
    #undef ISSUE_B

    float bvc[4], bdc[4];
    #pragma unroll
    for (int nt = 0; nt < 4; ++nt) {
        int col = n0 + nt * 16 + frow;
        bvc[nt] = bias[col];
        bdc[nt] = HASWD ? biasd[col] : 0.f;
    }
    float S[2][4], Q[2][4];
    #pragma unroll
    for (int h = 0; h < 2; ++h)
        #pragma unroll
        for (int nt = 0; nt < 4; ++nt) { S[h][nt] = 0.f; Q[h][nt] = 0.f; }
    #pragma unroll
    for (int mr = 0; mr < 4; ++mr) {
        const int h = mr >> 1;
        #pragma unroll
        for (int nt = 0; nt < 4; ++nt)
            #pragma unroll
            for (int r = 0; r < 4; ++r) {
                int l = (mr & 1) * 16 + fq * 4 + r;
                if (l < nn) {
                    float v = sane(accC[mr][nt][r] + bvc[nt]);
                    S[h][nt] += v; Q[h][nt] += v * v;
                }
            }
    }
    const float inv = 1.f / (float)nn;
    float mu[2][4], rsg[2][4];
    #pragma unroll
    for (int h = 0; h < 2; ++h)
        #pragma unroll
        for (int nt = 0; nt < 4; ++nt) {
            float s = S[h][nt], q = Q[h][nt];
            s += __shfl_xor(s, 16); s += __shfl_xor(s, 32);
            q += __shfl_xor(q, 16); q += __shfl_xor(q, 32);
            float m = s * inv;
            float var = q * inv - m * m;
            mu[h][nt]  = m;
            rsg[h][nt] = rsqrtf(fmaxf(var, 0.f) + 1e-5f);
        }
    float lw[2][4], lb2[2][4];
    #pragma unroll
    for (int p = 0; p < 2; ++p)
        #pragma unroll
        for (int r = 0; r < 4; ++r) {
            int l = p * 16 + fq * 4 + r;
            bool ok = l < nn;
            lw[p][r]  = ok ? lnw[l] : 0.f;
            lb2[p][r] = ok ? lnb[l] : 0.f;
        }
    #pragma unroll
    for (int nt = 0; nt < 4; ++nt) {
        const int colg = n0 + nt * 16 + frow;
        #pragma unroll
        for (int mr = 0; mr < 4; ++mr) {
            const int h = mr >> 1, p = mr & 1;
            #pragma unroll
            for (int r = 0; r < 4; ++r) {
                int l = p * 16 + fq * 4 + r;
                int grow = m0 + wv * 64 + mr * 16 + fq * 4 + r;
                float outv = 0.f;
                if (l < nn) {
                    float v = (sane(accC[mr][nt][r] + bvc[nt]) - mu[h][nt]) * rsg[h][nt] * lw[p][r] + lb2[p][r];
                    v = fmaxf(v, 0.f);
                    float rr;
                    if constexpr (HASWD) rr = sane(accR[mr][nt][r] + bdc[nt]);
                    else rr = __bfloat162float(res[(size_t)grow * res_stride + colg]);
                    outv = clamp256(v + rr);
                }
                outb[(size_t)grow * out_stride + colg] = __float2bfloat16(outv);
            }
        }
    }
}

// ---------------------------------------------------------------------------
// Fused per-graph GAT v4. CONV=1 additionally fuses TCN block 0:
//   h kept in LDS (sH[33][264], row 32 = zeros); per-wave 64-col MFMA conv
//   (3 taps, K=256) with B-frags read COALESCED from L2 (frag-layout Wf);
//   in-register LayerNorm(nn) + relu + residual; writes y0 (padded 32 rows).
// CONV=1 requires HC==256 and xrb in 32-row padded layout.
// ---------------------------------------------------------------------------
#define MAXNE 270
#define XLS   260   // padded XL row stride (channels)
#define SHP   264   // padded H row stride (channels)
template<int CONV>
__global__ __launch_bounds__(256, 3) void gat_fused4(
    const int* __restrict__ ei, const bf* __restrict__ xlb, const bf* __restrict__ xrb,
    const float* __restrict__ att, const float* __restrict__ gbias,
    const bf* __restrict__ Wf, const float* __restrict__ cbias,
    const float* __restrict__ lnw, const float* __restrict__ lnb,
    bf* __restrict__ yout, float* __restrict__ dalpha, float* __restrict__ dei,
    int E0, int ET, int EPG, int nn)
{
    __shared__ __align__(16) __bf16 sXL[32 * XLS];   // 16.25 KB (padded rows)
    __shared__ __align__(16) __bf16 sHX[33 * SHP];   // 17.0 KB: XR (stride 256) then H (stride 264)
    __shared__ float sExp[MAXNE * 4];
    __shared__ int   sSrc[MAXNE], sDst[MAXNE];
    __shared__ int   sList[MAXNE];
    __shared__ int   sCnt[32];
    __shared__ int   sOff[33];

    const int g = blockIdx.x, tid = threadIdx.x, wv = tid >> 6, lane = tid & 63;
    if (EPG + nn > MAXNE) return;
    const int NE = EPG + nn;

    // Phase 0a: edges + self loops; stage xl/xr; zero H row 32 (beyond XR area)
    for (int k = tid; k < EPG; k += 256) {
        int s = ei[(size_t)g * EPG + k] - g * nn;
        int d = ei[(size_t)E0 + (size_t)g * EPG + k] - g * nn;
        sSrc[k] = min(max(s, 0), nn - 1);
        sDst[k] = min(max(d, 0), nn - 1);
    }
    for (int k = EPG + tid; k < NE; k += 256) { sSrc[k] = k - EPG; sDst[k] = k - EPG; }
    {
        const uint4* gxl = (const uint4*)(xlb + (size_t)g * nn * 256);
        const uint4* gxr = (const uint4*)(xrb + (size_t)g * (CONV ? 32 : nn) * 256);
        for (int k = tid; k < nn * 32; k += 256) {
            int node = k >> 5, c8 = k & 31;
            *(uint4*)(sXL + node * XLS + c8 * 8) = gxl[k];
            *(uint4*)(sHX + k * 8) = gxr[k];                 // XR layout, stride 256
        }
    }
    if (CONV) { for (int k = tid; k < SHP; k += 256) sHX[32 * SHP + k] = (__bf16)0.f; }
    if (tid < 32) sCnt[tid] = 0;
    __syncthreads();

    // Phase 0b: histogram -> parallel exclusive scan -> scatter
    for (int k = tid; k < NE; k += 256) atomicAdd(&sCnt[sDst[k]], 1);
    __syncthreads();
    if (tid < 32) {
        int acc = 0, last = 0;
        #pragma unroll
        for (int j = 0; j < 32; ++j) {
            int c = sCnt[j];
            if (j < tid) acc += c;
            if (j == 31) last = c;
        }
        sOff[tid] = acc;
        if (tid == 31) sOff[32] = acc + last;
        sCnt[tid] = 0;
    }
    __syncthreads();
    for (int k = tid; k < NE; k += 256) {
        int d = sDst[k];
        int p = atomicAdd(&sCnt[d], 1);
        sList[sOff[d] + p] = k;
    }

    // ei echo
    for (int k = tid; k < NE; k += 256) {
        int s, d; size_t eg;
        if (k < EPG) { s = g * nn + sSrc[k]; d = g * nn + sDst[k]; eg = (size_t)g * EPG + k; }
        else { int node = g * nn + (k - EPG); s = d = node; eg = (size_t)E0 + (size_t)g * nn + (k - EPG); }
        dei[eg] = (float)s;
        dei[(size_t)ET + eg] = (float)d;
    }
    __syncthreads();

    // Phase 1: wave-per-edge scores (reads XR from sHX, stride 256)
    const float4 attv = *(const float4*)(att + lane * 4);
    const int h4 = lane >> 4;
    for (int i = wv; i < NE; i += 4) {
        int srcl = sSrc[i], dstl = sDst[i];
        bf16x4 a = *(const bf16x4*)(sXL + srcl * XLS + lane * 4);
        bf16x4 b = *(const bf16x4*)(sHX + dstl * 256 + lane * 4);
        float p = 0.f;
        {
            float v0 = (float)a[0] + (float)b[0]; v0 = v0 > 0.f ? v0 : 0.2f * v0; p += v0 * attv.x;
            float v1 = (float)a[1] + (float)b[1]; v1 = v1 > 0.f ? v1 : 0.2f * v1; p += v1 * attv.y;
            float v2 = (float)a[2] + (float)b[2]; v2 = v2 > 0.f ? v2 : 0.2f * v2; p += v2 * attv.z;
            float v3 = (float)a[3] + (float)b[3]; v3 = v3 > 0.f ? v3 : 0.2f * v3; p += v3 * attv.w;
        }
        p += __shfl_xor(p, 1); p += __shfl_xor(p, 2);
        p += __shfl_xor(p, 4); p += __shfl_xor(p, 8);
        if ((lane & 15) == 0)
            sExp[i * 4 + h4] = __expf(fminf(fmaxf(p, -60.f), 60.f));
    }
    __syncthreads();

    // Phase 2: 8-lane group per dst node; lane owns 32 channels.
    // CONV: h written to sH (stride SHP, overwrites dead XR); else to global.
    {
        const int grp  = wv * 8 + (lane >> 3);
        const int s8   = lane & 7;
        const int chb  = s8 * 32;
        const int head = s8 >> 1;
        bf* hrow = yout + ((size_t)g * 32 + grp) * 256 + chb;   // !CONV only

        if (grp < nn) {
            const int beg = sOff[grp], end = sOff[grp + 1];
            float den = 0.f;
            f32x4 acc[8];
            #pragma unroll
            for (int k2 = 0; k2 < 8; ++k2) acc[k2] = 0.f;

            for (int q = beg; q < end; ++q) {
                int e = sList[q];
                float ev = sExp[e * 4 + head];
                den += ev;
                const __bf16* xp = sXL + sSrc[e] * XLS + chb;
                #pragma unroll
                for (int k2 = 0; k2 < 4; ++k2) {
                    bf16x8 xa = *(const bf16x8*)(xp + k2 * 8);
                    #pragma unroll
                    for (int j = 0; j < 4; ++j)
                        acc[k2 * 2][j]     += ev * (float)xa[j];
                    #pragma unroll
                    for (int j = 0; j < 4; ++j)
                        acc[k2 * 2 + 1][j] += ev * (float)xa[4 + j];
                }
            }
            const float rden = 1.f / fmaxf(den, 1e-30f);

            if (!(s8 & 1)) {
                for (int q = beg; q < end; ++q) {
                    int e = sList[q];
                    float al = fminf(fmaxf(sExp[e * 4 + head] * rden, 0.f), 1.f);
                    size_t eg = (e < EPG) ? ((size_t)g * EPG + e)
                                          : ((size_t)E0 + (size_t)g * nn + (e - EPG));
                    dalpha[eg * 4 + head] = al;
                }
            }

            #pragma unroll
            for (int k2 = 0; k2 < 8; ++k2) {
                float4 gbv = *(const float4*)(gbias + chb + k2 * 4);
                bf16x4 o;
                o[0] = (__bf16)clamp256(fmaxf(acc[k2][0] * rden + gbv.x, 0.f));
                o[1] = (__bf16)clamp256(fmaxf(acc[k2][1] * rden + gbv.y, 0.f));
                o[2] = (__bf16)clamp256(fmaxf(acc[k2][2] * rden + gbv.z, 0.f));
                o[3] = (__bf16)clamp256(fmaxf(acc[k2][3] * rden + gbv.w, 0.f));
                if constexpr (CONV) *(bf16x4*)(sHX + grp * SHP + chb + k2 * 4) = o;
                else                *(bf16x4*)(hrow + k2 * 4) = o;
            }
        } else {
            bf16x4 z; z[0] = (__bf16)0.f; z[1] = (__bf16)0.f; z[2] = (__bf16)0.f; z[3] = (__bf16)0.f;
            #pragma unroll
            for (int k2 = 0; k2 < 8; ++k2) {
                if constexpr (CONV) *(bf16x4*)(sHX + grp * SHP + chb + k2 * 4) = z;
                else                *(bf16x4*)(hrow + k2 * 4) = z;
            }
        }
    }

    // Phase 3 (CONV): y0 = relu(LN(conv3(h))) + h, per-wave 64 cols via MFMA
    if constexpr (CONV) {
        __syncthreads();
        const int frow = lane & 15;
        const int fq   = lane >> 4;
        const int colw = wv * 64;
        f32x4 c0[2][4];
        #pragma unroll
        for (int i = 0; i < 2; ++i)
            #pragma unroll
            for (int j = 0; j < 4; ++j) c0[i][j] = 0.f;

        #pragma unroll
        for (int kc = 0; kc < 8; ++kc) {
            bf16x8 af[3][2];
            #pragma unroll
            for (int t = 0; t < 3; ++t)
                #pragma unroll
                for (int mr = 0; mr < 2; ++mr) {
                    int l = mr * 16 + frow + t - 1;
                    int ar = ((unsigned)l < 32u) ? l : 32;
                    af[t][mr] = *(const bf16x8*)(sHX + ar * SHP + kc * 32 + fq * 8);
                }
            #pragma unroll
            for (int t = 0; t < 3; ++t)
                #pragma unroll
                for (int nt = 0; nt < 4; ++nt) {
                    // frag layout: ((((t*16 + cg)*8 + kc)*16 + frow)*4 + fq)*8
                    const __bf16* bp = (const __bf16*)Wf +
                        ((((size_t)(t * 16 + (colw >> 4) + nt) * 8 + kc) * 16 + frow) * 4 + fq) * 8;
                    bf16x8 bg = *(const bf16x8*)bp;
                    c0[0][nt] = __builtin_amdgcn_mfma_f32_16x16x32_bf16(af[t][0], bg, c0[0][nt], 0, 0, 0);
                    c0[1][nt] = __builtin_amdgcn_mfma_f32_16x16x32_bf16(af[t][1], bg, c0[1][nt], 0, 0, 0);
                }
        }

        float bv[4];
        #pragma unroll
        for (int nt = 0; nt < 4; ++nt) bv[nt] = cbias[colw + nt * 16 + frow];
        float S[4], Q[4];
        #pragma unroll
        for (int nt = 0; nt < 4; ++nt) { S[nt] = 0.f; Q[nt] = 0.f; }
        #pragma unroll
        for (int mr = 0; mr < 2; ++mr)
            #pragma unroll
            for (int nt = 0; nt < 4; ++nt)
                #pragma unroll
                for (int r = 0; r < 4; ++r) {
                    int l = mr * 16 + fq * 4 + r;
                    if (l < nn) {
                        float v = sane(c0[mr][nt][r] + bv[nt]);
                        S[nt] += v; Q[nt] += v * v;
                    }
                }
        const float inv = 1.f / (float)nn;
        float mu[4], rsg[4];
        #pragma unroll
        for (int nt = 0; nt < 4; ++nt) {
            float s = S[nt], q = Q[nt];
            s += __shfl_xor(s, 16); s += __shfl_xor(s, 32);
            q += __shfl_xor(q, 16); q += __shfl_xor(q, 32);
            float m = s * inv;
            float var = q * inv - m * m;
            mu[nt]  = m;
            rsg[nt] = rsqrtf(fmaxf(var, 0.f) + 1e-5f);
        }
        float lw[2][4], lb2[2][4];
        #pragma unroll
        for (int p = 0; p < 2; ++p)
            #pragma unroll
            for (int r = 0; r < 4; ++r) {
                int l = p * 16 + fq * 4 + r;
                bool ok = l < nn;
                lw[p][r]  = ok ? lnw[l] : 0.f;
                lb2[p][r] = ok ? lnb[l] : 0.f;
            }
        #pragma unroll
        for (int nt = 0; nt < 4; ++nt) {
            const int colf = colw + nt * 16 + frow;
            #pragma unroll
            for (int mr = 0; mr < 2; ++mr)
                #pragma unroll
                for (int r = 0; r < 4; ++r) {
                    int l = mr * 16 + fq * 4 + r;
                    float outv = 0.f;
                    if (l < nn) {
                        float v = (sane(c0[mr][nt][r] + bv[nt]) - mu[nt]) * rsg[nt] * lw[mr][r] + lb2[mr][r];
                        v = fmaxf(v, 0.f);
                        float rr = (float)sHX[l * SHP + colf];
                        outv = clamp256(v + rr);
                    }
                    yout[((size_t)g * 32 + l) * 256 + colf] = __float2bfloat16(outv);
                }
        }
    }
}

// ---- fused weight prep ----
struct CvtSegs { const float* in[7]; bf* out[7]; int n[7]; };
__global__ void prep_cvt(CvtSegs s, int total)
{
    int idx = blockIdx.x * 256 + threadIdx.x;
    if (idx >= total) return;
    #pragma unroll
    for (int i = 0; i < 7; ++i) {
        if (idx < s.n[i]) { s.out[i][idx] = __float2bfloat16(s.in[i][idx]); return; }
        idx -= s.n[i];
    }
}
// taps, optionally swizzled for gemm_tcn's global_load_lds path
struct TapSegs { const float* w[3]; bf* o[3]; int cc[3]; int kk[3]; int swz[3]; };
__global__ void prep_taps3(TapSegs s, int total)
{
    int idx = blockIdx.x * 256 + threadIdx.x;
    if (idx >= total) return;
    #pragma unroll
    for (int i = 0; i < 3; ++i) {
        if (idx < s.cc[i]) {
            int K = s.kk[i];
            int co = idx / K, ci = idx % K;
            int dst = co * K + (s.swz[i] ? swzk(ci, co) : ci);
            #pragma unroll
            for (int k = 0; k < 3; ++k)
                s.o[i][(size_t)k * s.cc[i] + dst] = __float2bfloat16(s.w[i][(size_t)idx * 3 + k]);
            return;
        }
        idx -= s.cc[i];
    }
}
// downsample weights, optionally swizzled
__global__ void prep_wswz(const float* __restrict__ w, bf* __restrict__ o,
                          int total, int K, int swz)
{
    int idx = blockIdx.x * 256 + threadIdx.x;
    if (idx >= total) return;
    int co = idx / K, ci = idx % K;
    o[(size_t)co * K + (swz ? swzk(ci, co) : ci)] = __float2bfloat16(w[idx]);
}
// conv0 weights -> MFMA-fragment-contiguous layout (coalesced 1KB wave loads)
__global__ void prep_bfrag(const float* __restrict__ w, bf* __restrict__ o, int HC)
{
    int idx = blockIdx.x * 256 + threadIdx.x;
    if (idx >= HC * HC) return;
    int co = idx / HC, ci = idx % HC;
    int cg = co >> 4, fr = co & 15, kc = ci >> 5, fq = (ci >> 3) & 3, w8 = ci & 7;
    int NCg = HC >> 4, NKc = HC >> 5;
    #pragma unroll
    for (int t = 0; t < 3; ++t) {
        size_t dst = (((((size_t)t * NCg + cg) * NKc + kc) * 16 + fr) * 4 + fq) * 8 + w8;
        o[dst] = __float2bfloat16(w[(size_t)idx * 3 + t]);
    }
}

// fc1_w f32 [F1][ci*nn+l] -> bf16 W1t [F1][l*HC+ci], l padded to 32
__global__ void prep_fc1(const float* __restrict__ w, bf* __restrict__ o, int F1, int nn, int HC)
{
    int idx = blockIdx.x * 256 + threadIdx.x;
    int kw = 32 * HC;
    if (idx >= F1 * kw) return;
    int co = idx / kw, r = idx % kw, l = r / HC, ci = r % HC;
    float hv = 0.f;
    if (l < nn) hv = w[(size_t)co * (HC * nn) + ci * nn + l];
    o[idx] = __float2bfloat16(hv);
}

// fc1 split-K reduce: z1 = bf16(relu(sum_z partials + bias))
__global__ void fc1red(const bf* __restrict__ zp, const float* __restrict__ bias,
                       bf* __restrict__ o, int MN, int N, int S)
{
    int idx = blockIdx.x * 256 + threadIdx.x;
    if (idx >= MN) return;
    float s = 0.f;
    for (int z = 0; z < S; ++z) s += __bfloat162float(zp[(size_t)z * MN + idx]);
    o[idx] = __float2bfloat16(clamp256(fmaxf(s + bias[idx % N], 0.f)));
}

extern "C" void kernel_launch(void* const* d_in, const int* in_sizes, int n_in,
                              void* d_out, int out_size, void* d_ws, size_t ws_size,
                              hipStream_t stream)
{
    (void)n_in; (void)ws_size;
    const float* x   = (const float*)d_in[0];
    const float* Wl  = (const float*)d_in[1];  const float* bl  = (const float*)d_in[2];
    const float* Wr  = (const float*)d_in[3];  const float* br  = (const float*)d_in[4];
    const float* att = (const float*)d_in[5];  const float* gb  = (const float*)d_in[6];
    const float* t0w = (const float*)d_in[7];  const float* t0b = (const float*)d_in[8];
    const float* l0w = (const float*)d_in[9];  const float* l0b = (const float*)d_in[10];
    const float* t1w = (const float*)d_in[11]; const float* t1b = (const float*)d_in[12];
    const float* l1w = (const float*)d_in[13]; const float* l1b = (const float*)d_in[14];
    const float* d1w = (const float*)d_in[15]; const float* d1b = (const float*)d_in[16];
    const float* t2w = (const float*)d_in[17]; const float* t2b = (const float*)d_in[18];
    const float* l2w = (const float*)d_in[19]; const float* l2b = (const float*)d_in[20];
    const float* d2w = (const float*)d_in[21]; const float* d2b = (const float*)d_in[22];
    const float* f1w = (const float*)d_in[23]; const float* f1b = (const float*)d_in[24];
    const float* f2w = (const float*)d_in[25]; const float* f2b = (const float*)d_in[26];
    const float* f3w = (const float*)d_in[27]; const float* f3b = (const float*)d_in[28];
    const int*   ei  = (const int*)d_in[29];

    const int HC   = in_sizes[6];                        // 256
    const int F_IN = in_sizes[1] / (HC > 0 ? HC : 1);    // 64
    const int NN   = in_sizes[0] / (F_IN > 0 ? F_IN : 1);// 30720
    const int E0   = in_sizes[29] / 2;                   // 245760
    const int ET   = E0 + NN;                            // 276480
    int nn = in_sizes[9];  nn = nn < 1 ? 1 : (nn > 32 ? 32 : nn);  // 30
    const int NG   = NN / nn;                            // 1024
    const int EPG  = NG > 0 ? E0 / NG : 0;               // 240
    const int C1   = in_sizes[12];                       // 512
    const int C2   = in_sizes[18];                       // 256
    const int F1   = in_sizes[24];                       // 512
    const int F2   = in_sizes[26];                       // 256
    const int F3   = in_sizes[28];                       // 144
    const int NG2  = (NG + 1) / 2;

    float* dout   = (float*)d_out;
    float* dei    = dout + ((size_t)out_size - 2 * (size_t)ET);
    float* dalpha = dei - (size_t)ET * 4;

    // ---- path eligibility ----
    const bool fused0 = (HC == 256) && (nn >= 1) && (nn <= 32) && (EPG + nn <= MAXNE)
                        && ((NN % 64) == 0);
    const int  gcA = NG2, gcB = NG - NG2;
    const bool fastc = ((gcA * 32) % 256 == 0) && ((gcB * 32) % 256 == 0)
                       && (C1 % 64 == 0) && (C2 % 64 == 0)
                       && (HC % 32 == 0) && (C1 % 32 == 0);

    // ---- workspace map (42 MB):
    //  [0,4M)      xb (dead after GAT gemm) -> z1, z2
    //  [4M,7.5M)   weights (incl. WkAf frag layout)
    //  S0 [7.5,25M): fused: xrb(pad32) -> y0 -> y2 ; fallback: xrb/hbuf
    //  S1 [25,42M):  xlb -> (fused: y1c -> W1t+z1p) (fallback: y0 -> y2)
    //  fallback: y1c/W1t/z1p live at S0 after hbuf dies.
    char* ws = (char*)d_ws;
    const size_t MB = 1ull << 20;
    bf*    xb   = (bf*)(ws);
    bf*    WkA  = (bf*)(ws + 4 * MB);
    bf*    WkB  = WkA + (size_t)3 * HC * HC;
    bf*    WkC  = WkB + (size_t)3 * C1 * HC;
    bf*    Wlb  = WkC + (size_t)3 * C2 * C1;
    bf*    Wrb  = Wlb + (size_t)HC * F_IN;
    bf*    f2wb = Wrb + (size_t)HC * F_IN;
    bf*    f3wb = f2wb + (size_t)F2 * F1;
    bf*    d1wb = f3wb + (size_t)F3 * F2;
    bf*    d2wb = d1wb + (size_t)C1 * HC;
    bf*    WkAf = d2wb + (size_t)C2 * C1;                // frag-layout conv0 weights
    char*  S0   = ws + (size_t)(7.5 * MB);
    char*  S1   = ws + 25 * MB;

    bf*    xrb  = (bf*)S0;                               // padded 32 rows when fused0
    bf*    hbuf = (bf*)S0;                               // fallback GAT output
    bf*    xlb  = (bf*)S1;
    bf*    y0   = fused0 ? (bf*)S0 : (bf*)S1;
    bf*    y1c  = fused0 ? (bf*)S1 : (bf*)S0;
    char*  fcS  = fused0 ? S1 : S0;                      // FC staging region
    bf*    W1t  = (bf*)fcS;                              // 8.4 MB
    bf*    z1p  = (bf*)(fcS + (size_t)(8.5 * MB));       // 8 MB
    bf*    z1   = (bf*)(ws);                             // 1 MB (over dead xb)
    bf*    z2   = (bf*)(ws + 2 * MB);                    // 0.5 MB

    // ---- fused weight prep ----
    {
        CvtSegs cs;
        cs.in[0] = x;   cs.out[0] = xb;   cs.n[0] = NN * F_IN;
        cs.in[1] = Wl;  cs.out[1] = Wlb;  cs.n[1] = HC * F_IN;
        cs.in[2] = Wr;  cs.out[2] = Wrb;  cs.n[2] = HC * F_IN;
        cs.in[3] = f2w; cs.out[3] = f2wb; cs.n[3] = F2 * F1;
        cs.in[4] = f3w; cs.out[4] = f3wb; cs.n[4] = F3 * F2;
        cs.in[5] = nullptr; cs.out[5] = nullptr; cs.n[5] = 0;
        cs.in[6] = nullptr; cs.out[6] = nullptr; cs.n[6] = 0;
        int tot = 0; for (int i = 0; i < 5; ++i) tot += cs.n[i];
        prep_cvt<<<(tot + 255) / 256, 256, 0, stream>>>(cs, tot);
        TapSegs ts;
        ts.w[0] = t0w; ts.o[0] = WkA; ts.cc[0] = HC * HC; ts.kk[0] = HC; ts.swz[0] = 0;
        ts.w[1] = t1w; ts.o[1] = WkB; ts.cc[1] = C1 * HC; ts.kk[1] = HC; ts.swz[1] = fastc ? 1 : 0;
        ts.w[2] = t2w; ts.o[2] = WkC; ts.cc[2] = C2 * C1; ts.kk[2] = C1; ts.swz[2] = fastc ? 1 : 0;
        int tt = ts.cc[0] + ts.cc[1] + ts.cc[2];
        prep_taps3<<<(tt + 255) / 256, 256, 0, stream>>>(ts, tt);
        prep_wswz<<<(C1 * HC + 255) / 256, 256, 0, stream>>>(d1w, d1wb, C1 * HC, HC, fastc ? 1 : 0);
        prep_wswz<<<(C2 * C1 + 255) / 256, 256, 0, stream>>>(d2w, d2wb, C2 * C1, C1, fastc ? 1 : 0);
        if (fused0)
            prep_bfrag<<<(HC * HC + 255) / 256, 256, 0, stream>>>(t0w, WkAf, HC);
    }

    // ---- GAT transforms: dual-output GEMM (mode 5; xr padded when fused0) ----
    gemm_tf<1, true><<<dim3((HC + 63) / 64, (NN + 63) / 64), 256, 0, stream>>>(
        xb, Wlb, Wrb, bl, br, nullptr, nullptr, (const bf*)xrb, HC,
        xlb, nullptr, HC, NN, HC, F_IN, 1, 5, fused0 ? 1 : 0, 0, nn, F_IN);

    // ---- fused GAT (+TCN block 0 when fused0) ----
    if (fused0)
        gat_fused4<1><<<NG, 256, 0, stream>>>(ei, xlb, xrb, att, gb,
                                              WkAf, t0b, l0w, l0b,
                                              y0, dalpha, dei, E0, ET, EPG, nn);
    else {
        gat_fused4<0><<<NG, 256, 0, stream>>>(ei, xlb, xrb, att, gb,
                                              nullptr, nullptr, nullptr, nullptr,
                                              hbuf, dalpha, dei, E0, ET, EPG, nn);
        // fallback TCN block 0
        gemm_tf<3, false><<<dim3((HC + 63) / 64, NG * 32 / 64), 256, 0, stream>>>(
            hbuf, WkA, nullptr, t0b, nullptr, l0w, l0b, hbuf, HC,
            y0, nullptr, HC, NG * 32, HC, HC, 1, 2, 0, 1, nn, HC);
    }

    // ---- TCN blocks 1 & 2, two graph-chunks ----
    for (int c = 0; c < 2; ++c) {
        int g0 = c * NG2;
        int gc = (c == 0) ? NG2 : (NG - NG2);
        if (gc <= 0) continue;
        const bf* y0c = y0 + (size_t)g0 * 32 * HC;
        bf*       y2c = y0 + (size_t)g0 * 32 * HC;
        if (fastc) {
            gemm_tcn<3, true><<<dim3(C1 / 64, gc * 32 / 256), 256, 0, stream>>>(
                y0c, WkB, d1wb, t1b, d1b, l1w, l1b, nullptr, 0,
                y1c, C1, gc * 32, C1, HC, 2, nn);
            gemm_tcn<3, true><<<dim3(C2 / 64, gc * 32 / 256), 256, 0, stream>>>(
                y1c, WkC, d2wb, t2b, d2b, l2w, l2b, nullptr, 0,
                y2c, C2, gc * 32, C2, C1, 4, nn);
        } else {
            gemm_tf<3, true><<<dim3((C1 + 63) / 64, gc * 32 / 64), 256, 0, stream>>>(
                y0c, WkB, d1wb, t1b, d1b, l1w, l1b, nullptr, 0,
                y1c, nullptr, C1, gc * 32, C1, HC, 2, 2, 0, 1, nn, HC);
            gemm_tf<3, true><<<dim3((C2 + 63) / 64, gc * 32 / 64), 256, 0, stream>>>(
                y1c, WkC, d2wb, t2b, d2b, l2w, l2b, nullptr, 0,
                y2c, nullptr, C2, gc * 32, C2, C1, 4, 2, 0, 1, nn, C1);
        }
    }

    // ---- FC head ----
    prep_fc1<<<(F1 * 32 * HC + 255) / 256, 256, 0, stream>>>(f1w, W1t, F1, nn, HC);
    gemm_tf<1, false><<<dim3((F1 + 63) / 64, (NG + 63) / 64, 8), 256, 0, stream>>>(
        y0, W1t, nullptr, nullptr, nullptr, nullptr, nullptr, nullptr, 0,
        z1p, nullptr, F1, NG, F1, 32 * HC, 1, 3, 0, 0, nn, 4 * HC);
    fc1red<<<(NG * F1 + 255) / 256, 256, 0, stream>>>(z1p, f1b, z1, NG * F1, F1, 8);

    gemm_tf<1, false><<<dim3((F2 + 63) / 64, (NG + 63) / 64), 256, 0, stream>>>(
        z1, f2wb, nullptr, f2b, nullptr, nullptr, nullptr, nullptr, 0,
        z2, nullptr, F2, NG, F2, F1, 1, 0, 1, 0, nn, F1);
    gemm_tf<1, false><<<dim3((F3 + 63) / 64, (NG + 63) / 64), 256, 0, stream>>>(
        z2, f3wb, nullptr, f3b, nullptr, nullptr, nullptr, nullptr, 0,
        nullptr, dout, F3, NG, F3, F2, 1, 0, 0, 0, nn, F2);
}

// Round 6
// 498.720 us; speedup vs baseline: 1.0730x; 1.0730x over previous
//
#include <hip/hip_runtime.h>
#include <hip/hip_bf16.h>

typedef __bf16  bf16x8 __attribute__((ext_vector_type(8)));
typedef __bf16  bf16x4 __attribute__((ext_vector_type(4)));
typedef float   f32x4  __attribute__((ext_vector_type(4)));
typedef __hip_bfloat16 bf;

__device__ __forceinline__ float clamp256(float v) {
    return fminf(fmaxf(v, -256.f), 256.f);
}
__device__ __forceinline__ float sane(float v) {
    return fminf(fmaxf(v, -1e4f), 1e4f);
}
// 16B-chunk XOR swizzle baked into weight layout: spreads B-tile rows over
// 8 LDS bank-groups (2-way = free) while keeping global_load_lds linear.
__device__ __forceinline__ int swzk(int k, int col) {
    return (k & ~31) | ((((k >> 3) & 3) ^ ((col >> 1) & 3)) << 3) | (k & 7);
}

// ---------------------------------------------------------------------------
// Tap-fused, register-prefetch 64x64 bf16 MFMA GEMM (GAT + FC head + fallback).
// mode 0: store (+bias,relu) -> outb bf16 or outf f32
// mode 2: register-resident LayerNorm(nn)+relu+residual (accR/Wd or res[])
// mode 3: split-K bf16 partials: outb[z*M*ostride + row*ostride + col]
// mode 5: dual output (HASWD): outb=accC+bias, res(cast bf*)=accR+biasd
//         relu!=0 => out2 rows padded per-graph: orow=(row/nn)*32+row%nn
// NOTE: expects UNSWIZZLED weights.
// ---------------------------------------------------------------------------
template<int TAPS, bool HASWD>
__global__ __launch_bounds__(256) void gemm_tf(
    const bf* __restrict__ A, const bf* __restrict__ Wt, const bf* __restrict__ Wd,
    const float* __restrict__ bias, const float* __restrict__ biasd,
    const float* __restrict__ lnw, const float* __restrict__ lnb,
    const bf* __restrict__ res, int res_stride,
    bf* __restrict__ outb, float* __restrict__ outf, int out_stride,
    int M, int N, int K, int dil, int mode, int relu, int padded, int nn, int kLen)
{
    constexpr int NT = TAPS + (HASWD ? 1 : 0);
    __shared__ __align__(16) unsigned short sA[66 * 40];      // 64 rows + zero row 64
    __shared__ __align__(16) unsigned short sB[NT][64 * 40];
    __shared__ float sS[4][64], sS2[4][64];

    const int tid  = threadIdx.x;
    const int wv   = tid >> 6;
    const int lane = tid & 63;
    const int m0   = blockIdx.y * 64;
    const int n0   = blockIdx.x * 64;
    const int frow = lane & 15;
    const int fq   = lane >> 4;
    const int kOff = blockIdx.z * kLen;
    const int kEnd = (kOff + kLen < K) ? (kOff + kLen) : K;

    if (tid < 40) sA[64 * 40 + tid] = (unsigned short)0;

    int aoff[NT];
    {
        int token = wv * 16 + frow;
        int b = token >> 5, l = token & 31;
        #pragma unroll
        for (int t = 0; t < NT; ++t) {
            int s = (t < TAPS) ? (t - TAPS / 2) * dil : 0;
            int ar;
            if (padded) {
                int ls = l + s;
                ar = ((unsigned)ls < 32u) ? (b * 32 + ls) : 64;
            } else {
                ar = token;
            }
            aoff[t] = ar * 40 + fq * 8;
        }
    }

    const int srow = tid >> 2;
    const int schk = (tid & 3) << 3;
    int raG = m0 + srow;
    if (!padded && raG >= M) raG = -1;
    const int rbG  = n0 + srow;
    const bool bval = rbG < N;
    const bf* Ap = (raG >= 0) ? (A + (size_t)raG * K) : nullptr;
    const bf* Bp[NT];
    #pragma unroll
    for (int t = 0; t < NT; ++t)
        Bp[t] = (HASWD && t == TAPS) ? (Wd + (size_t)rbG * K)
                                     : (Wt + ((size_t)t * N + rbG) * K);

    f32x4 accC[4], accR[4];
    #pragma unroll
    for (int i = 0; i < 4; ++i) { accC[i] = 0.f; accR[i] = 0.f; }

    const uint4 zu = make_uint4(0u, 0u, 0u, 0u);
    uint4 pa, pb[NT];
    pa = Ap ? *(const uint4*)(Ap + kOff + schk) : zu;
    #pragma unroll
    for (int t = 0; t < NT; ++t)
        pb[t] = bval ? *(const uint4*)(Bp[t] + kOff + schk) : zu;

    for (int kb = kOff; kb < kEnd; kb += 32) {
        __syncthreads();
        *(uint4*)(sA + srow * 40 + schk) = pa;
        #pragma unroll
        for (int t = 0; t < NT; ++t)
            *(uint4*)(&sB[t][srow * 40 + schk]) = pb[t];
        __syncthreads();
        int kn = kb + 32;
        if (kn < kEnd) {
            pa = Ap ? *(const uint4*)(Ap + kn + schk) : zu;
            #pragma unroll
            for (int t = 0; t < NT; ++t)
                pb[t] = bval ? *(const uint4*)(Bp[t] + kn + schk) : zu;
        }
        #pragma unroll
        for (int t = 0; t < TAPS; ++t) {
            bf16x8 af = *(const bf16x8*)(sA + aoff[t]);
            #pragma unroll
            for (int nt = 0; nt < 4; ++nt) {
                bf16x8 bg = *(const bf16x8*)(&sB[t][(nt * 16 + frow) * 40 + fq * 8]);
                accC[nt] = __builtin_amdgcn_mfma_f32_16x16x32_bf16(af, bg, accC[nt], 0, 0, 0);
            }
        }
        if constexpr (HASWD) {
            bf16x8 af = *(const bf16x8*)(sA + aoff[TAPS]);
            #pragma unroll
            for (int nt = 0; nt < 4; ++nt) {
                bf16x8 bg = *(const bf16x8*)(&sB[TAPS][(nt * 16 + frow) * 40 + fq * 8]);
                accR[nt] = __builtin_amdgcn_mfma_f32_16x16x32_bf16(af, bg, accR[nt], 0, 0, 0);
            }
        }
    }

    if (mode == 0) {
        #pragma unroll
        for (int nt = 0; nt < 4; ++nt) {
            int col = n0 + nt * 16 + frow;
            if (col >= N) continue;
            float bv = bias ? bias[col] : 0.f;
            #pragma unroll
            for (int r = 0; r < 4; ++r) {
                int row = m0 + wv * 16 + fq * 4 + r;
                if (row >= M) continue;
                float v = accC[nt][r] + bv;
                if (relu) v = fmaxf(v, 0.f);
                if (outb) outb[(size_t)row * out_stride + col] = __float2bfloat16(clamp256(v));
                else      outf[(size_t)row * out_stride + col] = sane(v);
            }
        }
    } else if (mode == 3) {
        bf* po = outb + (size_t)blockIdx.z * M * out_stride;
        #pragma unroll
        for (int nt = 0; nt < 4; ++nt) {
            int col = n0 + nt * 16 + frow;
            if (col >= N) continue;
            #pragma unroll
            for (int r = 0; r < 4; ++r) {
                int row = m0 + wv * 16 + fq * 4 + r;
                if (row >= M) continue;
                po[(size_t)row * out_stride + col] = __float2bfloat16(accC[nt][r]);
            }
        }
    } else if (mode == 5) {
        if constexpr (HASWD) {
            bf* out2 = (bf*)res;
            // hoist padded-row mapping: 4 divisions instead of 16
            int orow_[4];
            #pragma unroll
            for (int r = 0; r < 4; ++r) {
                int row = m0 + wv * 16 + fq * 4 + r;
                orow_[r] = relu ? ((row / nn) * 32 + (row % nn)) : row;
            }
            #pragma unroll
            for (int nt = 0; nt < 4; ++nt) {
                int col = n0 + nt * 16 + frow;
                if (col >= N) continue;
                float bv = bias[col], bd = biasd[col];
                #pragma unroll
                for (int r = 0; r < 4; ++r) {
                    int row = m0 + wv * 16 + fq * 4 + r;
                    if (row >= M) continue;
                    outb[(size_t)row * out_stride + col] = __float2bfloat16(clamp256(accC[nt][r] + bv));
                    out2[(size_t)orow_[r] * res_stride + col] = __float2bfloat16(clamp256(accR[nt][r] + bd));
                }
            }
        }
    } else {  // mode 2
        float bvc[4], bdc[4];
        #pragma unroll
        for (int nt = 0; nt < 4; ++nt) {
            int col = n0 + nt * 16 + frow;
            bvc[nt] = bias[col];
            bdc[nt] = (HASWD && biasd) ? biasd[col] : 0.f;
        }
        float s[4], s2[4];
        #pragma unroll
        for (int nt = 0; nt < 4; ++nt) { s[nt] = 0.f; s2[nt] = 0.f; }
        #pragma unroll
        for (int nt = 0; nt < 4; ++nt)
            #pragma unroll
            for (int r = 0; r < 4; ++r) {
                int row = wv * 16 + fq * 4 + r;
                int l = row & 31;
                float v = sane(accC[nt][r] + bvc[nt]);
                if (l < nn) { s[nt] += v; s2[nt] += v * v; }
            }
        #pragma unroll
        for (int nt = 0; nt < 4; ++nt) {
            s[nt]  += __shfl_xor(s[nt], 16);  s[nt]  += __shfl_xor(s[nt], 32);
            s2[nt] += __shfl_xor(s2[nt], 16); s2[nt] += __shfl_xor(s2[nt], 32);
        }
        if (fq == 0) {
            #pragma unroll
            for (int nt = 0; nt < 4; ++nt) {
                sS[wv][nt * 16 + frow]  = s[nt];
                sS2[wv][nt * 16 + frow] = s2[nt];
            }
        }
        __syncthreads();
        const int gi = wv >> 1;
        const float inv = 1.f / (float)nn;
        #pragma unroll
        for (int nt = 0; nt < 4; ++nt) {
            int c = nt * 16 + frow;
            int colg = n0 + c;
            float S  = sS[2 * gi][c]  + sS[2 * gi + 1][c];
            float S2 = sS2[2 * gi][c] + sS2[2 * gi + 1][c];
            float mu = S * inv;
            float var = S2 * inv - mu * mu;
            float rs = rsqrtf(fmaxf(var, 0.f) + 1e-5f);
            #pragma unroll
            for (int r = 0; r < 4; ++r) {
                int row = wv * 16 + fq * 4 + r;
                int l = row & 31;
                int grow = m0 + row;
                float outv = 0.f;
                if (l < nn) {
                    float v = (sane(accC[nt][r] + bvc[nt]) - mu) * rs * lnw[l] + lnb[l];
                    v = fmaxf(v, 0.f);
                    float rr;
                    if constexpr (HASWD) rr = sane(accR[nt][r] + bdc[nt]);
                    else rr = __bfloat162float(res[(size_t)grow * res_stride + colg]);
                    outv = clamp256(v + rr);
                }
                outb[(size_t)grow * out_stride + colg] = __float2bfloat16(outv);
            }
        }
    }
}

// ---------------------------------------------------------------------------
// TCN tap-fused GEMM v3 (round-4 winner, unchanged): 256x64 macro-tile,
// 64x64 per wave, B via dbuf global_load_lds DMA of pre-swizzled weights.
// ---------------------------------------------------------------------------
template<int TAPS, bool HASWD>
__global__ __launch_bounds__(256, 2) void gemm_tcn(
    const bf* __restrict__ A, const bf* __restrict__ Wt, const bf* __restrict__ Wd,
    const float* __restrict__ bias, const float* __restrict__ biasd,
    const float* __restrict__ lnw, const float* __restrict__ lnb,
    const bf* __restrict__ res, int res_stride,
    bf* __restrict__ outb, int out_stride,
    int M, int N, int K, int dil, int nn)
{
    constexpr int NT = TAPS + (HASWD ? 1 : 0);
    __shared__ __align__(16) unsigned short sA[257 * 40];
    __shared__ __align__(16) unsigned short sBall[2 * NT * 64 * 32];

    const int tid  = threadIdx.x;
    const int wv   = tid >> 6;
    const int lane = tid & 63;
    const int frow = lane & 15;
    const int fq   = lane >> 4;

    const int gx  = gridDim.x;
    const int nwg = gx * gridDim.y;
    int wg = blockIdx.y * gx + blockIdx.x;
    if ((nwg & 7) == 0) wg = (wg & 7) * (nwg >> 3) + (wg >> 3);
    const int n0 = (wg % gx) * 64;
    const int m0 = (wg / gx) * 256;

    if (tid < 40) sA[256 * 40 + tid] = (unsigned short)0;

    int aoff[TAPS][4];
    #pragma unroll
    for (int mr = 0; mr < 4; ++mr) {
        int token = wv * 64 + mr * 16 + frow;
        int b5 = token >> 5, l = token & 31;
        #pragma unroll
        for (int t = 0; t < TAPS; ++t) {
            int ls = l + (t - TAPS / 2) * dil;
            int ar = ((unsigned)ls < 32u) ? (b5 * 32 + ls) : 256;
            aoff[t][mr] = ar * 40 + fq * 8;
        }
    }
    const int bco = (fq ^ ((frow >> 1) & 3)) << 3;

    const int srow = tid >> 2;
    const int chS  = (tid & 3) << 3;
    const bf* Ap = A + (size_t)(m0 + srow) * K + chS;

    const bf* bsrc[4];
    {
        int lr = lane >> 2, lc = lane & 3;
        #pragma unroll
        for (int i = 0; i < 4; ++i) {
            int colb = n0 + i * 16 + lr;
            const bf* Wb;
            if (HASWD && wv == TAPS) Wb = Wd + (size_t)colb * K;
            else if (wv < TAPS)      Wb = Wt + ((size_t)wv * N + colb) * K;
            else                     Wb = Wt + (size_t)colb * K;
            bsrc[i] = Wb + lc * 8;
        }
    }

    f32x4 accC[4][4], accR[4][4];
    #pragma unroll
    for (int i = 0; i < 4; ++i)
        #pragma unroll
        for (int j = 0; j < 4; ++j) { accC[i][j] = 0.f; if (HASWD) accR[i][j] = 0.f; }

    #define ISSUE_B(BUFB, KBS)                                                      \
        if (wv < NT) {                                                              \
            unsigned short* bas = sBall + ((size_t)((BUFB) * NT + wv) * 64) * 32;   \
            _Pragma("unroll")                                                       \
            for (int i = 0; i < 4; ++i) {                                           \
                __builtin_amdgcn_global_load_lds(                                   \
                    (const __attribute__((address_space(1))) void*)(bsrc[i] + (KBS)), \
                    (__attribute__((address_space(3))) void*)(bas + i * 512),       \
                    16, 0, 0);                                                      \
            }                                                                       \
        }

    uint4 pa[4];
    #pragma unroll
    for (int i = 0; i < 4; ++i) pa[i] = *(const uint4*)(Ap + (size_t)i * 64 * K);
    ISSUE_B(0, 0);

    int buf = 0;
    for (int kb = 0; kb < K; kb += 32) {
        __syncthreads();
        #pragma unroll
        for (int i = 0; i < 4; ++i)
            *(uint4*)(sA + (srow + i * 64) * 40 + chS) = pa[i];
        __syncthreads();
        int kn = kb + 32;
        if (kn < K) {
            ISSUE_B(buf ^ 1, kn);
            #pragma unroll
            for (int i = 0; i < 4; ++i)
                pa[i] = *(const uint4*)(Ap + (size_t)i * 64 * K + kn);
        }
        const unsigned short* sBb = sBall + (size_t)buf * NT * 2048;
        bf16x8 aMid[4];
        #pragma unroll
        for (int mr = 0; mr < 4; ++mr)
            aMid[mr] = *(const bf16x8*)(sA + aoff[TAPS / 2][mr]);
        #pragma unroll
        for (int t = 0; t < TAPS; ++t) {
            bf16x8 af[4];
            #pragma unroll
            for (int mr = 0; mr < 4; ++mr)
                af[mr] = (t == TAPS / 2) ? aMid[mr]
                                         : *(const bf16x8*)(sA + aoff[t][mr]);
            #pragma unroll
            for (int nt = 0; nt < 4; ++nt) {
                bf16x8 bg = *(const bf16x8*)(sBb + (size_t)t * 2048 + (nt * 16 + frow) * 32 + bco);
                #pragma unroll
                for (int mr = 0; mr < 4; ++mr)
                    accC[mr][nt] = __builtin_amdgcn_mfma_f32_16x16x32_bf16(af[mr], bg, accC[mr][nt], 0, 0, 0);
            }
        }
        if constexpr (HASWD) {
            #pragma unroll
            for (int nt = 0; nt < 4; ++nt) {
                bf16x8 bg = *(const bf16x8*)(sBb + (size_t)TAPS * 2048 + (nt * 16 + frow) * 32 + bco);
                #pragma unroll
                for (int mr = 0; mr < 4; ++mr)
                    accR[mr][nt] = __builtin_amdgcn_mfma_f32_16x16x32_bf16(aMid[mr], bg, accR[mr][nt], 0, 0, 0);
            }
        }
        buf ^= 1;
    }
    #undef ISSUE_B

    float bvc[4], bdc[4];
    #pragma unroll
    for (int nt = 0; nt < 4; ++nt) {
        int col = n0 + nt * 16 + frow;
        bvc[nt] = bias[col];
        bdc[nt] = HASWD ? biasd[col] : 0.f;
    }
    float S[2][4], Q[2][4];
    #pragma unroll
    for (int h = 0; h < 2; ++h)
        #pragma unroll
        for (int nt = 0; nt < 4; ++nt) { S[h][nt] = 0.f; Q[h][nt] = 0.f; }
    #pragma unroll
    for (int mr = 0; mr < 4; ++mr) {
        const int h = mr >> 1;
        #pragma unroll
        for (int nt = 0; nt < 4; ++nt)
            #pragma unroll
            for (int r = 0; r < 4; ++r) {
                int l = (mr & 1) * 16 + fq * 4 + r;
                if (l < nn) {
                    float v = sane(accC[mr][nt][r] + bvc[nt]);
                    S[h][nt] += v; Q[h][nt] += v * v;
                }
            }
    }
    const float inv = 1.f / (float)nn;
    float mu[2][4], rsg[2][4];
    #pragma unroll
    for (int h = 0; h < 2; ++h)
        #pragma unroll
        for (int nt = 0; nt < 4; ++nt) {
            float s = S[h][nt], q = Q[h][nt];
            s += __shfl_xor(s, 16); s += __shfl_xor(s, 32);
            q += __shfl_xor(q, 16); q += __shfl_xor(q, 32);
            float m = s * inv;
            float var = q * inv - m * m;
            mu[h][nt]  = m;
            rsg[h][nt] = rsqrtf(fmaxf(var, 0.f) + 1e-5f);
        }
    float lw[2][4], lb2[2][4];
    #pragma unroll
    for (int p = 0; p < 2; ++p)
        #pragma unroll
        for (int r = 0; r < 4; ++r) {
            int l = p * 16 + fq * 4 + r;
            bool ok = l < nn;
            lw[p][r]  = ok ? lnw[l] : 0.f;
            lb2[p][r] = ok ? lnb[l] : 0.f;
        }
    #pragma unroll
    for (int nt = 0; nt < 4; ++nt) {
        const int colg = n0 + nt * 16 + frow;
        #pragma unroll
        for (int mr = 0; mr < 4; ++mr) {
            const int h = mr >> 1, p = mr & 1;
            #pragma unroll
            for (int r = 0; r < 4; ++r) {
                int l = p * 16 + fq * 4 + r;
                int grow = m0 + wv * 64 + mr * 16 + fq * 4 + r;
                float outv = 0.f;
                if (l < nn) {
                    float v = (sane(accC[mr][nt][r] + bvc[nt]) - mu[h][nt]) * rsg[h][nt] * lw[p][r] + lb2[p][r];
                    v = fmaxf(v, 0.f);
                    float rr;
                    if constexpr (HASWD) rr = sane(accR[mr][nt][r] + bdc[nt]);
                    else rr = __bfloat162float(res[(size_t)grow * res_stride + colg]);
                    outv = clamp256(v + rr);
                }
                outb[(size_t)grow * out_stride + colg] = __float2bfloat16(outv);
            }
        }
    }
}

// ---------------------------------------------------------------------------
// Fused per-graph GAT v4.1. CONV=1 fuses TCN block 0 (h in LDS, MFMA conv,
// in-register LN+relu+residual). LDS dieted to 40264 B -> 4 blocks/CU
// (= the 1024-block grid's exact residency): sSrc/sDst packed into sSD,
// sList as u16.
// ---------------------------------------------------------------------------
#define MAXNE 270
#define XLS   260   // padded XL row stride (channels)
#define SHP   264   // padded H row stride (channels)
template<int CONV>
__global__ __launch_bounds__(256, 4) void gat_fused4(
    const int* __restrict__ ei, const bf* __restrict__ xlb, const bf* __restrict__ xrb,
    const float* __restrict__ att, const float* __restrict__ gbias,
    const bf* __restrict__ Wf, const float* __restrict__ cbias,
    const float* __restrict__ lnw, const float* __restrict__ lnb,
    bf* __restrict__ yout, float* __restrict__ dalpha, float* __restrict__ dei,
    int E0, int ET, int EPG, int nn)
{
    __shared__ __align__(16) __bf16 sXL[32 * XLS];   // 16.25 KB (padded rows)
    __shared__ __align__(16) __bf16 sHX[33 * SHP];   // 17.0 KB: XR (stride 256) then H (stride SHP)
    __shared__ float sExp[MAXNE * 4];                // 4.2 KB
    __shared__ int   sSD[MAXNE];                     // src | dst<<16
    __shared__ unsigned short sList[MAXNE];
    __shared__ int   sCnt[32];
    __shared__ int   sOff[33];

    const int g = blockIdx.x, tid = threadIdx.x, wv = tid >> 6, lane = tid & 63;
    if (EPG + nn > MAXNE) return;
    const int NE = EPG + nn;

    // Phase 0a: edges + self loops; stage xl/xr; zero H row 32
    for (int k = tid; k < EPG; k += 256) {
        int s = ei[(size_t)g * EPG + k] - g * nn;
        int d = ei[(size_t)E0 + (size_t)g * EPG + k] - g * nn;
        s = min(max(s, 0), nn - 1);
        d = min(max(d, 0), nn - 1);
        sSD[k] = s | (d << 16);
    }
    for (int k = EPG + tid; k < NE; k += 256) {
        int node = k - EPG;
        sSD[k] = node | (node << 16);
    }
    {
        const uint4* gxl = (const uint4*)(xlb + (size_t)g * nn * 256);
        const uint4* gxr = (const uint4*)(xrb + (size_t)g * (CONV ? 32 : nn) * 256);
        for (int k = tid; k < nn * 32; k += 256) {
            int node = k >> 5, c8 = k & 31;
            *(uint4*)(sXL + node * XLS + c8 * 8) = gxl[k];
            *(uint4*)(sHX + k * 8) = gxr[k];                 // XR layout, stride 256
        }
    }
    if (CONV) { for (int k = tid; k < SHP; k += 256) sHX[32 * SHP + k] = (__bf16)0.f; }
    if (tid < 32) sCnt[tid] = 0;
    __syncthreads();

    // Phase 0b: histogram -> parallel exclusive scan -> scatter
    for (int k = tid; k < NE; k += 256) atomicAdd(&sCnt[sSD[k] >> 16], 1);
    __syncthreads();
    if (tid < 32) {
        int acc = 0, last = 0;
        #pragma unroll
        for (int j = 0; j < 32; ++j) {
            int c = sCnt[j];
            if (j < tid) acc += c;
            if (j == 31) last = c;
        }
        sOff[tid] = acc;
        if (tid == 31) sOff[32] = acc + last;
        sCnt[tid] = 0;
    }
    __syncthreads();
    for (int k = tid; k < NE; k += 256) {
        int d = sSD[k] >> 16;
        int p = atomicAdd(&sCnt[d], 1);
        sList[sOff[d] + p] = (unsigned short)k;
    }

    // ei echo
    for (int k = tid; k < NE; k += 256) {
        int s, d; size_t eg;
        if (k < EPG) {
            int sd = sSD[k];
            s = g * nn + (sd & 0xffff); d = g * nn + (sd >> 16);
            eg = (size_t)g * EPG + k;
        }
        else { int node = g * nn + (k - EPG); s = d = node; eg = (size_t)E0 + (size_t)g * nn + (k - EPG); }
        dei[eg] = (float)s;
        dei[(size_t)ET + eg] = (float)d;
    }
    __syncthreads();

    // Phase 1: wave-per-edge scores (reads XR from sHX, stride 256)
    const float4 attv = *(const float4*)(att + lane * 4);
    const int h4 = lane >> 4;
    for (int i = wv; i < NE; i += 4) {
        int sd = sSD[i];
        int srcl = sd & 0xffff, dstl = sd >> 16;
        bf16x4 a = *(const bf16x4*)(sXL + srcl * XLS + lane * 4);
        bf16x4 b = *(const bf16x4*)(sHX + dstl * 256 + lane * 4);
        float p = 0.f;
        {
            float v0 = (float)a[0] + (float)b[0]; v0 = v0 > 0.f ? v0 : 0.2f * v0; p += v0 * attv.x;
            float v1 = (float)a[1] + (float)b[1]; v1 = v1 > 0.f ? v1 : 0.2f * v1; p += v1 * attv.y;
            float v2 = (float)a[2] + (float)b[2]; v2 = v2 > 0.f ? v2 : 0.2f * v2; p += v2 * attv.z;
            float v3 = (float)a[3] + (float)b[3]; v3 = v3 > 0.f ? v3 : 0.2f * v3; p += v3 * attv.w;
        }
        p += __shfl_xor(p, 1); p += __shfl_xor(p, 2);
        p += __shfl_xor(p, 4); p += __shfl_xor(p, 8);
        if ((lane & 15) == 0)
            sExp[i * 4 + h4] = __expf(fminf(fmaxf(p, -60.f), 60.f));
    }
    __syncthreads();

    // Phase 2: 8-lane group per dst node; lane owns 32 channels.
    {
        const int grp  = wv * 8 + (lane >> 3);
        const int s8   = lane & 7;
        const int chb  = s8 * 32;
        const int head = s8 >> 1;
        bf* hrow = yout + ((size_t)g * 32 + grp) * 256 + chb;   // !CONV only

        if (grp < nn) {
            const int beg = sOff[grp], end = sOff[grp + 1];
            float den = 0.f;
            f32x4 acc[8];
            #pragma unroll
            for (int k2 = 0; k2 < 8; ++k2) acc[k2] = 0.f;

            for (int q = beg; q < end; ++q) {
                int e = sList[q];
                float ev = sExp[e * 4 + head];
                den += ev;
                const __bf16* xp = sXL + (sSD[e] & 0xffff) * XLS + chb;
                #pragma unroll
                for (int k2 = 0; k2 < 4; ++k2) {
                    bf16x8 xa = *(const bf16x8*)(xp + k2 * 8);
                    #pragma unroll
                    for (int j = 0; j < 4; ++j)
                        acc[k2 * 2][j]     += ev * (float)xa[j];
                    #pragma unroll
                    for (int j = 0; j < 4; ++j)
                        acc[k2 * 2 + 1][j] += ev * (float)xa[4 + j];
                }
            }
            const float rden = 1.f / fmaxf(den, 1e-30f);

            if (!(s8 & 1)) {
                for (int q = beg; q < end; ++q) {
                    int e = sList[q];
                    float al = fminf(fmaxf(sExp[e * 4 + head] * rden, 0.f), 1.f);
                    size_t eg = (e < EPG) ? ((size_t)g * EPG + e)
                                          : ((size_t)E0 + (size_t)g * nn + (e - EPG));
                    dalpha[eg * 4 + head] = al;
                }
            }

            #pragma unroll
            for (int k2 = 0; k2 < 8; ++k2) {
                float4 gbv = *(const float4*)(gbias + chb + k2 * 4);
                bf16x4 o;
                o[0] = (__bf16)clamp256(fmaxf(acc[k2][0] * rden + gbv.x, 0.f));
                o[1] = (__bf16)clamp256(fmaxf(acc[k2][1] * rden + gbv.y, 0.f));
                o[2] = (__bf16)clamp256(fmaxf(acc[k2][2] * rden + gbv.z, 0.f));
                o[3] = (__bf16)clamp256(fmaxf(acc[k2][3] * rden + gbv.w, 0.f));
                if constexpr (CONV) *(bf16x4*)(sHX + grp * SHP + chb + k2 * 4) = o;
                else                *(bf16x4*)(hrow + k2 * 4) = o;
            }
        } else {
            bf16x4 z; z[0] = (__bf16)0.f; z[1] = (__bf16)0.f; z[2] = (__bf16)0.f; z[3] = (__bf16)0.f;
            #pragma unroll
            for (int k2 = 0; k2 < 8; ++k2) {
                if constexpr (CONV) *(bf16x4*)(sHX + grp * SHP + chb + k2 * 4) = z;
                else                *(bf16x4*)(hrow + k2 * 4) = z;
            }
        }
    }

    // Phase 3 (CONV): y0 = relu(LN(conv3(h))) + h, per-wave 64 cols via MFMA
    if constexpr (CONV) {
        __syncthreads();
        const int frow = lane & 15;
        const int fq   = lane >> 4;
        const int colw = wv * 64;
        f32x4 c0[2][4];
        #pragma unroll
        for (int i = 0; i < 2; ++i)
            #pragma unroll
            for (int j = 0; j < 4; ++j) c0[i][j] = 0.f;

        #pragma unroll
        for (int kc = 0; kc < 8; ++kc) {
            bf16x8 af[3][2];
            #pragma unroll
            for (int t = 0; t < 3; ++t)
                #pragma unroll
                for (int mr = 0; mr < 2; ++mr) {
                    int l = mr * 16 + frow + t - 1;
                    int ar = ((unsigned)l < 32u) ? l : 32;
                    af[t][mr] = *(const bf16x8*)(sHX + ar * SHP + kc * 32 + fq * 8);
                }
            #pragma unroll
            for (int t = 0; t < 3; ++t) {
                // hoist the 4 B-frag loads of this tap -> more VMEM in flight
                bf16x8 bgs[4];
                #pragma unroll
                for (int nt = 0; nt < 4; ++nt) {
                    const __bf16* bp = (const __bf16*)Wf +
                        ((((size_t)(t * 16 + (colw >> 4) + nt) * 8 + kc) * 16 + frow) * 4 + fq) * 8;
                    bgs[nt] = *(const bf16x8*)bp;
                }
                #pragma unroll
                for (int nt = 0; nt < 4; ++nt) {
                    c0[0][nt] = __builtin_amdgcn_mfma_f32_16x16x32_bf16(af[t][0], bgs[nt], c0[0][nt], 0, 0, 0);
                    c0[1][nt] = __builtin_amdgcn_mfma_f32_16x16x32_bf16(af[t][1], bgs[nt], c0[1][nt], 0, 0, 0);
                }
            }
        }

        float bv[4];
        #pragma unroll
        for (int nt = 0; nt < 4; ++nt) bv[nt] = cbias[colw + nt * 16 + frow];
        float S[4], Q[4];
        #pragma unroll
        for (int nt = 0; nt < 4; ++nt) { S[nt] = 0.f; Q[nt] = 0.f; }
        #pragma unroll
        for (int mr = 0; mr < 2; ++mr)
            #pragma unroll
            for (int nt = 0; nt < 4; ++nt)
                #pragma unroll
                for (int r = 0; r < 4; ++r) {
                    int l = mr * 16 + fq * 4 + r;
                    if (l < nn) {
                        float v = sane(c0[mr][nt][r] + bv[nt]);
                        S[nt] += v; Q[nt] += v * v;
                    }
                }
        const float inv = 1.f / (float)nn;
        float mu[4], rsg[4];
        #pragma unroll
        for (int nt = 0; nt < 4; ++nt) {
            float s = S[nt], q = Q[nt];
            s += __shfl_xor(s, 16); s += __shfl_xor(s, 32);
            q += __shfl_xor(q, 16); q += __shfl_xor(q, 32);
            float m = s * inv;
            float var = q * inv - m * m;
            mu[nt]  = m;
            rsg[nt] = rsqrtf(fmaxf(var, 0.f) + 1e-5f);
        }
        float lw[2][4], lb2[2][4];
        #pragma unroll
        for (int p = 0; p < 2; ++p)
            #pragma unroll
            for (int r = 0; r < 4; ++r) {
                int l = p * 16 + fq * 4 + r;
                bool ok = l < nn;
                lw[p][r]  = ok ? lnw[l] : 0.f;
                lb2[p][r] = ok ? lnb[l] : 0.f;
            }
        #pragma unroll
        for (int nt = 0; nt < 4; ++nt) {
            const int colf = colw + nt * 16 + frow;
            #pragma unroll
            for (int mr = 0; mr < 2; ++mr)
                #pragma unroll
                for (int r = 0; r < 4; ++r) {
                    int l = mr * 16 + fq * 4 + r;
                    float outv = 0.f;
                    if (l < nn) {
                        float v = (sane(c0[mr][nt][r] + bv[nt]) - mu[nt]) * rsg[nt] * lw[mr][r] + lb2[mr][r];
                        v = fmaxf(v, 0.f);
                        float rr = (float)sHX[l * SHP + colf];
                        outv = clamp256(v + rr);
                    }
                    yout[((size_t)g * 32 + l) * 256 + colf] = __float2bfloat16(outv);
                }
        }
    }
}

// ---- fused weight prep ----
struct CvtSegs { const float* in[7]; bf* out[7]; int n[7]; };
__global__ void prep_cvt(CvtSegs s, int total)
{
    int idx = blockIdx.x * 256 + threadIdx.x;
    if (idx >= total) return;
    #pragma unroll
    for (int i = 0; i < 7; ++i) {
        if (idx < s.n[i]) { s.out[i][idx] = __float2bfloat16(s.in[i][idx]); return; }
        idx -= s.n[i];
    }
}
// taps, optionally swizzled for gemm_tcn's global_load_lds path
struct TapSegs { const float* w[3]; bf* o[3]; int cc[3]; int kk[3]; int swz[3]; };
__global__ void prep_taps3(TapSegs s, int total)
{
    int idx = blockIdx.x * 256 + threadIdx.x;
    if (idx >= total) return;
    #pragma unroll
    for (int i = 0; i < 3; ++i) {
        if (idx < s.cc[i]) {
            unsigned K = (unsigned)s.kk[i];
            unsigned co = (unsigned)idx / K, ci = (unsigned)idx % K;
            int dst = co * K + (s.swz[i] ? swzk(ci, co) : ci);
            #pragma unroll
            for (int k = 0; k < 3; ++k)
                s.o[i][(size_t)k * s.cc[i] + dst] = __float2bfloat16(s.w[i][(size_t)idx * 3 + k]);
            return;
        }
        idx -= s.cc[i];
    }
}
// downsample weights, optionally swizzled
__global__ void prep_wswz(const float* __restrict__ w, bf* __restrict__ o,
                          int total, int K, int swz)
{
    int idx = blockIdx.x * 256 + threadIdx.x;
    if (idx >= total) return;
    int co = idx / K, ci = idx % K;
    o[(size_t)co * K + (swz ? swzk(ci, co) : ci)] = __float2bfloat16(w[idx]);
}
// conv0 weights -> MFMA-fragment-contiguous layout (coalesced 1KB wave loads)
__global__ void prep_bfrag(const float* __restrict__ w, bf* __restrict__ o, int HC)
{
    int idx = blockIdx.x * 256 + threadIdx.x;
    if (idx >= HC * HC) return;
    int co = idx / HC, ci = idx % HC;
    int cg = co >> 4, fr = co & 15, kc = ci >> 5, fq = (ci >> 3) & 3, w8 = ci & 7;
    int NCg = HC >> 4, NKc = HC >> 5;
    #pragma unroll
    for (int t = 0; t < 3; ++t) {
        size_t dst = (((((size_t)t * NCg + cg) * NKc + kc) * 16 + fr) * 4 + fq) * 8 + w8;
        o[dst] = __float2bfloat16(w[(size_t)idx * 3 + t]);
    }
}

// fc1_w f32 [F1][ci*nn+l] -> bf16 W1t [F1][l*HC+ci], l padded to 32
__global__ void prep_fc1(const float* __restrict__ w, bf* __restrict__ o, int F1, int nn, int HC)
{
    int idx = blockIdx.x * 256 + threadIdx.x;
    int kw = 32 * HC;
    if (idx >= F1 * kw) return;
    int co = idx / kw, r = idx % kw, l = r / HC, ci = r % HC;
    float hv = 0.f;
    if (l < nn) hv = w[(size_t)co * (HC * nn) + ci * nn + l];
    o[idx] = __float2bfloat16(hv);
}

// fc1 split-K reduce: z1 = bf16(relu(sum_z partials + bias))
__global__ void fc1red(const bf* __restrict__ zp, const float* __restrict__ bias,
                       bf* __restrict__ o, int MN, int N, int S)
{
    int idx = blockIdx.x * 256 + threadIdx.x;
    if (idx >= MN) return;
    float s = 0.f;
    for (int z = 0; z < S; ++z) s += __bfloat162float(zp[(size_t)z * MN + idx]);
    o[idx] = __float2bfloat16(clamp256(fmaxf(s + bias[idx % N], 0.f)));
}

extern "C" void kernel_launch(void* const* d_in, const int* in_sizes, int n_in,
                              void* d_out, int out_size, void* d_ws, size_t ws_size,
                              hipStream_t stream)
{
    (void)n_in; (void)ws_size;
    const float* x   = (const float*)d_in[0];
    const float* Wl  = (const float*)d_in[1];  const float* bl  = (const float*)d_in[2];
    const float* Wr  = (const float*)d_in[3];  const float* br  = (const float*)d_in[4];
    const float* att = (const float*)d_in[5];  const float* gb  = (const float*)d_in[6];
    const float* t0w = (const float*)d_in[7];  const float* t0b = (const float*)d_in[8];
    const float* l0w = (const float*)d_in[9];  const float* l0b = (const float*)d_in[10];
    const float* t1w = (const float*)d_in[11]; const float* t1b = (const float*)d_in[12];
    const float* l1w = (const float*)d_in[13]; const float* l1b = (const float*)d_in[14];
    const float* d1w = (const float*)d_in[15]; const float* d1b = (const float*)d_in[16];
    const float* t2w = (const float*)d_in[17]; const float* t2b = (const float*)d_in[18];
    const float* l2w = (const float*)d_in[19]; const float* l2b = (const float*)d_in[20];
    const float* d2w = (const float*)d_in[21]; const float* d2b = (const float*)d_in[22];
    const float* f1w = (const float*)d_in[23]; const float* f1b = (const float*)d_in[24];
    const float* f2w = (const float*)d_in[25]; const float* f2b = (const float*)d_in[26];
    const float* f3w = (const float*)d_in[27]; const float* f3b = (const float*)d_in[28];
    const int*   ei  = (const int*)d_in[29];

    const int HC   = in_sizes[6];                        // 256
    const int F_IN = in_sizes[1] / (HC > 0 ? HC : 1);    // 64
    const int NN   = in_sizes[0] / (F_IN > 0 ? F_IN : 1);// 30720
    const int E0   = in_sizes[29] / 2;                   // 245760
    const int ET   = E0 + NN;                            // 276480
    int nn = in_sizes[9];  nn = nn < 1 ? 1 : (nn > 32 ? 32 : nn);  // 30
    const int NG   = NN / nn;                            // 1024
    const int EPG  = NG > 0 ? E0 / NG : 0;               // 240
    const int C1   = in_sizes[12];                       // 512
    const int C2   = in_sizes[18];                       // 256
    const int F1   = in_sizes[24];                       // 512
    const int F2   = in_sizes[26];                       // 256
    const int F3   = in_sizes[28];                       // 144
    const int NG2  = (NG + 1) / 2;

    float* dout   = (float*)d_out;
    float* dei    = dout + ((size_t)out_size - 2 * (size_t)ET);
    float* dalpha = dei - (size_t)ET * 4;

    // ---- path eligibility ----
    const bool fused0 = (HC == 256) && (nn >= 1) && (nn <= 32) && (EPG + nn <= MAXNE)
                        && ((NN % 64) == 0);
    const int  gcA = NG2, gcB = NG - NG2;
    const bool fastc = ((gcA * 32) % 256 == 0) && ((gcB * 32) % 256 == 0)
                       && (C1 % 64 == 0) && (C2 % 64 == 0)
                       && (HC % 32 == 0) && (C1 % 32 == 0);

    // ---- workspace map (42 MB):
    //  [0,4M)      xb (dead after GAT gemm) -> z1, z2
    //  [4M,7.5M)   weights (incl. WkAf frag layout)
    //  S0 [7.5,25M): fused: xrb(pad32) -> y0 -> y2 ; fallback: xrb/hbuf
    //  S1 [25,42M):  xlb -> (fused: y1c -> W1t+z1p) (fallback: y0 -> y2)
    char* ws = (char*)d_ws;
    const size_t MB = 1ull << 20;
    bf*    xb   = (bf*)(ws);
    bf*    WkA  = (bf*)(ws + 4 * MB);
    bf*    WkB  = WkA + (size_t)3 * HC * HC;
    bf*    WkC  = WkB + (size_t)3 * C1 * HC;
    bf*    Wlb  = WkC + (size_t)3 * C2 * C1;
    bf*    Wrb  = Wlb + (size_t)HC * F_IN;
    bf*    f2wb = Wrb + (size_t)HC * F_IN;
    bf*    f3wb = f2wb + (size_t)F2 * F1;
    bf*    d1wb = f3wb + (size_t)F3 * F2;
    bf*    d2wb = d1wb + (size_t)C1 * HC;
    bf*    WkAf = d2wb + (size_t)C2 * C1;                // frag-layout conv0 weights
    char*  S0   = ws + (size_t)(7.5 * MB);
    char*  S1   = ws + 25 * MB;

    bf*    xrb  = (bf*)S0;                               // padded 32 rows when fused0
    bf*    hbuf = (bf*)S0;                               // fallback GAT output
    bf*    xlb  = (bf*)S1;
    bf*    y0   = fused0 ? (bf*)S0 : (bf*)S1;
    bf*    y1c  = fused0 ? (bf*)S1 : (bf*)S0;
    char*  fcS  = fused0 ? S1 : S0;                      // FC staging region
    bf*    W1t  = (bf*)fcS;                              // 8.4 MB
    bf*    z1p  = (bf*)(fcS + (size_t)(8.5 * MB));       // 8 MB
    bf*    z1   = (bf*)(ws);                             // 1 MB (over dead xb)
    bf*    z2   = (bf*)(ws + 2 * MB);                    // 0.5 MB

    // ---- fused weight prep ----
    {
        CvtSegs cs;
        cs.in[0] = x;   cs.out[0] = xb;   cs.n[0] = NN * F_IN;
        cs.in[1] = Wl;  cs.out[1] = Wlb;  cs.n[1] = HC * F_IN;
        cs.in[2] = Wr;  cs.out[2] = Wrb;  cs.n[2] = HC * F_IN;
        cs.in[3] = f2w; cs.out[3] = f2wb; cs.n[3] = F2 * F1;
        cs.in[4] = f3w; cs.out[4] = f3wb; cs.n[4] = F3 * F2;
        cs.in[5] = nullptr; cs.out[5] = nullptr; cs.n[5] = 0;
        cs.in[6] = nullptr; cs.out[6] = nullptr; cs.n[6] = 0;
        int tot = 0; for (int i = 0; i < 5; ++i) tot += cs.n[i];
        prep_cvt<<<(tot + 255) / 256, 256, 0, stream>>>(cs, tot);
        TapSegs ts;
        ts.w[0] = t0w; ts.o[0] = WkA; ts.cc[0] = HC * HC; ts.kk[0] = HC; ts.swz[0] = 0;
        ts.w[1] = t1w; ts.o[1] = WkB; ts.cc[1] = C1 * HC; ts.kk[1] = HC; ts.swz[1] = fastc ? 1 : 0;
        ts.w[2] = t2w; ts.o[2] = WkC; ts.cc[2] = C2 * C1; ts.kk[2] = C1; ts.swz[2] = fastc ? 1 : 0;
        int tt = ts.cc[0] + ts.cc[1] + ts.cc[2];
        prep_taps3<<<(tt + 255) / 256, 256, 0, stream>>>(ts, tt);
        prep_wswz<<<(C1 * HC + 255) / 256, 256, 0, stream>>>(d1w, d1wb, C1 * HC, HC, fastc ? 1 : 0);
        prep_wswz<<<(C2 * C1 + 255) / 256, 256, 0, stream>>>(d2w, d2wb, C2 * C1, C1, fastc ? 1 : 0);
        if (fused0)
            prep_bfrag<<<(HC * HC + 255) / 256, 256, 0, stream>>>(t0w, WkAf, HC);
    }

    // ---- GAT transforms: dual-output GEMM (mode 5; xr padded when fused0) ----
    gemm_tf<1, true><<<dim3((HC + 63) / 64, (NN + 63) / 64), 256, 0, stream>>>(
        xb, Wlb, Wrb, bl, br, nullptr, nullptr, (const bf*)xrb, HC,
        xlb, nullptr, HC, NN, HC, F_IN, 1, 5, fused0 ? 1 : 0, 0, nn, F_IN);

    // ---- fused GAT (+TCN block 0 when fused0) ----
    if (fused0)
        gat_fused4<1><<<NG, 256, 0, stream>>>(ei, xlb, xrb, att, gb,
                                              WkAf, t0b, l0w, l0b,
                                              y0, dalpha, dei, E0, ET, EPG, nn);
    else {
        gat_fused4<0><<<NG, 256, 0, stream>>>(ei, xlb, xrb, att, gb,
                                              nullptr, nullptr, nullptr, nullptr,
                                              hbuf, dalpha, dei, E0, ET, EPG, nn);
        // fallback TCN block 0
        gemm_tf<3, false><<<dim3((HC + 63) / 64, NG * 32 / 64), 256, 0, stream>>>(
            hbuf, WkA, nullptr, t0b, nullptr, l0w, l0b, hbuf, HC,
            y0, nullptr, HC, NG * 32, HC, HC, 1, 2, 0, 1, nn, HC);
    }

    // ---- TCN blocks 1 & 2, two graph-chunks ----
    for (int c = 0; c < 2; ++c) {
        int g0 = c * NG2;
        int gc = (c == 0) ? NG2 : (NG - NG2);
        if (gc <= 0) continue;
        const bf* y0c = y0 + (size_t)g0 * 32 * HC;
        bf*       y2c = y0 + (size_t)g0 * 32 * HC;
        if (fastc) {
            gemm_tcn<3, true><<<dim3(C1 / 64, gc * 32 / 256), 256, 0, stream>>>(
                y0c, WkB, d1wb, t1b, d1b, l1w, l1b, nullptr, 0,
                y1c, C1, gc * 32, C1, HC, 2, nn);
            gemm_tcn<3, true><<<dim3(C2 / 64, gc * 32 / 256), 256, 0, stream>>>(
                y1c, WkC, d2wb, t2b, d2b, l2w, l2b, nullptr, 0,
                y2c, C2, gc * 32, C2, C1, 4, nn);
        } else {
            gemm_tf<3, true><<<dim3((C1 + 63) / 64, gc * 32 / 64), 256, 0, stream>>>(
                y0c, WkB, d1wb, t1b, d1b, l1w, l1b, nullptr, 0,
                y1c, nullptr, C1, gc * 32, C1, HC, 2, 2, 0, 1, nn, HC);
            gemm_tf<3, true><<<dim3((C2 + 63) / 64, gc * 32 / 64), 256, 0, stream>>>(
                y1c, WkC, d2wb, t2b, d2b, l2w, l2b, nullptr, 0,
                y2c, nullptr, C2, gc * 32, C2, C1, 4, 2, 0, 1, nn, C1);
        }
    }

    // ---- FC head ----
    prep_fc1<<<(F1 * 32 * HC + 255) / 256, 256, 0, stream>>>(f1w, W1t, F1, nn, HC);
    gemm_tf<1, false><<<dim3((F1 + 63) / 64, (NG + 63) / 64, 8), 256, 0, stream>>>(
        y0, W1t, nullptr, nullptr, nullptr, nullptr, nullptr, nullptr, 0,
        z1p, nullptr, F1, NG, F1, 32 * HC, 1, 3, 0, 0, nn, 4 * HC);
    fc1red<<<(NG * F1 + 255) / 256, 256, 0, stream>>>(z1p, f1b, z1, NG * F1, F1, 8);

    gemm_tf<1, false><<<dim3((F2 + 63) / 64, (NG + 63) / 64), 256, 0, stream>>>(
        z1, f2wb, nullptr, f2b, nullptr, nullptr, nullptr, nullptr, 0,
        z2, nullptr, F2, NG, F2, F1, 1, 0, 1, 0, nn, F1);
    gemm_tf<1, false><<<dim3((F3 + 63) / 64, (NG + 63) / 64), 256, 0, stream>>>(
        z2, f3wb, nullptr, f3b, nullptr, nullptr, nullptr, nullptr, 0,
        nullptr, dout, F3, NG, F3, F2, 1, 0, 0, 0, nn, F2);
}

// Round 8
// 496.537 us; speedup vs baseline: 1.0777x; 1.0044x over previous
//
#include <hip/hip_runtime.h>
#include <hip/hip_bf16.h>

typedef __bf16  bf16x8 __attribute__((ext_vector_type(8)));
typedef __bf16  bf16x4 __attribute__((ext_vector_type(4)));
typedef float   f32x4  __attribute__((ext_vector_type(4)));
typedef __hip_bfloat16 bf;

__device__ __forceinline__ float clamp256(float v) {
    return fminf(fmaxf(v, -256.f), 256.f);
}
__device__ __forceinline__ float sane(float v) {
    return fminf(fmaxf(v, -1e4f), 1e4f);
}
// 16B-chunk XOR swizzle baked into weight layout: spreads B-tile rows over
// 8 LDS bank-groups (2-way = free) while keeping global_load_lds linear.
__device__ __forceinline__ int swzk(int k, int col) {
    return (k & ~31) | ((((k >> 3) & 3) ^ ((col >> 1) & 3)) << 3) | (k & 7);
}

// ---------------------------------------------------------------------------
// Tap-fused, register-prefetch 64x64 bf16 MFMA GEMM (GAT + FC head + fallback).
// mode 0: store (+bias,relu) -> outb bf16 or outf f32
// mode 2: register-resident LayerNorm(nn)+relu+residual (accR/Wd or res[])
// mode 3: split-K bf16 partials: outb[z*M*ostride + row*ostride + col]
// mode 5: dual output (HASWD): outb=accC+bias, res(cast bf*)=accR+biasd
//         relu!=0 => out2 rows padded per-graph: orow=(row/nn)*32+row%nn
// NOTE: expects UNSWIZZLED weights.
// ---------------------------------------------------------------------------
template<int TAPS, bool HASWD>
__global__ __launch_bounds__(256) void gemm_tf(
    const bf* __restrict__ A, const bf* __restrict__ Wt, const bf* __restrict__ Wd,
    const float* __restrict__ bias, const float* __restrict__ biasd,
    const float* __restrict__ lnw, const float* __restrict__ lnb,
    const bf* __restrict__ res, int res_stride,
    bf* __restrict__ outb, float* __restrict__ outf, int out_stride,
    int M, int N, int K, int dil, int mode, int relu, int padded, int nn, int kLen)
{
    constexpr int NT = TAPS + (HASWD ? 1 : 0);
    __shared__ __align__(16) unsigned short sA[66 * 40];      // 64 rows + zero row 64
    __shared__ __align__(16) unsigned short sB[NT][64 * 40];
    __shared__ float sS[4][64], sS2[4][64];

    const int tid  = threadIdx.x;
    const int wv   = tid >> 6;
    const int lane = tid & 63;
    const int m0   = blockIdx.y * 64;
    const int n0   = blockIdx.x * 64;
    const int frow = lane & 15;
    const int fq   = lane >> 4;
    const int kOff = blockIdx.z * kLen;
    const int kEnd = (kOff + kLen < K) ? (kOff + kLen) : K;

    if (tid < 40) sA[64 * 40 + tid] = (unsigned short)0;

    int aoff[NT];
    {
        int token = wv * 16 + frow;
        int b = token >> 5, l = token & 31;
        #pragma unroll
        for (int t = 0; t < NT; ++t) {
            int s = (t < TAPS) ? (t - TAPS / 2) * dil : 0;
            int ar;
            if (padded) {
                int ls = l + s;
                ar = ((unsigned)ls < 32u) ? (b * 32 + ls) : 64;
            } else {
                ar = token;
            }
            aoff[t] = ar * 40 + fq * 8;
        }
    }

    const int srow = tid >> 2;
    const int schk = (tid & 3) << 3;
    int raG = m0 + srow;
    if (!padded && raG >= M) raG = -1;
    const int rbG  = n0 + srow;
    const bool bval = rbG < N;
    const bf* Ap = (raG >= 0) ? (A + (size_t)raG * K) : nullptr;
    const bf* Bp[NT];
    #pragma unroll
    for (int t = 0; t < NT; ++t)
        Bp[t] = (HASWD && t == TAPS) ? (Wd + (size_t)rbG * K)
                                     : (Wt + ((size_t)t * N + rbG) * K);

    f32x4 accC[4], accR[4];
    #pragma unroll
    for (int i = 0; i < 4; ++i) { accC[i] = 0.f; accR[i] = 0.f; }

    const uint4 zu = make_uint4(0u, 0u, 0u, 0u);
    uint4 pa, pb[NT];
    pa = Ap ? *(const uint4*)(Ap + kOff + schk) : zu;
    #pragma unroll
    for (int t = 0; t < NT; ++t)
        pb[t] = bval ? *(const uint4*)(Bp[t] + kOff + schk) : zu;

    for (int kb = kOff; kb < kEnd; kb += 32) {
        __syncthreads();
        *(uint4*)(sA + srow * 40 + schk) = pa;
        #pragma unroll
        for (int t = 0; t < NT; ++t)
            *(uint4*)(&sB[t][srow * 40 + schk]) = pb[t];
        __syncthreads();
        int kn = kb + 32;
        if (kn < kEnd) {
            pa = Ap ? *(const uint4*)(Ap + kn + schk) : zu;
            #pragma unroll
            for (int t = 0; t < NT; ++t)
                pb[t] = bval ? *(const uint4*)(Bp[t] + kn + schk) : zu;
        }
        #pragma unroll
        for (int t = 0; t < TAPS; ++t) {
            bf16x8 af = *(const bf16x8*)(sA + aoff[t]);
            #pragma unroll
            for (int nt = 0; nt < 4; ++nt) {
                bf16x8 bg = *(const bf16x8*)(&sB[t][(nt * 16 + frow) * 40 + fq * 8]);
                accC[nt] = __builtin_amdgcn_mfma_f32_16x16x32_bf16(af, bg, accC[nt], 0, 0, 0);
            }
        }
        if constexpr (HASWD) {
            bf16x8 af = *(const bf16x8*)(sA + aoff[TAPS]);
            #pragma unroll
            for (int nt = 0; nt < 4; ++nt) {
                bf16x8 bg = *(const bf16x8*)(&sB[TAPS][(nt * 16 + frow) * 40 + fq * 8]);
                accR[nt] = __builtin_amdgcn_mfma_f32_16x16x32_bf16(af, bg, accR[nt], 0, 0, 0);
            }
        }
    }

    if (mode == 0) {
        #pragma unroll
        for (int nt = 0; nt < 4; ++nt) {
            int col = n0 + nt * 16 + frow;
            if (col >= N) continue;
            float bv = bias ? bias[col] : 0.f;
            #pragma unroll
            for (int r = 0; r < 4; ++r) {
                int row = m0 + wv * 16 + fq * 4 + r;
                if (row >= M) continue;
                float v = accC[nt][r] + bv;
                if (relu) v = fmaxf(v, 0.f);
                if (outb) outb[(size_t)row * out_stride + col] = __float2bfloat16(clamp256(v));
                else      outf[(size_t)row * out_stride + col] = sane(v);
            }
        }
    } else if (mode == 3) {
        bf* po = outb + (size_t)blockIdx.z * M * out_stride;
        #pragma unroll
        for (int nt = 0; nt < 4; ++nt) {
            int col = n0 + nt * 16 + frow;
            if (col >= N) continue;
            #pragma unroll
            for (int r = 0; r < 4; ++r) {
                int row = m0 + wv * 16 + fq * 4 + r;
                if (row >= M) continue;
                po[(size_t)row * out_stride + col] = __float2bfloat16(accC[nt][r]);
            }
        }
    } else if (mode == 5) {
        if constexpr (HASWD) {
            bf* out2 = (bf*)res;
            // hoist padded-row mapping: 4 divisions instead of 16
            int orow_[4];
            #pragma unroll
            for (int r = 0; r < 4; ++r) {
                int row = m0 + wv * 16 + fq * 4 + r;
                orow_[r] = relu ? ((row / nn) * 32 + (row % nn)) : row;
            }
            #pragma unroll
            for (int nt = 0; nt < 4; ++nt) {
                int col = n0 + nt * 16 + frow;
                if (col >= N) continue;
                float bv = bias[col], bd = biasd[col];
                #pragma unroll
                for (int r = 0; r < 4; ++r) {
                    int row = m0 + wv * 16 + fq * 4 + r;
                    if (row >= M) continue;
                    outb[(size_t)row * out_stride + col] = __float2bfloat16(clamp256(accC[nt][r] + bv));
                    out2[(size_t)orow_[r] * res_stride + col] = __float2bfloat16(clamp256(accR[nt][r] + bd));
                }
            }
        }
    } else {  // mode 2
        float bvc[4], bdc[4];
        #pragma unroll
        for (int nt = 0; nt < 4; ++nt) {
            int col = n0 + nt * 16 + frow;
            bvc[nt] = bias[col];
            bdc[nt] = (HASWD && biasd) ? biasd[col] : 0.f;
        }
        float s[4], s2[4];
        #pragma unroll
        for (int nt = 0; nt < 4; ++nt) { s[nt] = 0.f; s2[nt] = 0.f; }
        #pragma unroll
        for (int nt = 0; nt < 4; ++nt)
            #pragma unroll
            for (int r = 0; r < 4; ++r) {
                int row = wv * 16 + fq * 4 + r;
                int l = row & 31;
                float v = sane(accC[nt][r] + bvc[nt]);
                if (l < nn) { s[nt] += v; s2[nt] += v * v; }
            }
        #pragma unroll
        for (int nt = 0; nt < 4; ++nt) {
            s[nt]  += __shfl_xor(s[nt], 16);  s[nt]  += __shfl_xor(s[nt], 32);
            s2[nt] += __shfl_xor(s2[nt], 16); s2[nt] += __shfl_xor(s2[nt], 32);
        }
        if (fq == 0) {
            #pragma unroll
            for (int nt = 0; nt < 4; ++nt) {
                sS[wv][nt * 16 + frow]  = s[nt];
                sS2[wv][nt * 16 + frow] = s2[nt];
            }
        }
        __syncthreads();
        const int gi = wv >> 1;
        const float inv = 1.f / (float)nn;
        #pragma unroll
        for (int nt = 0; nt < 4; ++nt) {
            int c = nt * 16 + frow;
            int colg = n0 + c;
            float S  = sS[2 * gi][c]  + sS[2 * gi + 1][c];
            float S2 = sS2[2 * gi][c] + sS2[2 * gi + 1][c];
            float mu = S * inv;
            float var = S2 * inv - mu * mu;
            float rs = rsqrtf(fmaxf(var, 0.f) + 1e-5f);
            #pragma unroll
            for (int r = 0; r < 4; ++r) {
                int row = wv * 16 + fq * 4 + r;
                int l = row & 31;
                int grow = m0 + row;
                float outv = 0.f;
                if (l < nn) {
                    float v = (sane(accC[nt][r] + bvc[nt]) - mu) * rs * lnw[l] + lnb[l];
                    v = fmaxf(v, 0.f);
                    float rr;
                    if constexpr (HASWD) rr = sane(accR[nt][r] + bdc[nt]);
                    else rr = __bfloat162float(res[(size_t)grow * res_stride + colg]);
                    outv = clamp256(v + rr);
                }
                outb[(size_t)grow * out_stride + colg] = __float2bfloat16(outv);
            }
        }
    }
}

// ---------------------------------------------------------------------------
// TCN tap-fused GEMM v3 (round-4 winner, unchanged): 256x64 macro-tile,
// 64x64 per wave, B via dbuf global_load_lds DMA of pre-swizzled weights.
// ---------------------------------------------------------------------------
template<int TAPS, bool HASWD>
__global__ __launch_bounds__(256, 2) void gemm_tcn(
    const bf* __restrict__ A, const bf* __restrict__ Wt, const bf* __restrict__ Wd,
    const float* __restrict__ bias, const float* __restrict__ biasd,
    const float* __restrict__ lnw, const float* __restrict__ lnb,
    const bf* __restrict__ res, int res_stride,
    bf* __restrict__ outb, int out_stride,
    int M, int N, int K, int dil, int nn)
{
    constexpr int NT = TAPS + (HASWD ? 1 : 0);
    __shared__ __align__(16) unsigned short sA[257 * 40];
    __shared__ __align__(16) unsigned short sBall[2 * NT * 64 * 32];

    const int tid  = threadIdx.x;
    const int wv   = tid >> 6;
    const int lane = tid & 63;
    const int frow = lane & 15;
    const int fq   = lane >> 4;

    const int gx  = gridDim.x;
    const int nwg = gx * gridDim.y;
    int wg = blockIdx.y * gx + blockIdx.x;
    if ((nwg & 7) == 0) wg = (wg & 7) * (nwg >> 3) + (wg >> 3);
    const int n0 = (wg % gx) * 64;
    const int m0 = (wg / gx) * 256;

    if (tid < 40) sA[256 * 40 + tid] = (unsigned short)0;

    int aoff[TAPS][4];
    #pragma unroll
    for (int mr = 0; mr < 4; ++mr) {
        int token = wv * 64 + mr * 16 + frow;
        int b5 = token >> 5, l = token & 31;
        #pragma unroll
        for (int t = 0; t < TAPS; ++t) {
            int ls = l + (t - TAPS / 2) * dil;
            int ar = ((unsigned)ls < 32u) ? (b5 * 32 + ls) : 256;
            aoff[t][mr] = ar * 40 + fq * 8;
        }
    }
    const int bco = (fq ^ ((frow >> 1) & 3)) << 3;

    const int srow = tid >> 2;
    const int chS  = (tid & 3) << 3;
    const bf* Ap = A + (size_t)(m0 + srow) * K + chS;

    const bf* bsrc[4];
    {
        int lr = lane >> 2, lc = lane & 3;
        #pragma unroll
        for (int i = 0; i < 4; ++i) {
            int colb = n0 + i * 16 + lr;
            const bf* Wb;
            if (HASWD && wv == TAPS) Wb = Wd + (size_t)colb * K;
            else if (wv < TAPS)      Wb = Wt + ((size_t)wv * N + colb) * K;
            else                     Wb = Wt + (size_t)colb * K;
            bsrc[i] = Wb + lc * 8;
        }
    }

    f32x4 accC[4][4], accR[4][4];
    #pragma unroll
    for (int i = 0; i < 4; ++i)
        #pragma unroll
        for (int j = 0; j < 4; ++j) { accC[i][j] = 0.f; if (HASWD) accR[i][j] = 0.f; }

    #define ISSUE_B(BUFB, KBS)                                                      \
        if (wv < NT) {                                                              \
            unsigned short* bas = sBall + ((size_t)((BUFB) * NT + wv) * 64) * 32;   \
            _Pragma("unroll")                                                       \
            for (int i = 0; i < 4; ++i) {                                           \
                __builtin_amdgcn_global_load_lds(                                   \
                    (const __attribute__((address_space(1))) void*)(bsrc[i] + (KBS)), \
                    (__attribute__((address_space(3))) void*)(bas + i * 512),       \
                    16, 0, 0);                                                      \
            }                                                                       \
        }

    uint4 pa[4];
    #pragma unroll
    for (int i = 0; i < 4; ++i) pa[i] = *(const uint4*)(Ap + (size_t)i * 64 * K);
    ISSUE_B(0, 0);

    int buf = 0;
    for (int kb = 0; kb < K; kb += 32) {
        __syncthreads();
        #pragma unroll
        for (int i = 0; i < 4; ++i)
            *(uint4*)(sA + (srow + i * 64) * 40 + chS) = pa[i];
        __syncthreads();
        int kn = kb + 32;
        if (kn < K) {
            ISSUE_B(buf ^ 1, kn);
            #pragma unroll
            for (int i = 0; i < 4; ++i)
                pa[i] = *(const uint4*)(Ap + (size_t)i * 64 * K + kn);
        }
        const unsigned short* sBb = sBall + (size_t)buf * NT * 2048;
        bf16x8 aMid[4];
        #pragma unroll
        for (int mr = 0; mr < 4; ++mr)
            aMid[mr] = *(const bf16x8*)(sA + aoff[TAPS / 2][mr]);
        #pragma unroll
        for (int t = 0; t < TAPS; ++t) {
            bf16x8 af[4];
            #pragma unroll
            for (int mr = 0; mr < 4; ++mr)
                af[mr] = (t == TAPS / 2) ? aMid[mr]
                                         : *(const bf16x8*)(sA + aoff[t][mr]);
            #pragma unroll
            for (int nt = 0; nt < 4; ++nt) {
                bf16x8 bg = *(const bf16x8*)(sBb + (size_t)t * 2048 + (nt * 16 + frow) * 32 + bco);
                #pragma unroll
                for (int mr = 0; mr < 4; ++mr)
                    accC[mr][nt] = __builtin_amdgcn_mfma_f32_16x16x32_bf16(af[mr], bg, accC[mr][nt], 0, 0, 0);
            }
        }
        if constexpr (HASWD) {
            #pragma unroll
            for (int nt = 0; nt < 4; ++nt) {
                bf16x8 bg = *(const bf16x8*)(sBb + (size_t)TAPS * 2048 + (nt * 16 + frow) * 32 + bco);
                #pragma unroll
                for (int mr = 0; mr < 4; ++mr)
                    accR[mr][nt] = __builtin_amdgcn_mfma_f32_16x16x32_bf16(aMid[mr], bg, accR[mr][nt], 0, 0, 0);
            }
        }
        buf ^= 1;
    }
    #undef ISSUE_B

    float bvc[4], bdc[4];
    #pragma unroll
    for (int nt = 0; nt < 4; ++nt) {
        int col = n0 + nt * 16 + frow;
        bvc[nt] = bias[col];
        bdc[nt] = HASWD ? biasd[col] : 0.f;
    }
    float S[2][4], Q[2][4];
    #pragma unroll
    for (int h = 0; h < 2; ++h)
        #pragma unroll
        for (int nt = 0; nt < 4; ++nt) { S[h][nt] = 0.f; Q[h][nt] = 0.f; }
    #pragma unroll
    for (int mr = 0; mr < 4; ++mr) {
        const int h = mr >> 1;
        #pragma unroll
        for (int nt = 0; nt < 4; ++nt)
            #pragma unroll
            for (int r = 0; r < 4; ++r) {
                int l = (mr & 1) * 16 + fq * 4 + r;
                if (l < nn) {
                    float v = sane(accC[mr][nt][r] + bvc[nt]);
                    S[h][nt] += v; Q[h][nt] += v * v;
                }
            }
    }
    const float inv = 1.f / (float)nn;
    float mu[2][4], rsg[2][4];
    #pragma unroll
    for (int h = 0; h < 2; ++h)
        #pragma unroll
        for (int nt = 0; nt < 4; ++nt) {
            float s = S[h][nt], q = Q[h][nt];
            s += __shfl_xor(s, 16); s += __shfl_xor(s, 32);
            q += __shfl_xor(q, 16); q += __shfl_xor(q, 32);
            float m = s * inv;
            float var = q * inv - m * m;
            mu[h][nt]  = m;
            rsg[h][nt] = rsqrtf(fmaxf(var, 0.f) + 1e-5f);
        }
    float lw[2][4], lb2[2][4];
    #pragma unroll
    for (int p = 0; p < 2; ++p)
        #pragma unroll
        for (int r = 0; r < 4; ++r) {
            int l = p * 16 + fq * 4 + r;
            bool ok = l < nn;
            lw[p][r]  = ok ? lnw[l] : 0.f;
            lb2[p][r] = ok ? lnb[l] : 0.f;
        }
    #pragma unroll
    for (int nt = 0; nt < 4; ++nt) {
        const int colg = n0 + nt * 16 + frow;
        #pragma unroll
        for (int mr = 0; mr < 4; ++mr) {
            const int h = mr >> 1, p = mr & 1;
            #pragma unroll
            for (int r = 0; r < 4; ++r) {
                int l = p * 16 + fq * 4 + r;
                int grow = m0 + wv * 64 + mr * 16 + fq * 4 + r;
                float outv = 0.f;
                if (l < nn) {
                    float v = (sane(accC[mr][nt][r] + bvc[nt]) - mu[h][nt]) * rsg[h][nt] * lw[p][r] + lb2[p][r];
                    v = fmaxf(v, 0.f);
                    float rr;
                    if constexpr (HASWD) rr = sane(accR[mr][nt][r] + bdc[nt]);
                    else rr = __bfloat162float(res[(size_t)grow * res_stride + colg]);
                    outv = clamp256(v + rr);
                }
                outb[(size_t)grow * out_stride + colg] = __float2bfloat16(outv);
            }
        }
    }
}

// ---------------------------------------------------------------------------
// Fused per-graph GAT v5: MFMA aggregation via dense-P scatter.
//   Phase 1: wave-per-edge scores -> sExp (unchanged).
//   Phase 2: scatter exp into dense P[4][32][33] f32 (ds_add_f32, folds
//     duplicate edges exactly like segment_sum) -> row sums (den) ->
//     alpha echo (exact f32) -> normalize to bf16 Pb[4][32][40] ->
//     wave-per-head MFMA: agg_h = Pn_h @ XL_h (8 MFMAs/wave) -> H.
//   Deletes the CSR build (histogram/scan/scatter) and the serial edge walks.
// CONV=1 additionally fuses TCN block 0 (phase 3) as in v4.
// LDS 39976 B -> 4 blocks/CU.
// ---------------------------------------------------------------------------
#define MAXNE 270
#define XLS   260   // padded XL row stride (channels)
#define SHP   264   // padded H row stride (channels)
template<int CONV>
__global__ __launch_bounds__(256, 4) void gat_fused5(
    const int* __restrict__ ei, const bf* __restrict__ xlb, const bf* __restrict__ xrb,
    const float* __restrict__ att, const float* __restrict__ gbias,
    const bf* __restrict__ Wf, const float* __restrict__ cbias,
    const float* __restrict__ lnw, const float* __restrict__ lnb,
    bf* __restrict__ yout, float* __restrict__ dalpha, float* __restrict__ dei,
    int E0, int ET, int EPG, int nn)
{
    __shared__ __align__(16) __bf16 sXL[32 * XLS];   // 16.25 KB (padded rows)
    // sPH: phase 0/1 = XR (bf16, stride 256, rows 0..31); phase 2 = P f32
    // [4][32][33] (16896 B = exactly rows 0..31) then Pb bf16 [4][32][40]
    // (10240 B); phase 2f..3 = H (bf16, stride SHP) + zero row 32 (bytes
    // 16896..17423, untouched by P/Pb).
    __shared__ __align__(16) float sPH[(33 * SHP) / 2];   // 17424 B
    __shared__ float sExp[MAXNE * 4];                // 4.2 KB
    __shared__ int   sSD[MAXNE];                     // src | dst<<16
    __shared__ float sDen[128];                      // [h*32+dst]

    const int g = blockIdx.x, tid = threadIdx.x, wv = tid >> 6, lane = tid & 63;
    if (EPG + nn > MAXNE) return;
    const int NE = EPG + nn;
    __bf16* sHX = (__bf16*)sPH;
    __bf16* Pb  = (__bf16*)sPH;                      // [4][32][40] bf16

    // Phase 0a: edges + self loops; stage xl/xr; zero tail rows
    for (int k = tid; k < EPG; k += 256) {
        int s = ei[(size_t)g * EPG + k] - g * nn;
        int d = ei[(size_t)E0 + (size_t)g * EPG + k] - g * nn;
        s = min(max(s, 0), nn - 1);
        d = min(max(d, 0), nn - 1);
        sSD[k] = s | (d << 16);
    }
    for (int k = EPG + tid; k < NE; k += 256) {
        int node = k - EPG;
        sSD[k] = node | (node << 16);
    }
    {
        const uint4* gxl = (const uint4*)(xlb + (size_t)g * nn * 256);
        const uint4* gxr = (const uint4*)(xrb + (size_t)g * (CONV ? 32 : nn) * 256);
        for (int k = tid; k < nn * 32; k += 256) {
            int node = k >> 5, c8 = k & 31;
            *(uint4*)(sXL + node * XLS + c8 * 8) = gxl[k];
            *(uint4*)(sHX + k * 8) = gxr[k];                 // XR layout, stride 256
        }
        // zero XL rows nn..31: MFMA K=32 reads them (0 * garbage could be NaN)
        const uint4 zu = make_uint4(0u, 0u, 0u, 0u);
        for (int k = nn * 32 + tid; k < 32 * 32; k += 256)
            *(uint4*)(sXL + (k >> 5) * XLS + (k & 31) * 8) = zu;
    }
    if (CONV) { __bf16 z = (__bf16)0.f; for (int k = tid; k < SHP; k += 256) sHX[32 * SHP + k] = z; }
    __syncthreads();

    // ei echo
    for (int k = tid; k < NE; k += 256) {
        int s, d; size_t eg;
        if (k < EPG) {
            int sd = sSD[k];
            s = g * nn + (sd & 0xffff); d = g * nn + (sd >> 16);
            eg = (size_t)g * EPG + k;
        }
        else { int node = g * nn + (k - EPG); s = d = node; eg = (size_t)E0 + (size_t)g * nn + (k - EPG); }
        dei[eg] = (float)s;
        dei[(size_t)ET + eg] = (float)d;
    }

    // Phase 1: wave-per-edge scores (reads XR from sHX, stride 256)
    const float4 attv = *(const float4*)(att + lane * 4);
    const int h4 = lane >> 4;
    for (int i = wv; i < NE; i += 4) {
        int sd = sSD[i];
        int srcl = sd & 0xffff, dstl = sd >> 16;
        bf16x4 a = *(const bf16x4*)(sXL + srcl * XLS + lane * 4);
        bf16x4 b = *(const bf16x4*)(sHX + dstl * 256 + lane * 4);
        float p = 0.f;
        {
            float v0 = (float)a[0] + (float)b[0]; v0 = v0 > 0.f ? v0 : 0.2f * v0; p += v0 * attv.x;
            float v1 = (float)a[1] + (float)b[1]; v1 = v1 > 0.f ? v1 : 0.2f * v1; p += v1 * attv.y;
            float v2 = (float)a[2] + (float)b[2]; v2 = v2 > 0.f ? v2 : 0.2f * v2; p += v2 * attv.z;
            float v3 = (float)a[3] + (float)b[3]; v3 = v3 > 0.f ? v3 : 0.2f * v3; p += v3 * attv.w;
        }
        p += __shfl_xor(p, 1); p += __shfl_xor(p, 2);
        p += __shfl_xor(p, 4); p += __shfl_xor(p, 8);
        if ((lane & 15) == 0)
            sExp[i * 4 + h4] = __expf(fminf(fmaxf(p, -60.f), 60.f));
    }
    __syncthreads();

    // Phase 2a: zero P (XR is dead now). P[h][d][s] = sPH[(h*32+d)*33 + s]
    for (int k = tid; k < 4 * 32 * 33; k += 256) sPH[k] = 0.f;
    __syncthreads();

    // Phase 2b: dense scatter (ds_add_f32; duplicates fold like segment_sum)
    for (int k = tid; k < NE; k += 256) {
        int sd = sSD[k];
        int s = sd & 0xffff, d = sd >> 16;
        int base = d * 33 + s;
        #pragma unroll
        for (int h = 0; h < 4; ++h)
            atomicAdd(&sPH[h * 1056 + base], sExp[k * 4 + h]);
    }
    __syncthreads();

    // Phase 2c: row sums -> sDen; keep this thread's 16 P values in regs
    const int prow = tid >> 1;       // 0..127 = h*32+dst
    const int phalf = tid & 1;
    float pv[16];
    {
        const float* pr = sPH + prow * 33 + phalf * 16;
        #pragma unroll
        for (int j = 0; j < 16; ++j) pv[j] = pr[j];
        float ssum = 0.f;
        #pragma unroll
        for (int j = 0; j < 16; ++j) ssum += pv[j];
        ssum += __shfl_xor(ssum, 1);
        if (!phalf) sDen[prow] = ssum;
    }
    __syncthreads();

    // Phase 2d: alpha echo (exact f32) + normalized bf16 Pb write
    for (int k = tid; k < NE; k += 256) {
        int d = sSD[k] >> 16;
        size_t eg = (k < EPG) ? ((size_t)g * EPG + k)
                              : ((size_t)E0 + (size_t)g * nn + (k - EPG));
        #pragma unroll
        for (int h = 0; h < 4; ++h) {
            float rd = 1.f / fmaxf(sDen[h * 32 + d], 1e-30f);
            dalpha[eg * 4 + h] = fminf(fmaxf(sExp[k * 4 + h] * rd, 0.f), 1.f);
        }
    }
    {
        float rd = 1.f / fmaxf(sDen[prow], 1e-30f);
        bf16x8 w0, w1;
        #pragma unroll
        for (int j = 0; j < 8; ++j) w0[j] = (__bf16)(pv[j] * rd);
        #pragma unroll
        for (int j = 0; j < 8; ++j) w1[j] = (__bf16)(pv[8 + j] * rd);
        __bf16* pw = Pb + prow * 40 + phalf * 16;
        *(bf16x8*)(pw)     = w0;
        *(bf16x8*)(pw + 8) = w1;
    }
    __syncthreads();

    // Phase 2e: MFMA aggregation, wave wv = head wv. agg_h = Pn_h @ XL_h
    const int frow = lane & 15;
    const int fq   = lane >> 4;
    f32x4 hacc[2][4];
    #pragma unroll
    for (int dt = 0; dt < 2; ++dt)
        #pragma unroll
        for (int ct = 0; ct < 4; ++ct) hacc[dt][ct] = 0.f;
    {
        bf16x8 afr[2];
        #pragma unroll
        for (int dt = 0; dt < 2; ++dt)
            afr[dt] = *(const bf16x8*)(Pb + (wv * 32 + dt * 16 + frow) * 40 + fq * 8);
        #pragma unroll
        for (int ct = 0; ct < 4; ++ct) {
            const int chc = wv * 64 + ct * 16 + frow;
            bf16x8 bfr;
            #pragma unroll
            for (int s2 = 0; s2 < 8; ++s2)
                bfr[s2] = sXL[(fq * 8 + s2) * XLS + chc];
            hacc[0][ct] = __builtin_amdgcn_mfma_f32_16x16x32_bf16(afr[0], bfr, hacc[0][ct], 0, 0, 0);
            hacc[1][ct] = __builtin_amdgcn_mfma_f32_16x16x32_bf16(afr[1], bfr, hacc[1][ct], 0, 0, 0);
        }
    }
    __syncthreads();   // all Pb reads complete before H overwrites the region

    // Phase 2f: H = relu(agg + gbias), clamp; rows >= nn zeroed
    #pragma unroll
    for (int ct = 0; ct < 4; ++ct) {
        const int ch = wv * 64 + ct * 16 + frow;
        const float gb = gbias[ch];
        #pragma unroll
        for (int dt = 0; dt < 2; ++dt)
            #pragma unroll
            for (int r = 0; r < 4; ++r) {
                int d = dt * 16 + fq * 4 + r;
                float v = (d < nn) ? clamp256(fmaxf(hacc[dt][ct][r] + gb, 0.f)) : 0.f;
                if constexpr (CONV) sHX[d * SHP + ch] = (__bf16)v;
                else yout[((size_t)g * 32 + d) * 256 + ch] = __float2bfloat16(v);
            }
    }

    // Phase 3 (CONV): y0 = relu(LN(conv3(h))) + h, per-wave 64 cols via MFMA
    if constexpr (CONV) {
        __syncthreads();
        const int colw = wv * 64;
        f32x4 c0[2][4];
        #pragma unroll
        for (int i = 0; i < 2; ++i)
            #pragma unroll
            for (int j = 0; j < 4; ++j) c0[i][j] = 0.f;

        #pragma unroll
        for (int kc = 0; kc < 8; ++kc) {
            bf16x8 af[3][2];
            #pragma unroll
            for (int t = 0; t < 3; ++t)
                #pragma unroll
                for (int mr = 0; mr < 2; ++mr) {
                    int l = mr * 16 + frow + t - 1;
                    int ar = ((unsigned)l < 32u) ? l : 32;
                    af[t][mr] = *(const bf16x8*)(sHX + ar * SHP + kc * 32 + fq * 8);
                }
            #pragma unroll
            for (int t = 0; t < 3; ++t) {
                bf16x8 bgs[4];
                #pragma unroll
                for (int nt = 0; nt < 4; ++nt) {
                    const __bf16* bp = (const __bf16*)Wf +
                        ((((size_t)(t * 16 + (colw >> 4) + nt) * 8 + kc) * 16 + frow) * 4 + fq) * 8;
                    bgs[nt] = *(const bf16x8*)bp;
                }
                #pragma unroll
                for (int nt = 0; nt < 4; ++nt) {
                    c0[0][nt] = __builtin_amdgcn_mfma_f32_16x16x32_bf16(af[t][0], bgs[nt], c0[0][nt], 0, 0, 0);
                    c0[1][nt] = __builtin_amdgcn_mfma_f32_16x16x32_bf16(af[t][1], bgs[nt], c0[1][nt], 0, 0, 0);
                }
            }
        }

        float bv[4];
        #pragma unroll
        for (int nt = 0; nt < 4; ++nt) bv[nt] = cbias[colw + nt * 16 + frow];
        float S[4], Q[4];
        #pragma unroll
        for (int nt = 0; nt < 4; ++nt) { S[nt] = 0.f; Q[nt] = 0.f; }
        #pragma unroll
        for (int mr = 0; mr < 2; ++mr)
            #pragma unroll
            for (int nt = 0; nt < 4; ++nt)
                #pragma unroll
                for (int r = 0; r < 4; ++r) {
                    int l = mr * 16 + fq * 4 + r;
                    if (l < nn) {
                        float v = sane(c0[mr][nt][r] + bv[nt]);
                        S[nt] += v; Q[nt] += v * v;
                    }
                }
        const float inv = 1.f / (float)nn;
        float mu[4], rsg[4];
        #pragma unroll
        for (int nt = 0; nt < 4; ++nt) {
            float s = S[nt], q = Q[nt];
            s += __shfl_xor(s, 16); s += __shfl_xor(s, 32);
            q += __shfl_xor(q, 16); q += __shfl_xor(q, 32);
            float m = s * inv;
            float var = q * inv - m * m;
            mu[nt]  = m;
            rsg[nt] = rsqrtf(fmaxf(var, 0.f) + 1e-5f);
        }
        float lw[2][4], lb2[2][4];
        #pragma unroll
        for (int p = 0; p < 2; ++p)
            #pragma unroll
            for (int r = 0; r < 4; ++r) {
                int l = p * 16 + fq * 4 + r;
                bool ok = l < nn;
                lw[p][r]  = ok ? lnw[l] : 0.f;
                lb2[p][r] = ok ? lnb[l] : 0.f;
            }
        #pragma unroll
        for (int nt = 0; nt < 4; ++nt) {
            const int colf = colw + nt * 16 + frow;
            #pragma unroll
            for (int mr = 0; mr < 2; ++mr)
                #pragma unroll
                for (int r = 0; r < 4; ++r) {
                    int l = mr * 16 + fq * 4 + r;
                    float outv = 0.f;
                    if (l < nn) {
                        float v = (sane(c0[mr][nt][r] + bv[nt]) - mu[nt]) * rsg[nt] * lw[mr][r] + lb2[mr][r];
                        v = fmaxf(v, 0.f);
                        float rr = (float)sHX[l * SHP + colf];
                        outv = clamp256(v + rr);
                    }
                    yout[((size_t)g * 32 + l) * 256 + colf] = __float2bfloat16(outv);
                }
        }
    }
}

// ---- fused weight prep ----
struct CvtSegs { const float* in[7]; bf* out[7]; int n[7]; };
__global__ void prep_cvt(CvtSegs s, int total)
{
    int idx = blockIdx.x * 256 + threadIdx.x;
    if (idx >= total) return;
    #pragma unroll
    for (int i = 0; i < 7; ++i) {
        if (idx < s.n[i]) { s.out[i][idx] = __float2bfloat16(s.in[i][idx]); return; }
        idx -= s.n[i];
    }
}
// taps, optionally swizzled for gemm_tcn's global_load_lds path
struct TapSegs { const float* w[3]; bf* o[3]; int cc[3]; int kk[3]; int swz[3]; };
__global__ void prep_taps3(TapSegs s, int total)
{
    int idx = blockIdx.x * 256 + threadIdx.x;
    if (idx >= total) return;
    #pragma unroll
    for (int i = 0; i < 3; ++i) {
        if (idx < s.cc[i]) {
            unsigned K = (unsigned)s.kk[i];
            unsigned co = (unsigned)idx / K, ci = (unsigned)idx % K;
            int dst = co * K + (s.swz[i] ? swzk(ci, co) : ci);
            #pragma unroll
            for (int k = 0; k < 3; ++k)
                s.o[i][(size_t)k * s.cc[i] + dst] = __float2bfloat16(s.w[i][(size_t)idx * 3 + k]);
            return;
        }
        idx -= s.cc[i];
    }
}
// downsample weights, optionally swizzled
__global__ void prep_wswz(const float* __restrict__ w, bf* __restrict__ o,
                          int total, int K, int swz)
{
    int idx = blockIdx.x * 256 + threadIdx.x;
    if (idx >= total) return;
    int co = idx / K, ci = idx % K;
    o[(size_t)co * K + (swz ? swzk(ci, co) : ci)] = __float2bfloat16(w[idx]);
}
// conv0 weights -> MFMA-fragment-contiguous layout (coalesced 1KB wave loads)
__global__ void prep_bfrag(const float* __restrict__ w, bf* __restrict__ o, int HC)
{
    int idx = blockIdx.x * 256 + threadIdx.x;
    if (idx >= HC * HC) return;
    int co = idx / HC, ci = idx % HC;
    int cg = co >> 4, fr = co & 15, kc = ci >> 5, fq = (ci >> 3) & 3, w8 = ci & 7;
    int NCg = HC >> 4, NKc = HC >> 5;
    #pragma unroll
    for (int t = 0; t < 3; ++t) {
        size_t dst = (((((size_t)t * NCg + cg) * NKc + kc) * 16 + fr) * 4 + fq) * 8 + w8;
        o[dst] = __float2bfloat16(w[(size_t)idx * 3 + t]);
    }
}

// fc1_w f32 [F1][ci*nn+l] -> bf16 W1t [F1][l*HC+ci], l padded to 32
__global__ void prep_fc1(const float* __restrict__ w, bf* __restrict__ o, int F1, int nn, int HC)
{
    int idx = blockIdx.x * 256 + threadIdx.x;
    int kw = 32 * HC;
    if (idx >= F1 * kw) return;
    int co = idx / kw, r = idx % kw, l = r / HC, ci = r % HC;
    float hv = 0.f;
    if (l < nn) hv = w[(size_t)co * (HC * nn) + ci * nn + l];
    o[idx] = __float2bfloat16(hv);
}

// fc1 split-K reduce: z1 = bf16(relu(sum_z partials + bias))
__global__ void fc1red(const bf* __restrict__ zp, const float* __restrict__ bias,
                       bf* __restrict__ o, int MN, int N, int S)
{
    int idx = blockIdx.x * 256 + threadIdx.x;
    if (idx >= MN) return;
    float s = 0.f;
    for (int z = 0; z < S; ++z) s += __bfloat162float(zp[(size_t)z * MN + idx]);
    o[idx] = __float2bfloat16(clamp256(fmaxf(s + bias[idx % N], 0.f)));
}

extern "C" void kernel_launch(void* const* d_in, const int* in_sizes, int n_in,
                              void* d_out, int out_size, void* d_ws, size_t ws_size,
                              hipStream_t stream)
{
    (void)n_in; (void)ws_size;
    const float* x   = (const float*)d_in[0];
    const float* Wl  = (const float*)d_in[1];  const float* bl  = (const float*)d_in[2];
    const float* Wr  = (const float*)d_in[3];  const float* br  = (const float*)d_in[4];
    const float* att = (const float*)d_in[5];  const float* gb  = (const float*)d_in[6];
    const float* t0w = (const float*)d_in[7];  const float* t0b = (const float*)d_in[8];
    const float* l0w = (const float*)d_in[9];  const float* l0b = (const float*)d_in[10];
    const float* t1w = (const float*)d_in[11]; const float* t1b = (const float*)d_in[12];
    const float* l1w = (const float*)d_in[13]; const float* l1b = (const float*)d_in[14];
    const float* d1w = (const float*)d_in[15]; const float* d1b = (const float*)d_in[16];
    const float* t2w = (const float*)d_in[17]; const float* t2b = (const float*)d_in[18];
    const float* l2w = (const float*)d_in[19]; const float* l2b = (const float*)d_in[20];
    const float* d2w = (const float*)d_in[21]; const float* d2b = (const float*)d_in[22];
    const float* f1w = (const float*)d_in[23]; const float* f1b = (const float*)d_in[24];
    const float* f2w = (const float*)d_in[25]; const float* f2b = (const float*)d_in[26];
    const float* f3w = (const float*)d_in[27]; const float* f3b = (const float*)d_in[28];
    const int*   ei  = (const int*)d_in[29];

    const int HC   = in_sizes[6];                        // 256
    const int F_IN = in_sizes[1] / (HC > 0 ? HC : 1);    // 64
    const int NN   = in_sizes[0] / (F_IN > 0 ? F_IN : 1);// 30720
    const int E0   = in_sizes[29] / 2;                   // 245760
    const int ET   = E0 + NN;                            // 276480
    int nn = in_sizes[9];  nn = nn < 1 ? 1 : (nn > 32 ? 32 : nn);  // 30
    const int NG   = NN / nn;                            // 1024
    const int EPG  = NG > 0 ? E0 / NG : 0;               // 240
    const int C1   = in_sizes[12];                       // 512
    const int C2   = in_sizes[18];                       // 256
    const int F1   = in_sizes[24];                       // 512
    const int F2   = in_sizes[26];                       // 256
    const int F3   = in_sizes[28];                       // 144
    const int NG2  = (NG + 1) / 2;

    float* dout   = (float*)d_out;
    float* dei    = dout + ((size_t)out_size - 2 * (size_t)ET);
    float* dalpha = dei - (size_t)ET * 4;

    // ---- path eligibility ----
    const bool fused0 = (HC == 256) && (nn >= 1) && (nn <= 32) && (EPG + nn <= MAXNE)
                        && ((NN % 64) == 0);
    const int  gcA = NG2, gcB = NG - NG2;
    const bool fastc = ((gcA * 32) % 256 == 0) && ((gcB * 32) % 256 == 0)
                       && (C1 % 64 == 0) && (C2 % 64 == 0)
                       && (HC % 32 == 0) && (C1 % 32 == 0);

    // ---- workspace map (42 MB):
    //  [0,4M)      xb (dead after GAT gemm) -> z1, z2
    //  [4M,7.5M)   weights (incl. WkAf frag layout)
    //  S0 [7.5,25M): fused: xrb(pad32) -> y0 -> y2 ; fallback: xrb/hbuf
    //  S1 [25,42M):  xlb -> (fused: y1c -> W1t+z1p) (fallback: y0 -> y2)
    char* ws = (char*)d_ws;
    const size_t MB = 1ull << 20;
    bf*    xb   = (bf*)(ws);
    bf*    WkA  = (bf*)(ws + 4 * MB);
    bf*    WkB  = WkA + (size_t)3 * HC * HC;
    bf*    WkC  = WkB + (size_t)3 * C1 * HC;
    bf*    Wlb  = WkC + (size_t)3 * C2 * C1;
    bf*    Wrb  = Wlb + (size_t)HC * F_IN;
    bf*    f2wb = Wrb + (size_t)HC * F_IN;
    bf*    f3wb = f2wb + (size_t)F2 * F1;
    bf*    d1wb = f3wb + (size_t)F3 * F2;
    bf*    d2wb = d1wb + (size_t)C1 * HC;
    bf*    WkAf = d2wb + (size_t)C2 * C1;                // frag-layout conv0 weights
    char*  S0   = ws + (size_t)(7.5 * MB);
    char*  S1   = ws + 25 * MB;

    bf*    xrb  = (bf*)S0;                               // padded 32 rows when fused0
    bf*    hbuf = (bf*)S0;                               // fallback GAT output
    bf*    xlb  = (bf*)S1;
    bf*    y0   = fused0 ? (bf*)S0 : (bf*)S1;
    bf*    y1c  = fused0 ? (bf*)S1 : (bf*)S0;
    char*  fcS  = fused0 ? S1 : S0;                      // FC staging region
    bf*    W1t  = (bf*)fcS;                              // 8.4 MB
    bf*    z1p  = (bf*)(fcS + (size_t)(8.5 * MB));       // 8 MB
    bf*    z1   = (bf*)(ws);                             // 1 MB (over dead xb)
    bf*    z2   = (bf*)(ws + 2 * MB);                    // 0.5 MB

    // ---- fused weight prep ----
    {
        CvtSegs cs;
        cs.in[0] = x;   cs.out[0] = xb;   cs.n[0] = NN * F_IN;
        cs.in[1] = Wl;  cs.out[1] = Wlb;  cs.n[1] = HC * F_IN;
        cs.in[2] = Wr;  cs.out[2] = Wrb;  cs.n[2] = HC * F_IN;
        cs.in[3] = f2w; cs.out[3] = f2wb; cs.n[3] = F2 * F1;
        cs.in[4] = f3w; cs.out[4] = f3wb; cs.n[4] = F3 * F2;
        cs.in[5] = nullptr; cs.out[5] = nullptr; cs.n[5] = 0;
        cs.in[6] = nullptr; cs.out[6] = nullptr; cs.n[6] = 0;
        int tot = 0; for (int i = 0; i < 5; ++i) tot += cs.n[i];
        prep_cvt<<<(tot + 255) / 256, 256, 0, stream>>>(cs, tot);
        TapSegs ts;
        ts.w[0] = t0w; ts.o[0] = WkA; ts.cc[0] = HC * HC; ts.kk[0] = HC; ts.swz[0] = 0;
        ts.w[1] = t1w; ts.o[1] = WkB; ts.cc[1] = C1 * HC; ts.kk[1] = HC; ts.swz[1] = fastc ? 1 : 0;
        ts.w[2] = t2w; ts.o[2] = WkC; ts.cc[2] = C2 * C1; ts.kk[2] = C1; ts.swz[2] = fastc ? 1 : 0;
        int tt = ts.cc[0] + ts.cc[1] + ts.cc[2];
        prep_taps3<<<(tt + 255) / 256, 256, 0, stream>>>(ts, tt);
        prep_wswz<<<(C1 * HC + 255) / 256, 256, 0, stream>>>(d1w, d1wb, C1 * HC, HC, fastc ? 1 : 0);
        prep_wswz<<<(C2 * C1 + 255) / 256, 256, 0, stream>>>(d2w, d2wb, C2 * C1, C1, fastc ? 1 : 0);
        if (fused0)
            prep_bfrag<<<(HC * HC + 255) / 256, 256, 0, stream>>>(t0w, WkAf, HC);
    }

    // ---- GAT transforms: dual-output GEMM (mode 5; xr padded when fused0) ----
    gemm_tf<1, true><<<dim3((HC + 63) / 64, (NN + 63) / 64), 256, 0, stream>>>(
        xb, Wlb, Wrb, bl, br, nullptr, nullptr, (const bf*)xrb, HC,
        xlb, nullptr, HC, NN, HC, F_IN, 1, 5, fused0 ? 1 : 0, 0, nn, F_IN);

    // ---- fused GAT (+TCN block 0 when fused0) ----
    if (fused0)
        gat_fused5<1><<<NG, 256, 0, stream>>>(ei, xlb, xrb, att, gb,
                                              WkAf, t0b, l0w, l0b,
                                              y0, dalpha, dei, E0, ET, EPG, nn);
    else {
        gat_fused5<0><<<NG, 256, 0, stream>>>(ei, xlb, xrb, att, gb,
                                              nullptr, nullptr, nullptr, nullptr,
                                              hbuf, dalpha, dei, E0, ET, EPG, nn);
        // fallback TCN block 0
        gemm_tf<3, false><<<dim3((HC + 63) / 64, NG * 32 / 64), 256, 0, stream>>>(
            hbuf, WkA, nullptr, t0b, nullptr, l0w, l0b, hbuf, HC,
            y0, nullptr, HC, NG * 32, HC, HC, 1, 2, 0, 1, nn, HC);
    }

    // ---- TCN blocks 1 & 2, two graph-chunks ----
    for (int c = 0; c < 2; ++c) {
        int g0 = c * NG2;
        int gc = (c == 0) ? NG2 : (NG - NG2);
        if (gc <= 0) continue;
        const bf* y0c = y0 + (size_t)g0 * 32 * HC;
        bf*       y2c = y0 + (size_t)g0 * 32 * HC;
        if (fastc) {
            gemm_tcn<3, true><<<dim3(C1 / 64, gc * 32 / 256), 256, 0, stream>>>(
                y0c, WkB, d1wb, t1b, d1b, l1w, l1b, nullptr, 0,
                y1c, C1, gc * 32, C1, HC, 2, nn);
            gemm_tcn<3, true><<<dim3(C2 / 64, gc * 32 / 256), 256, 0, stream>>>(
                y1c, WkC, d2wb, t2b, d2b, l2w, l2b, nullptr, 0,
                y2c, C2, gc * 32, C2, C1, 4, nn);
        } else {
            gemm_tf<3, true><<<dim3((C1 + 63) / 64, gc * 32 / 64), 256, 0, stream>>>(
                y0c, WkB, d1wb, t1b, d1b, l1w, l1b, nullptr, 0,
                y1c, nullptr, C1, gc * 32, C1, HC, 2, 2, 0, 1, nn, HC);
            gemm_tf<3, true><<<dim3((C2 + 63) / 64, gc * 32 / 64), 256, 0, stream>>>(
                y1c, WkC, d2wb, t2b, d2b, l2w, l2b, nullptr, 0,
                y2c, nullptr, C2, gc * 32, C2, C1, 4, 2, 0, 1, nn, C1);
        }
    }

    // ---- FC head ----
    prep_fc1<<<(F1 * 32 * HC + 255) / 256, 256, 0, stream>>>(f1w, W1t, F1, nn, HC);
    gemm_tf<1, false><<<dim3((F1 + 63) / 64, (NG + 63) / 64, 8), 256, 0, stream>>>(
        y0, W1t, nullptr, nullptr, nullptr, nullptr, nullptr, nullptr, 0,
        z1p, nullptr, F1, NG, F1, 32 * HC, 1, 3, 0, 0, nn, 4 * HC);
    fc1red<<<(NG * F1 + 255) / 256, 256, 0, stream>>>(z1p, f1b, z1, NG * F1, F1, 8);

    gemm_tf<1, false><<<dim3((F2 + 63) / 64, (NG + 63) / 64), 256, 0, stream>>>(
        z1, f2wb, nullptr, f2b, nullptr, nullptr, nullptr, nullptr, 0,
        z2, nullptr, F2, NG, F2, F1, 1, 0, 1, 0, nn, F1);
    gemm_tf<1, false><<<dim3((F3 + 63) / 64, (NG + 63) / 64), 256, 0, stream>>>(
        z2, f3wb, nullptr, f3b, nullptr, nullptr, nullptr, nullptr, 0,
        nullptr, dout, F3, NG, F3, F2, 1, 0, 0, 0, nn, F2);
}

// Round 9
// 454.446 us; speedup vs baseline: 1.1775x; 1.0926x over previous
//
#include <hip/hip_runtime.h>
#include <hip/hip_bf16.h>

typedef __bf16  bf16x8 __attribute__((ext_vector_type(8)));
typedef __bf16  bf16x4 __attribute__((ext_vector_type(4)));
typedef float   f32x4  __attribute__((ext_vector_type(4)));
typedef __hip_bfloat16 bf;

__device__ __forceinline__ float clamp256(float v) {
    return fminf(fmaxf(v, -256.f), 256.f);
}
__device__ __forceinline__ float sane(float v) {
    return fminf(fmaxf(v, -1e4f), 1e4f);
}
// 16B-chunk XOR swizzle baked into weight layout: spreads B-tile rows over
// 8 LDS bank-groups (2-way = free) while keeping global_load_lds linear.
__device__ __forceinline__ int swzk(int k, int col) {
    return (k & ~31) | ((((k >> 3) & 3) ^ ((col >> 1) & 3)) << 3) | (k & 7);
}

// ---------------------------------------------------------------------------
// Tap-fused, register-prefetch 64x64 bf16 MFMA GEMM (GAT + FC head + fallback).
// mode 0: store (+bias,relu) -> outb bf16 or outf f32
// mode 2: register-resident LayerNorm(nn)+relu+residual (accR/Wd or res[])
// mode 3: split-K bf16 partials: outb[z*M*ostride + row*ostride + col]
// mode 5: dual output (HASWD): outb=accC+bias, res(cast bf*)=accR+biasd
//         relu!=0 => out2 rows padded per-graph: orow=(row/nn)*32+row%nn
// NOTE: expects UNSWIZZLED weights.
// ---------------------------------------------------------------------------
template<int TAPS, bool HASWD>
__global__ __launch_bounds__(256) void gemm_tf(
    const bf* __restrict__ A, const bf* __restrict__ Wt, const bf* __restrict__ Wd,
    const float* __restrict__ bias, const float* __restrict__ biasd,
    const float* __restrict__ lnw, const float* __restrict__ lnb,
    const bf* __restrict__ res, int res_stride,
    bf* __restrict__ outb, float* __restrict__ outf, int out_stride,
    int M, int N, int K, int dil, int mode, int relu, int padded, int nn, int kLen)
{
    constexpr int NT = TAPS + (HASWD ? 1 : 0);
    __shared__ __align__(16) unsigned short sA[66 * 40];      // 64 rows + zero row 64
    __shared__ __align__(16) unsigned short sB[NT][64 * 40];
    __shared__ float sS[4][64], sS2[4][64];

    const int tid  = threadIdx.x;
    const int wv   = tid >> 6;
    const int lane = tid & 63;
    const int m0   = blockIdx.y * 64;
    const int n0   = blockIdx.x * 64;
    const int frow = lane & 15;
    const int fq   = lane >> 4;
    const int kOff = blockIdx.z * kLen;
    const int kEnd = (kOff + kLen < K) ? (kOff + kLen) : K;

    if (tid < 40) sA[64 * 40 + tid] = (unsigned short)0;

    int aoff[NT];
    {
        int token = wv * 16 + frow;
        int b = token >> 5, l = token & 31;
        #pragma unroll
        for (int t = 0; t < NT; ++t) {
            int s = (t < TAPS) ? (t - TAPS / 2) * dil : 0;
            int ar;
            if (padded) {
                int ls = l + s;
                ar = ((unsigned)ls < 32u) ? (b * 32 + ls) : 64;
            } else {
                ar = token;
            }
            aoff[t] = ar * 40 + fq * 8;
        }
    }

    const int srow = tid >> 2;
    const int schk = (tid & 3) << 3;
    int raG = m0 + srow;
    if (!padded && raG >= M) raG = -1;
    const int rbG  = n0 + srow;
    const bool bval = rbG < N;
    const bf* Ap = (raG >= 0) ? (A + (size_t)raG * K) : nullptr;
    const bf* Bp[NT];
    #pragma unroll
    for (int t = 0; t < NT; ++t)
        Bp[t] = (HASWD && t == TAPS) ? (Wd + (size_t)rbG * K)
                                     : (Wt + ((size_t)t * N + rbG) * K);

    f32x4 accC[4], accR[4];
    #pragma unroll
    for (int i = 0; i < 4; ++i) { accC[i] = 0.f; accR[i] = 0.f; }

    const uint4 zu = make_uint4(0u, 0u, 0u, 0u);
    uint4 pa, pb[NT];
    pa = Ap ? *(const uint4*)(Ap + kOff + schk) : zu;
    #pragma unroll
    for (int t = 0; t < NT; ++t)
        pb[t] = bval ? *(const uint4*)(Bp[t] + kOff + schk) : zu;

    for (int kb = kOff; kb < kEnd; kb += 32) {
        __syncthreads();
        *(uint4*)(sA + srow * 40 + schk) = pa;
        #pragma unroll
        for (int t = 0; t < NT; ++t)
            *(uint4*)(&sB[t][srow * 40 + schk]) = pb[t];
        __syncthreads();
        int kn = kb + 32;
        if (kn < kEnd) {
            pa = Ap ? *(const uint4*)(Ap + kn + schk) : zu;
            #pragma unroll
            for (int t = 0; t < NT; ++t)
                pb[t] = bval ? *(const uint4*)(Bp[t] + kn + schk) : zu;
        }
        #pragma unroll
        for (int t = 0; t < TAPS; ++t) {
            bf16x8 af = *(const bf16x8*)(sA + aoff[t]);
            #pragma unroll
            for (int nt = 0; nt < 4; ++nt) {
                bf16x8 bg = *(const bf16x8*)(&sB[t][(nt * 16 + frow) * 40 + fq * 8]);
                accC[nt] = __builtin_amdgcn_mfma_f32_16x16x32_bf16(af, bg, accC[nt], 0, 0, 0);
            }
        }
        if constexpr (HASWD) {
            bf16x8 af = *(const bf16x8*)(sA + aoff[TAPS]);
            #pragma unroll
            for (int nt = 0; nt < 4; ++nt) {
                bf16x8 bg = *(const bf16x8*)(&sB[TAPS][(nt * 16 + frow) * 40 + fq * 8]);
                accR[nt] = __builtin_amdgcn_mfma_f32_16x16x32_bf16(af, bg, accR[nt], 0, 0, 0);
            }
        }
    }

    if (mode == 0) {
        #pragma unroll
        for (int nt = 0; nt < 4; ++nt) {
            int col = n0 + nt * 16 + frow;
            if (col >= N) continue;
            float bv = bias ? bias[col] : 0.f;
            #pragma unroll
            for (int r = 0; r < 4; ++r) {
                int row = m0 + wv * 16 + fq * 4 + r;
                if (row >= M) continue;
                float v = accC[nt][r] + bv;
                if (relu) v = fmaxf(v, 0.f);
                if (outb) outb[(size_t)row * out_stride + col] = __float2bfloat16(clamp256(v));
                else      outf[(size_t)row * out_stride + col] = sane(v);
            }
        }
    } else if (mode == 3) {
        bf* po = outb + (size_t)blockIdx.z * M * out_stride;
        #pragma unroll
        for (int nt = 0; nt < 4; ++nt) {
            int col = n0 + nt * 16 + frow;
            if (col >= N) continue;
            #pragma unroll
            for (int r = 0; r < 4; ++r) {
                int row = m0 + wv * 16 + fq * 4 + r;
                if (row >= M) continue;
                po[(size_t)row * out_stride + col] = __float2bfloat16(accC[nt][r]);
            }
        }
    } else if (mode == 5) {
        if constexpr (HASWD) {
            bf* out2 = (bf*)res;
            // hoist padded-row mapping: 4 divisions instead of 16
            int orow_[4];
            #pragma unroll
            for (int r = 0; r < 4; ++r) {
                int row = m0 + wv * 16 + fq * 4 + r;
                orow_[r] = relu ? ((row / nn) * 32 + (row % nn)) : row;
            }
            #pragma unroll
            for (int nt = 0; nt < 4; ++nt) {
                int col = n0 + nt * 16 + frow;
                if (col >= N) continue;
                float bv = bias[col], bd = biasd[col];
                #pragma unroll
                for (int r = 0; r < 4; ++r) {
                    int row = m0 + wv * 16 + fq * 4 + r;
                    if (row >= M) continue;
                    outb[(size_t)row * out_stride + col] = __float2bfloat16(clamp256(accC[nt][r] + bv));
                    out2[(size_t)orow_[r] * res_stride + col] = __float2bfloat16(clamp256(accR[nt][r] + bd));
                }
            }
        }
    } else {  // mode 2
        float bvc[4], bdc[4];
        #pragma unroll
        for (int nt = 0; nt < 4; ++nt) {
            int col = n0 + nt * 16 + frow;
            bvc[nt] = bias[col];
            bdc[nt] = (HASWD && biasd) ? biasd[col] : 0.f;
        }
        float s[4], s2[4];
        #pragma unroll
        for (int nt = 0; nt < 4; ++nt) { s[nt] = 0.f; s2[nt] = 0.f; }
        #pragma unroll
        for (int nt = 0; nt < 4; ++nt)
            #pragma unroll
            for (int r = 0; r < 4; ++r) {
                int row = wv * 16 + fq * 4 + r;
                int l = row & 31;
                float v = sane(accC[nt][r] + bvc[nt]);
                if (l < nn) { s[nt] += v; s2[nt] += v * v; }
            }
        #pragma unroll
        for (int nt = 0; nt < 4; ++nt) {
            s[nt]  += __shfl_xor(s[nt], 16);  s[nt]  += __shfl_xor(s[nt], 32);
            s2[nt] += __shfl_xor(s2[nt], 16); s2[nt] += __shfl_xor(s2[nt], 32);
        }
        if (fq == 0) {
            #pragma unroll
            for (int nt = 0; nt < 4; ++nt) {
                sS[wv][nt * 16 + frow]  = s[nt];
                sS2[wv][nt * 16 + frow] = s2[nt];
            }
        }
        __syncthreads();
        const int gi = wv >> 1;
        const float inv = 1.f / (float)nn;
        #pragma unroll
        for (int nt = 0; nt < 4; ++nt) {
            int c = nt * 16 + frow;
            int colg = n0 + c;
            float S  = sS[2 * gi][c]  + sS[2 * gi + 1][c];
            float S2 = sS2[2 * gi][c] + sS2[2 * gi + 1][c];
            float mu = S * inv;
            float var = S2 * inv - mu * mu;
            float rs = rsqrtf(fmaxf(var, 0.f) + 1e-5f);
            #pragma unroll
            for (int r = 0; r < 4; ++r) {
                int row = wv * 16 + fq * 4 + r;
                int l = row & 31;
                int grow = m0 + row;
                float outv = 0.f;
                if (l < nn) {
                    float v = (sane(accC[nt][r] + bvc[nt]) - mu) * rs * lnw[l] + lnb[l];
                    v = fmaxf(v, 0.f);
                    float rr;
                    if constexpr (HASWD) rr = sane(accR[nt][r] + bdc[nt]);
                    else rr = __bfloat162float(res[(size_t)grow * res_stride + colg]);
                    outv = clamp256(v + rr);
                }
                outb[(size_t)grow * out_stride + colg] = __float2bfloat16(outv);
            }
        }
    }
}

// ---------------------------------------------------------------------------
// TCN tap-fused GEMM v4: 256x64 macro-tile, 64x64 per wave, DMA-staged B
// (pre-swizzled weights), and now DOUBLE-BUFFERED sA -> ONE barrier per
// K-step (was 2). Schedule per step: issue pa-loads + B-DMA for k+1 ->
// compute on buf (loads land under MFMA) -> write sA[buf^1] -> barrier.
// LDS 73888 B; occupancy unchanged (VGPR-limited at 2 blocks/CU).
// ---------------------------------------------------------------------------
template<int TAPS, bool HASWD>
__global__ __launch_bounds__(256, 2) void gemm_tcn(
    const bf* __restrict__ A, const bf* __restrict__ Wt, const bf* __restrict__ Wd,
    const float* __restrict__ bias, const float* __restrict__ biasd,
    const float* __restrict__ lnw, const float* __restrict__ lnb,
    const bf* __restrict__ res, int res_stride,
    bf* __restrict__ outb, int out_stride,
    int M, int N, int K, int dil, int nn)
{
    constexpr int NT = TAPS + (HASWD ? 1 : 0);
    constexpr int SA = 257 * 40;                                   // shorts per A buffer
    __shared__ __align__(16) unsigned short sA[2 * SA];            // dbuf A + zero rows
    __shared__ __align__(16) unsigned short sBall[2 * NT * 64 * 32];

    const int tid  = threadIdx.x;
    const int wv   = tid >> 6;
    const int lane = tid & 63;
    const int frow = lane & 15;
    const int fq   = lane >> 4;

    const int gx  = gridDim.x;
    const int nwg = gx * gridDim.y;
    int wg = blockIdx.y * gx + blockIdx.x;
    if ((nwg & 7) == 0) wg = (wg & 7) * (nwg >> 3) + (wg >> 3);
    const int n0 = (wg % gx) * 64;
    const int m0 = (wg / gx) * 256;

    if (tid < 40) {                                 // zero row 256 of BOTH buffers
        sA[256 * 40 + tid]      = (unsigned short)0;
        sA[SA + 256 * 40 + tid] = (unsigned short)0;
    }

    int aoff[TAPS][4];
    #pragma unroll
    for (int mr = 0; mr < 4; ++mr) {
        int token = wv * 64 + mr * 16 + frow;
        int b5 = token >> 5, l = token & 31;
        #pragma unroll
        for (int t = 0; t < TAPS; ++t) {
            int ls = l + (t - TAPS / 2) * dil;
            int ar = ((unsigned)ls < 32u) ? (b5 * 32 + ls) : 256;
            aoff[t][mr] = ar * 40 + fq * 8;
        }
    }
    const int bco = (fq ^ ((frow >> 1) & 3)) << 3;

    const int srow = tid >> 2;
    const int chS  = (tid & 3) << 3;
    const bf* Ap = A + (size_t)(m0 + srow) * K + chS;

    const bf* bsrc[4];
    {
        int lr = lane >> 2, lc = lane & 3;
        #pragma unroll
        for (int i = 0; i < 4; ++i) {
            int colb = n0 + i * 16 + lr;
            const bf* Wb;
            if (HASWD && wv == TAPS) Wb = Wd + (size_t)colb * K;
            else if (wv < TAPS)      Wb = Wt + ((size_t)wv * N + colb) * K;
            else                     Wb = Wt + (size_t)colb * K;
            bsrc[i] = Wb + lc * 8;
        }
    }

    f32x4 accC[4][4], accR[4][4];
    #pragma unroll
    for (int i = 0; i < 4; ++i)
        #pragma unroll
        for (int j = 0; j < 4; ++j) { accC[i][j] = 0.f; if (HASWD) accR[i][j] = 0.f; }

    #define ISSUE_B(BUFB, KBS)                                                      \
        if (wv < NT) {                                                              \
            unsigned short* bas = sBall + ((size_t)((BUFB) * NT + wv) * 64) * 32;   \
            _Pragma("unroll")                                                       \
            for (int i = 0; i < 4; ++i) {                                           \
                __builtin_amdgcn_global_load_lds(                                   \
                    (const __attribute__((address_space(1))) void*)(bsrc[i] + (KBS)), \
                    (__attribute__((address_space(3))) void*)(bas + i * 512),       \
                    16, 0, 0);                                                      \
            }                                                                       \
        }

    // prologue: stage step 0 (A regs -> sA[0]; B via DMA -> sB[0])
    uint4 pa[4];
    #pragma unroll
    for (int i = 0; i < 4; ++i) pa[i] = *(const uint4*)(Ap + (size_t)i * 64 * K);
    ISSUE_B(0, 0);
    #pragma unroll
    for (int i = 0; i < 4; ++i)
        *(uint4*)(sA + (srow + i * 64) * 40 + chS) = pa[i];
    __syncthreads();                               // step-0 A writes + B DMA done

    int buf = 0;
    for (int kb = 0; kb < K; kb += 32) {
        int kn = kb + 32;
        if (kn < K) {                              // issue next-step loads EARLY
            #pragma unroll
            for (int i = 0; i < 4; ++i)
                pa[i] = *(const uint4*)(Ap + (size_t)i * 64 * K + kn);
            ISSUE_B(buf ^ 1, kn);
        }
        const unsigned short* sAb = sA + (size_t)buf * SA;
        const unsigned short* sBb = sBall + (size_t)buf * NT * 2048;
        bf16x8 aMid[4];
        #pragma unroll
        for (int mr = 0; mr < 4; ++mr)
            aMid[mr] = *(const bf16x8*)(sAb + aoff[TAPS / 2][mr]);
        #pragma unroll
        for (int t = 0; t < TAPS; ++t) {
            bf16x8 af[4];
            #pragma unroll
            for (int mr = 0; mr < 4; ++mr)
                af[mr] = (t == TAPS / 2) ? aMid[mr]
                                         : *(const bf16x8*)(sAb + aoff[t][mr]);
            #pragma unroll
            for (int nt = 0; nt < 4; ++nt) {
                bf16x8 bg = *(const bf16x8*)(sBb + (size_t)t * 2048 + (nt * 16 + frow) * 32 + bco);
                #pragma unroll
                for (int mr = 0; mr < 4; ++mr)
                    accC[mr][nt] = __builtin_amdgcn_mfma_f32_16x16x32_bf16(af[mr], bg, accC[mr][nt], 0, 0, 0);
            }
        }
        if constexpr (HASWD) {
            #pragma unroll
            for (int nt = 0; nt < 4; ++nt) {
                bf16x8 bg = *(const bf16x8*)(sBb + (size_t)TAPS * 2048 + (nt * 16 + frow) * 32 + bco);
                #pragma unroll
                for (int mr = 0; mr < 4; ++mr)
                    accR[mr][nt] = __builtin_amdgcn_mfma_f32_16x16x32_bf16(aMid[mr], bg, accR[mr][nt], 0, 0, 0);
            }
        }
        if (kn < K) {                              // pa landed under the MFMAs
            unsigned short* sAn = sA + (size_t)(buf ^ 1) * SA;
            #pragma unroll
            for (int i = 0; i < 4; ++i)
                *(uint4*)(sAn + (srow + i * 64) * 40 + chS) = pa[i];
        }
        __syncthreads();                           // ONE barrier per K-step
        buf ^= 1;
    }
    #undef ISSUE_B

    float bvc[4], bdc[4];
    #pragma unroll
    for (int nt = 0; nt < 4; ++nt) {
        int col = n0 + nt * 16 + frow;
        bvc[nt] = bias[col];
        bdc[nt] = HASWD ? biasd[col] : 0.f;
    }
    float S[2][4], Q[2][4];
    #pragma unroll
    for (int h = 0; h < 2; ++h)
        #pragma unroll
        for (int nt = 0; nt < 4; ++nt) { S[h][nt] = 0.f; Q[h][nt] = 0.f; }
    #pragma unroll
    for (int mr = 0; mr < 4; ++mr) {
        const int h = mr >> 1;
        #pragma unroll
        for (int nt = 0; nt < 4; ++nt)
            #pragma unroll
            for (int r = 0; r < 4; ++r) {
                int l = (mr & 1) * 16 + fq * 4 + r;
                if (l < nn) {
                    float v = sane(accC[mr][nt][r] + bvc[nt]);
                    S[h][nt] += v; Q[h][nt] += v * v;
                }
            }
    }
    const float inv = 1.f / (float)nn;
    float mu[2][4], rsg[2][4];
    #pragma unroll
    for (int h = 0; h < 2; ++h)
        #pragma unroll
        for (int nt = 0; nt < 4; ++nt) {
            float s = S[h][nt], q = Q[h][nt];
            s += __shfl_xor(s, 16); s += __shfl_xor(s, 32);
            q += __shfl_xor(q, 16); q += __shfl_xor(q, 32);
            float m = s * inv;
            float var = q * inv - m * m;
            mu[h][nt]  = m;
            rsg[h][nt] = rsqrtf(fmaxf(var, 0.f) + 1e-5f);
        }
    float lw[2][4], lb2[2][4];
    #pragma unroll
    for (int p = 0; p < 2; ++p)
        #pragma unroll
        for (int r = 0; r < 4; ++r) {
            int l = p * 16 + fq * 4 + r;
            bool ok = l < nn;
            lw[p][r]  = ok ? lnw[l] : 0.f;
            lb2[p][r] = ok ? lnb[l] : 0.f;
        }
    #pragma unroll
    for (int nt = 0; nt < 4; ++nt) {
        const int colg = n0 + nt * 16 + frow;
        #pragma unroll
        for (int mr = 0; mr < 4; ++mr) {
            const int h = mr >> 1, p = mr & 1;
            #pragma unroll
            for (int r = 0; r < 4; ++r) {
                int l = p * 16 + fq * 4 + r;
                int grow = m0 + wv * 64 + mr * 16 + fq * 4 + r;
                float outv = 0.f;
                if (l < nn) {
                    float v = (sane(accC[mr][nt][r] + bvc[nt]) - mu[h][nt]) * rsg[h][nt] * lw[p][r] + lb2[p][r];
                    v = fmaxf(v, 0.f);
                    float rr;
                    if constexpr (HASWD) rr = sane(accR[mr][nt][r] + bdc[nt]);
                    else rr = __bfloat162float(res[(size_t)grow * res_stride + colg]);
                    outv = clamp256(v + rr);
                }
                outb[(size_t)grow * out_stride + colg] = __float2bfloat16(outv);
            }
        }
    }
}

// ---------------------------------------------------------------------------
// Fused per-graph GAT v4.1 (round-6 verified: 77 us, LDS 40448, 4 blocks/CU).
// CONV=1 fuses TCN block 0 (h in LDS, MFMA conv, in-register LN+relu+res).
// ---------------------------------------------------------------------------
#define MAXNE 270
#define XLS   260   // padded XL row stride (channels)
#define SHP   264   // padded H row stride (channels)
template<int CONV>
__global__ __launch_bounds__(256, 4) void gat_fused4(
    const int* __restrict__ ei, const bf* __restrict__ xlb, const bf* __restrict__ xrb,
    const float* __restrict__ att, const float* __restrict__ gbias,
    const bf* __restrict__ Wf, const float* __restrict__ cbias,
    const float* __restrict__ lnw, const float* __restrict__ lnb,
    bf* __restrict__ yout, float* __restrict__ dalpha, float* __restrict__ dei,
    int E0, int ET, int EPG, int nn)
{
    __shared__ __align__(16) __bf16 sXL[32 * XLS];   // 16.25 KB (padded rows)
    __shared__ __align__(16) __bf16 sHX[33 * SHP];   // 17.0 KB: XR (stride 256) then H (stride SHP)
    __shared__ float sExp[MAXNE * 4];                // 4.2 KB
    __shared__ int   sSD[MAXNE];                     // src | dst<<16
    __shared__ unsigned short sList[MAXNE];
    __shared__ int   sCnt[32];
    __shared__ int   sOff[33];

    const int g = blockIdx.x, tid = threadIdx.x, wv = tid >> 6, lane = tid & 63;
    if (EPG + nn > MAXNE) return;
    const int NE = EPG + nn;

    // Phase 0a: edges + self loops; stage xl/xr; zero H row 32
    for (int k = tid; k < EPG; k += 256) {
        int s = ei[(size_t)g * EPG + k] - g * nn;
        int d = ei[(size_t)E0 + (size_t)g * EPG + k] - g * nn;
        s = min(max(s, 0), nn - 1);
        d = min(max(d, 0), nn - 1);
        sSD[k] = s | (d << 16);
    }
    for (int k = EPG + tid; k < NE; k += 256) {
        int node = k - EPG;
        sSD[k] = node | (node << 16);
    }
    {
        const uint4* gxl = (const uint4*)(xlb + (size_t)g * nn * 256);
        const uint4* gxr = (const uint4*)(xrb + (size_t)g * (CONV ? 32 : nn) * 256);
        for (int k = tid; k < nn * 32; k += 256) {
            int node = k >> 5, c8 = k & 31;
            *(uint4*)(sXL + node * XLS + c8 * 8) = gxl[k];
            *(uint4*)(sHX + k * 8) = gxr[k];                 // XR layout, stride 256
        }
    }
    if (CONV) { __bf16 z = (__bf16)0.f; for (int k = tid; k < SHP; k += 256) sHX[32 * SHP + k] = z; }
    if (tid < 32) sCnt[tid] = 0;
    __syncthreads();

    // Phase 0b: histogram -> parallel exclusive scan -> scatter
    for (int k = tid; k < NE; k += 256) atomicAdd(&sCnt[sSD[k] >> 16], 1);
    __syncthreads();
    if (tid < 32) {
        int acc = 0, last = 0;
        #pragma unroll
        for (int j = 0; j < 32; ++j) {
            int c = sCnt[j];
            if (j < tid) acc += c;
            if (j == 31) last = c;
        }
        sOff[tid] = acc;
        if (tid == 31) sOff[32] = acc + last;
        sCnt[tid] = 0;
    }
    __syncthreads();
    for (int k = tid; k < NE; k += 256) {
        int d = sSD[k] >> 16;
        int p = atomicAdd(&sCnt[d], 1);
        sList[sOff[d] + p] = (unsigned short)k;
    }

    // ei echo
    for (int k = tid; k < NE; k += 256) {
        int s, d; size_t eg;
        if (k < EPG) {
            int sd = sSD[k];
            s = g * nn + (sd & 0xffff); d = g * nn + (sd >> 16);
            eg = (size_t)g * EPG + k;
        }
        else { int node = g * nn + (k - EPG); s = d = node; eg = (size_t)E0 + (size_t)g * nn + (k - EPG); }
        dei[eg] = (float)s;
        dei[(size_t)ET + eg] = (float)d;
    }
    __syncthreads();

    // Phase 1: wave-per-edge scores (reads XR from sHX, stride 256)
    const float4 attv = *(const float4*)(att + lane * 4);
    const int h4 = lane >> 4;
    for (int i = wv; i < NE; i += 4) {
        int sd = sSD[i];
        int srcl = sd & 0xffff, dstl = sd >> 16;
        bf16x4 a = *(const bf16x4*)(sXL + srcl * XLS + lane * 4);
        bf16x4 b = *(const bf16x4*)(sHX + dstl * 256 + lane * 4);
        float p = 0.f;
        {
            float v0 = (float)a[0] + (float)b[0]; v0 = v0 > 0.f ? v0 : 0.2f * v0; p += v0 * attv.x;
            float v1 = (float)a[1] + (float)b[1]; v1 = v1 > 0.f ? v1 : 0.2f * v1; p += v1 * attv.y;
            float v2 = (float)a[2] + (float)b[2]; v2 = v2 > 0.f ? v2 : 0.2f * v2; p += v2 * attv.z;
            float v3 = (float)a[3] + (float)b[3]; v3 = v3 > 0.f ? v3 : 0.2f * v3; p += v3 * attv.w;
        }
        p += __shfl_xor(p, 1); p += __shfl_xor(p, 2);
        p += __shfl_xor(p, 4); p += __shfl_xor(p, 8);
        if ((lane & 15) == 0)
            sExp[i * 4 + h4] = __expf(fminf(fmaxf(p, -60.f), 60.f));
    }
    __syncthreads();

    // Phase 2: 8-lane group per dst node; lane owns 32 channels.
    {
        const int grp  = wv * 8 + (lane >> 3);
        const int s8   = lane & 7;
        const int chb  = s8 * 32;
        const int head = s8 >> 1;
        bf* hrow = yout + ((size_t)g * 32 + grp) * 256 + chb;   // !CONV only

        if (grp < nn) {
            const int beg = sOff[grp], end = sOff[grp + 1];
            float den = 0.f;
            f32x4 acc[8];
            #pragma unroll
            for (int k2 = 0; k2 < 8; ++k2) acc[k2] = 0.f;

            for (int q = beg; q < end; ++q) {
                int e = sList[q];
                float ev = sExp[e * 4 + head];
                den += ev;
                const __bf16* xp = sXL + (sSD[e] & 0xffff) * XLS + chb;
                #pragma unroll
                for (int k2 = 0; k2 < 4; ++k2) {
                    bf16x8 xa = *(const bf16x8*)(xp + k2 * 8);
                    #pragma unroll
                    for (int j = 0; j < 4; ++j)
                        acc[k2 * 2][j]     += ev * (float)xa[j];
                    #pragma unroll
                    for (int j = 0; j < 4; ++j)
                        acc[k2 * 2 + 1][j] += ev * (float)xa[4 + j];
                }
            }
            const float rden = 1.f / fmaxf(den, 1e-30f);

            if (!(s8 & 1)) {
                for (int q = beg; q < end; ++q) {
                    int e = sList[q];
                    float al = fminf(fmaxf(sExp[e * 4 + head] * rden, 0.f), 1.f);
                    size_t eg = (e < EPG) ? ((size_t)g * EPG + e)
                                          : ((size_t)E0 + (size_t)g * nn + (e - EPG));
                    dalpha[eg * 4 + head] = al;
                }
            }

            #pragma unroll
            for (int k2 = 0; k2 < 8; ++k2) {
                float4 gbv = *(const float4*)(gbias + chb + k2 * 4);
                bf16x4 o;
                o[0] = (__bf16)clamp256(fmaxf(acc[k2][0] * rden + gbv.x, 0.f));
                o[1] = (__bf16)clamp256(fmaxf(acc[k2][1] * rden + gbv.y, 0.f));
                o[2] = (__bf16)clamp256(fmaxf(acc[k2][2] * rden + gbv.z, 0.f));
                o[3] = (__bf16)clamp256(fmaxf(acc[k2][3] * rden + gbv.w, 0.f));
                if constexpr (CONV) *(bf16x4*)(sHX + grp * SHP + chb + k2 * 4) = o;
                else                *(bf16x4*)(hrow + k2 * 4) = o;
            }
        } else {
            bf16x4 z; z[0] = (__bf16)0.f; z[1] = (__bf16)0.f; z[2] = (__bf16)0.f; z[3] = (__bf16)0.f;
            #pragma unroll
            for (int k2 = 0; k2 < 8; ++k2) {
                if constexpr (CONV) *(bf16x4*)(sHX + grp * SHP + chb + k2 * 4) = z;
                else                *(bf16x4*)(hrow + k2 * 4) = z;
            }
        }
    }

    // Phase 3 (CONV): y0 = relu(LN(conv3(h))) + h, per-wave 64 cols via MFMA
    if constexpr (CONV) {
        __syncthreads();
        const int frow = lane & 15;
        const int fq   = lane >> 4;
        const int colw = wv * 64;
        f32x4 c0[2][4];
        #pragma unroll
        for (int i = 0; i < 2; ++i)
            #pragma unroll
            for (int j = 0; j < 4; ++j) c0[i][j] = 0.f;

        #pragma unroll
        for (int kc = 0; kc < 8; ++kc) {
            bf16x8 af[3][2];
            #pragma unroll
            for (int t = 0; t < 3; ++t)
                #pragma unroll
                for (int mr = 0; mr < 2; ++mr) {
                    int l = mr * 16 + frow + t - 1;
                    int ar = ((unsigned)l < 32u) ? l : 32;
                    af[t][mr] = *(const bf16x8*)(sHX + ar * SHP + kc * 32 + fq * 8);
                }
            #pragma unroll
            for (int t = 0; t < 3; ++t) {
                bf16x8 bgs[4];
                #pragma unroll
                for (int nt = 0; nt < 4; ++nt) {
                    const __bf16* bp = (const __bf16*)Wf +
                        ((((size_t)(t * 16 + (colw >> 4) + nt) * 8 + kc) * 16 + frow) * 4 + fq) * 8;
                    bgs[nt] = *(const bf16x8*)bp;
                }
                #pragma unroll
                for (int nt = 0; nt < 4; ++nt) {
                    c0[0][nt] = __builtin_amdgcn_mfma_f32_16x16x32_bf16(af[t][0], bgs[nt], c0[0][nt], 0, 0, 0);
                    c0[1][nt] = __builtin_amdgcn_mfma_f32_16x16x32_bf16(af[t][1], bgs[nt], c0[1][nt], 0, 0, 0);
                }
            }
        }

        float bv[4];
        #pragma unroll
        for (int nt = 0; nt < 4; ++nt) bv[nt] = cbias[colw + nt * 16 + frow];
        float S[4], Q[4];
        #pragma unroll
        for (int nt = 0; nt < 4; ++nt) { S[nt] = 0.f; Q[nt] = 0.f; }
        #pragma unroll
        for (int mr = 0; mr < 2; ++mr)
            #pragma unroll
            for (int nt = 0; nt < 4; ++nt)
                #pragma unroll
                for (int r = 0; r < 4; ++r) {
                    int l = mr * 16 + fq * 4 + r;
                    if (l < nn) {
                        float v = sane(c0[mr][nt][r] + bv[nt]);
                        S[nt] += v; Q[nt] += v * v;
                    }
                }
        const float inv = 1.f / (float)nn;
        float mu[4], rsg[4];
        #pragma unroll
        for (int nt = 0; nt < 4; ++nt) {
            float s = S[nt], q = Q[nt];
            s += __shfl_xor(s, 16); s += __shfl_xor(s, 32);
            q += __shfl_xor(q, 16); q += __shfl_xor(q, 32);
            float m = s * inv;
            float var = q * inv - m * m;
            mu[nt]  = m;
            rsg[nt] = rsqrtf(fmaxf(var, 0.f) + 1e-5f);
        }
        float lw[2][4], lb2[2][4];
        #pragma unroll
        for (int p = 0; p < 2; ++p)
            #pragma unroll
            for (int r = 0; r < 4; ++r) {
                int l = p * 16 + fq * 4 + r;
                bool ok = l < nn;
                lw[p][r]  = ok ? lnw[l] : 0.f;
                lb2[p][r] = ok ? lnb[l] : 0.f;
            }
        #pragma unroll
        for (int nt = 0; nt < 4; ++nt) {
            const int colf = colw + nt * 16 + frow;
            #pragma unroll
            for (int mr = 0; mr < 2; ++mr)
                #pragma unroll
                for (int r = 0; r < 4; ++r) {
                    int l = mr * 16 + fq * 4 + r;
                    float outv = 0.f;
                    if (l < nn) {
                        float v = (sane(c0[mr][nt][r] + bv[nt]) - mu[nt]) * rsg[nt] * lw[mr][r] + lb2[mr][r];
                        v = fmaxf(v, 0.f);
                        float rr = (float)sHX[l * SHP + colf];
                        outv = clamp256(v + rr);
                    }
                    yout[((size_t)g * 32 + l) * 256 + colf] = __float2bfloat16(outv);
                }
        }
    }
}

// ---- fused weight prep ----
struct CvtSegs { const float* in[7]; bf* out[7]; int n[7]; };
__global__ void prep_cvt(CvtSegs s, int total)
{
    int idx = blockIdx.x * 256 + threadIdx.x;
    if (idx >= total) return;
    #pragma unroll
    for (int i = 0; i < 7; ++i) {
        if (idx < s.n[i]) { s.out[i][idx] = __float2bfloat16(s.in[i][idx]); return; }
        idx -= s.n[i];
    }
}
// taps, optionally swizzled for gemm_tcn's global_load_lds path
struct TapSegs { const float* w[3]; bf* o[3]; int cc[3]; int kk[3]; int swz[3]; };
__global__ void prep_taps3(TapSegs s, int total)
{
    int idx = blockIdx.x * 256 + threadIdx.x;
    if (idx >= total) return;
    #pragma unroll
    for (int i = 0; i < 3; ++i) {
        if (idx < s.cc[i]) {
            unsigned K = (unsigned)s.kk[i];
            unsigned co = (unsigned)idx / K, ci = (unsigned)idx % K;
            int dst = co * K + (s.swz[i] ? swzk(ci, co) : ci);
            #pragma unroll
            for (int k = 0; k < 3; ++k)
                s.o[i][(size_t)k * s.cc[i] + dst] = __float2bfloat16(s.w[i][(size_t)idx * 3 + k]);
            return;
        }
        idx -= s.cc[i];
    }
}
// downsample weights, optionally swizzled
__global__ void prep_wswz(const float* __restrict__ w, bf* __restrict__ o,
                          int total, int K, int swz)
{
    int idx = blockIdx.x * 256 + threadIdx.x;
    if (idx >= total) return;
    int co = idx / K, ci = idx % K;
    o[(size_t)co * K + (swz ? swzk(ci, co) : ci)] = __float2bfloat16(w[idx]);
}
// conv0 weights -> MFMA-fragment-contiguous layout (coalesced 1KB wave loads)
__global__ void prep_bfrag(const float* __restrict__ w, bf* __restrict__ o, int HC)
{
    int idx = blockIdx.x * 256 + threadIdx.x;
    if (idx >= HC * HC) return;
    int co = idx / HC, ci = idx % HC;
    int cg = co >> 4, fr = co & 15, kc = ci >> 5, fq = (ci >> 3) & 3, w8 = ci & 7;
    int NCg = HC >> 4, NKc = HC >> 5;
    #pragma unroll
    for (int t = 0; t < 3; ++t) {
        size_t dst = (((((size_t)t * NCg + cg) * NKc + kc) * 16 + fr) * 4 + fq) * 8 + w8;
        o[dst] = __float2bfloat16(w[(size_t)idx * 3 + t]);
    }
}

// fc1_w f32 [F1][ci*nn+l] -> bf16 W1t [F1][l*HC+ci], l padded to 32
__global__ void prep_fc1(const float* __restrict__ w, bf* __restrict__ o, int F1, int nn, int HC)
{
    int idx = blockIdx.x * 256 + threadIdx.x;
    int kw = 32 * HC;
    if (idx >= F1 * kw) return;
    int co = idx / kw, r = idx % kw, l = r / HC, ci = r % HC;
    float hv = 0.f;
    if (l < nn) hv = w[(size_t)co * (HC * nn) + ci * nn + l];
    o[idx] = __float2bfloat16(hv);
}

// fc1 split-K reduce: z1 = bf16(relu(sum_z partials + bias))
__global__ void fc1red(const bf* __restrict__ zp, const float* __restrict__ bias,
                       bf* __restrict__ o, int MN, int N, int S)
{
    int idx = blockIdx.x * 256 + threadIdx.x;
    if (idx >= MN) return;
    float s = 0.f;
    for (int z = 0; z < S; ++z) s += __bfloat162float(zp[(size_t)z * MN + idx]);
    o[idx] = __float2bfloat16(clamp256(fmaxf(s + bias[idx % N], 0.f)));
}

extern "C" void kernel_launch(void* const* d_in, const int* in_sizes, int n_in,
                              void* d_out, int out_size, void* d_ws, size_t ws_size,
                              hipStream_t stream)
{
    (void)n_in; (void)ws_size;
    const float* x   = (const float*)d_in[0];
    const float* Wl  = (const float*)d_in[1];  const float* bl  = (const float*)d_in[2];
    const float* Wr  = (const float*)d_in[3];  const float* br  = (const float*)d_in[4];
    const float* att = (const float*)d_in[5];  const float* gb  = (const float*)d_in[6];
    const float* t0w = (const float*)d_in[7];  const float* t0b = (const float*)d_in[8];
    const float* l0w = (const float*)d_in[9];  const float* l0b = (const float*)d_in[10];
    const float* t1w = (const float*)d_in[11]; const float* t1b = (const float*)d_in[12];
    const float* l1w = (const float*)d_in[13]; const float* l1b = (const float*)d_in[14];
    const float* d1w = (const float*)d_in[15]; const float* d1b = (const float*)d_in[16];
    const float* t2w = (const float*)d_in[17]; const float* t2b = (const float*)d_in[18];
    const float* l2w = (const float*)d_in[19]; const float* l2b = (const float*)d_in[20];
    const float* d2w = (const float*)d_in[21]; const float* d2b = (const float*)d_in[22];
    const float* f1w = (const float*)d_in[23]; const float* f1b = (const float*)d_in[24];
    const float* f2w = (const float*)d_in[25]; const float* f2b = (const float*)d_in[26];
    const float* f3w = (const float*)d_in[27]; const float* f3b = (const float*)d_in[28];
    const int*   ei  = (const int*)d_in[29];

    const int HC   = in_sizes[6];                        // 256
    const int F_IN = in_sizes[1] / (HC > 0 ? HC : 1);    // 64
    const int NN   = in_sizes[0] / (F_IN > 0 ? F_IN : 1);// 30720
    const int E0   = in_sizes[29] / 2;                   // 245760
    const int ET   = E0 + NN;                            // 276480
    int nn = in_sizes[9];  nn = nn < 1 ? 1 : (nn > 32 ? 32 : nn);  // 30
    const int NG   = NN / nn;                            // 1024
    const int EPG  = NG > 0 ? E0 / NG : 0;               // 240
    const int C1   = in_sizes[12];                       // 512
    const int C2   = in_sizes[18];                       // 256
    const int F1   = in_sizes[24];                       // 512
    const int F2   = in_sizes[26];                       // 256
    const int F3   = in_sizes[28];                       // 144
    const int NG2  = (NG + 1) / 2;

    float* dout   = (float*)d_out;
    float* dei    = dout + ((size_t)out_size - 2 * (size_t)ET);
    float* dalpha = dei - (size_t)ET * 4;

    // ---- path eligibility ----
    const bool fused0 = (HC == 256) && (nn >= 1) && (nn <= 32) && (EPG + nn <= MAXNE)
                        && ((NN % 64) == 0);
    const int  gcA = NG2, gcB = NG - NG2;
    const bool fastc = ((gcA * 32) % 256 == 0) && ((gcB * 32) % 256 == 0)
                       && (C1 % 64 == 0) && (C2 % 64 == 0)
                       && (HC % 32 == 0) && (C1 % 32 == 0);

    // ---- workspace map (42 MB):
    //  [0,4M)      xb (dead after GAT gemm) -> z1, z2
    //  [4M,7.5M)   weights (incl. WkAf frag layout)
    //  S0 [7.5,25M): fused: xrb(pad32) -> y0 -> y2 ; fallback: xrb/hbuf
    //  S1 [25,42M):  xlb -> (fused: y1c -> W1t+z1p) (fallback: y0 -> y2)
    char* ws = (char*)d_ws;
    const size_t MB = 1ull << 20;
    bf*    xb   = (bf*)(ws);
    bf*    WkA  = (bf*)(ws + 4 * MB);
    bf*    WkB  = WkA + (size_t)3 * HC * HC;
    bf*    WkC  = WkB + (size_t)3 * C1 * HC;
    bf*    Wlb  = WkC + (size_t)3 * C2 * C1;
    bf*    Wrb  = Wlb + (size_t)HC * F_IN;
    bf*    f2wb = Wrb + (size_t)HC * F_IN;
    bf*    f3wb = f2wb + (size_t)F2 * F1;
    bf*    d1wb = f3wb + (size_t)F3 * F2;
    bf*    d2wb = d1wb + (size_t)C1 * HC;
    bf*    WkAf = d2wb + (size_t)C2 * C1;                // frag-layout conv0 weights
    char*  S0   = ws + (size_t)(7.5 * MB);
    char*  S1   = ws + 25 * MB;

    bf*    xrb  = (bf*)S0;                               // padded 32 rows when fused0
    bf*    hbuf = (bf*)S0;                               // fallback GAT output
    bf*    xlb  = (bf*)S1;
    bf*    y0   = fused0 ? (bf*)S0 : (bf*)S1;
    bf*    y1c  = fused0 ? (bf*)S1 : (bf*)S0;
    char*  fcS  = fused0 ? S1 : S0;                      // FC staging region
    bf*    W1t  = (bf*)fcS;                              // 8.4 MB
    bf*    z1p  = (bf*)(fcS + (size_t)(8.5 * MB));       // 8 MB
    bf*    z1   = (bf*)(ws);                             // 1 MB (over dead xb)
    bf*    z2   = (bf*)(ws + 2 * MB);                    // 0.5 MB

    // ---- fused weight prep ----
    {
        CvtSegs cs;
        cs.in[0] = x;   cs.out[0] = xb;   cs.n[0] = NN * F_IN;
        cs.in[1] = Wl;  cs.out[1] = Wlb;  cs.n[1] = HC * F_IN;
        cs.in[2] = Wr;  cs.out[2] = Wrb;  cs.n[2] = HC * F_IN;
        cs.in[3] = f2w; cs.out[3] = f2wb; cs.n[3] = F2 * F1;
        cs.in[4] = f3w; cs.out[4] = f3wb; cs.n[4] = F3 * F2;
        cs.in[5] = nullptr; cs.out[5] = nullptr; cs.n[5] = 0;
        cs.in[6] = nullptr; cs.out[6] = nullptr; cs.n[6] = 0;
        int tot = 0; for (int i = 0; i < 5; ++i) tot += cs.n[i];
        prep_cvt<<<(tot + 255) / 256, 256, 0, stream>>>(cs, tot);
        TapSegs ts;
        ts.w[0] = t0w; ts.o[0] = WkA; ts.cc[0] = HC * HC; ts.kk[0] = HC; ts.swz[0] = 0;
        ts.w[1] = t1w; ts.o[1] = WkB; ts.cc[1] = C1 * HC; ts.kk[1] = HC; ts.swz[1] = fastc ? 1 : 0;
        ts.w[2] = t2w; ts.o[2] = WkC; ts.cc[2] = C2 * C1; ts.kk[2] = C1; ts.swz[2] = fastc ? 1 : 0;
        int tt = ts.cc[0] + ts.cc[1] + ts.cc[2];
        prep_taps3<<<(tt + 255) / 256, 256, 0, stream>>>(ts, tt);
        prep_wswz<<<(C1 * HC + 255) / 256, 256, 0, stream>>>(d1w, d1wb, C1 * HC, HC, fastc ? 1 : 0);
        prep_wswz<<<(C2 * C1 + 255) / 256, 256, 0, stream>>>(d2w, d2wb, C2 * C1, C1, fastc ? 1 : 0);
        if (fused0)
            prep_bfrag<<<(HC * HC + 255) / 256, 256, 0, stream>>>(t0w, WkAf, HC);
    }

    // ---- GAT transforms: dual-output GEMM (mode 5; xr padded when fused0) ----
    gemm_tf<1, true><<<dim3((HC + 63) / 64, (NN + 63) / 64), 256, 0, stream>>>(
        xb, Wlb, Wrb, bl, br, nullptr, nullptr, (const bf*)xrb, HC,
        xlb, nullptr, HC, NN, HC, F_IN, 1, 5, fused0 ? 1 : 0, 0, nn, F_IN);

    // ---- fused GAT (+TCN block 0 when fused0) ----
    if (fused0)
        gat_fused4<1><<<NG, 256, 0, stream>>>(ei, xlb, xrb, att, gb,
                                              WkAf, t0b, l0w, l0b,
                                              y0, dalpha, dei, E0, ET, EPG, nn);
    else {
        gat_fused4<0><<<NG, 256, 0, stream>>>(ei, xlb, xrb, att, gb,
                                              nullptr, nullptr, nullptr, nullptr,
                                              hbuf, dalpha, dei, E0, ET, EPG, nn);
        // fallback TCN block 0
        gemm_tf<3, false><<<dim3((HC + 63) / 64, NG * 32 / 64), 256, 0, stream>>>(
            hbuf, WkA, nullptr, t0b, nullptr, l0w, l0b, hbuf, HC,
            y0, nullptr, HC, NG * 32, HC, HC, 1, 2, 0, 1, nn, HC);
    }

    // ---- TCN blocks 1 & 2, two graph-chunks ----
    for (int c = 0; c < 2; ++c) {
        int g0 = c * NG2;
        int gc = (c == 0) ? NG2 : (NG - NG2);
        if (gc <= 0) continue;
        const bf* y0c = y0 + (size_t)g0 * 32 * HC;
        bf*       y2c = y0 + (size_t)g0 * 32 * HC;
        if (fastc) {
            gemm_tcn<3, true><<<dim3(C1 / 64, gc * 32 / 256), 256, 0, stream>>>(
                y0c, WkB, d1wb, t1b, d1b, l1w, l1b, nullptr, 0,
                y1c, C1, gc * 32, C1, HC, 2, nn);
            gemm_tcn<3, true><<<dim3(C2 / 64, gc * 32 / 256), 256, 0, stream>>>(
                y1c, WkC, d2wb, t2b, d2b, l2w, l2b, nullptr, 0,
                y2c, C2, gc * 32, C2, C1, 4, nn);
        } else {
            gemm_tf<3, true><<<dim3((C1 + 63) / 64, gc * 32 / 64), 256, 0, stream>>>(
                y0c, WkB, d1wb, t1b, d1b, l1w, l1b, nullptr, 0,
                y1c, nullptr, C1, gc * 32, C1, HC, 2, 2, 0, 1, nn, HC);
            gemm_tf<3, true><<<dim3((C2 + 63) / 64, gc * 32 / 64), 256, 0, stream>>>(
                y1c, WkC, d2wb, t2b, d2b, l2w, l2b, nullptr, 0,
                y2c, nullptr, C2, gc * 32, C2, C1, 4, 2, 0, 1, nn, C1);
        }
    }

    // ---- FC head ----
    prep_fc1<<<(F1 * 32 * HC + 255) / 256, 256, 0, stream>>>(f1w, W1t, F1, nn, HC);
    gemm_tf<1, false><<<dim3((F1 + 63) / 64, (NG + 63) / 64, 8), 256, 0, stream>>>(
        y0, W1t, nullptr, nullptr, nullptr, nullptr, nullptr, nullptr, 0,
        z1p, nullptr, F1, NG, F1, 32 * HC, 1, 3, 0, 0, nn, 4 * HC);
    fc1red<<<(NG * F1 + 255) / 256, 256, 0, stream>>>(z1p, f1b, z1, NG * F1, F1, 8);

    gemm_tf<1, false><<<dim3((F2 + 63) / 64, (NG + 63) / 64), 256, 0, stream>>>(
        z1, f2wb, nullptr, f2b, nullptr, nullptr, nullptr, nullptr, 0,
        z2, nullptr, F2, NG, F2, F1, 1, 0, 1, 0, nn, F1);
    gemm_tf<1, false><<<dim3((F3 + 63) / 64, (NG + 63) / 64), 256, 0, stream>>>(
        z2, f3wb, nullptr, f3b, nullptr, nullptr, nullptr, nullptr, 0,
        nullptr, dout, F3, NG, F3, F2, 1, 0, 0, 0, nn, F2);
}

// Round 10
// 424.004 us; speedup vs baseline: 1.2621x; 1.0718x over previous
//
#include <hip/hip_runtime.h>
#include <hip/hip_bf16.h>

typedef __bf16  bf16x8 __attribute__((ext_vector_type(8)));
typedef __bf16  bf16x4 __attribute__((ext_vector_type(4)));
typedef float   f32x4  __attribute__((ext_vector_type(4)));
typedef __hip_bfloat16 bf;

__device__ __forceinline__ float clamp256(float v) {
    return fminf(fmaxf(v, -256.f), 256.f);
}
__device__ __forceinline__ float sane(float v) {
    return fminf(fmaxf(v, -1e4f), 1e4f);
}
// 16B-chunk XOR swizzle baked into weight layout: spreads B-tile rows over
// 8 LDS bank-groups (2-way = free) while keeping global_load_lds linear.
__device__ __forceinline__ int swzk(int k, int col) {
    return (k & ~31) | ((((k >> 3) & 3) ^ ((col >> 1) & 3)) << 3) | (k & 7);
}

// ---------------------------------------------------------------------------
// Tap-fused, register-prefetch 64x64 bf16 MFMA GEMM (fallback GAT + FC head).
// mode 0: store (+bias,relu) -> outb bf16 or outf f32
// mode 2: register-resident LayerNorm(nn)+relu+residual (accR/Wd or res[])
// mode 3: split-K bf16 partials: outb[z*M*ostride + row*ostride + col]
// mode 5: dual output (HASWD): outb=accC+bias, res(cast bf*)=accR+biasd
// NOTE: expects UNSWIZZLED weights.
// ---------------------------------------------------------------------------
template<int TAPS, bool HASWD>
__global__ __launch_bounds__(256) void gemm_tf(
    const bf* __restrict__ A, const bf* __restrict__ Wt, const bf* __restrict__ Wd,
    const float* __restrict__ bias, const float* __restrict__ biasd,
    const float* __restrict__ lnw, const float* __restrict__ lnb,
    const bf* __restrict__ res, int res_stride,
    bf* __restrict__ outb, float* __restrict__ outf, int out_stride,
    int M, int N, int K, int dil, int mode, int relu, int padded, int nn, int kLen)
{
    constexpr int NT = TAPS + (HASWD ? 1 : 0);
    __shared__ __align__(16) unsigned short sA[66 * 40];      // 64 rows + zero row 64
    __shared__ __align__(16) unsigned short sB[NT][64 * 40];
    __shared__ float sS[4][64], sS2[4][64];

    const int tid  = threadIdx.x;
    const int wv   = tid >> 6;
    const int lane = tid & 63;
    const int m0   = blockIdx.y * 64;
    const int n0   = blockIdx.x * 64;
    const int frow = lane & 15;
    const int fq   = lane >> 4;
    const int kOff = blockIdx.z * kLen;
    const int kEnd = (kOff + kLen < K) ? (kOff + kLen) : K;

    if (tid < 40) sA[64 * 40 + tid] = (unsigned short)0;

    int aoff[NT];
    {
        int token = wv * 16 + frow;
        int b = token >> 5, l = token & 31;
        #pragma unroll
        for (int t = 0; t < NT; ++t) {
            int s = (t < TAPS) ? (t - TAPS / 2) * dil : 0;
            int ar;
            if (padded) {
                int ls = l + s;
                ar = ((unsigned)ls < 32u) ? (b * 32 + ls) : 64;
            } else {
                ar = token;
            }
            aoff[t] = ar * 40 + fq * 8;
        }
    }

    const int srow = tid >> 2;
    const int schk = (tid & 3) << 3;
    int raG = m0 + srow;
    if (!padded && raG >= M) raG = -1;
    const int rbG  = n0 + srow;
    const bool bval = rbG < N;
    const bf* Ap = (raG >= 0) ? (A + (size_t)raG * K) : nullptr;
    const bf* Bp[NT];
    #pragma unroll
    for (int t = 0; t < NT; ++t)
        Bp[t] = (HASWD && t == TAPS) ? (Wd + (size_t)rbG * K)
                                     : (Wt + ((size_t)t * N + rbG) * K);

    f32x4 accC[4], accR[4];
    #pragma unroll
    for (int i = 0; i < 4; ++i) { accC[i] = 0.f; accR[i] = 0.f; }

    const uint4 zu = make_uint4(0u, 0u, 0u, 0u);
    uint4 pa, pb[NT];
    pa = Ap ? *(const uint4*)(Ap + kOff + schk) : zu;
    #pragma unroll
    for (int t = 0; t < NT; ++t)
        pb[t] = bval ? *(const uint4*)(Bp[t] + kOff + schk) : zu;

    for (int kb = kOff; kb < kEnd; kb += 32) {
        __syncthreads();
        *(uint4*)(sA + srow * 40 + schk) = pa;
        #pragma unroll
        for (int t = 0; t < NT; ++t)
            *(uint4*)(&sB[t][srow * 40 + schk]) = pb[t];
        __syncthreads();
        int kn = kb + 32;
        if (kn < kEnd) {
            pa = Ap ? *(const uint4*)(Ap + kn + schk) : zu;
            #pragma unroll
            for (int t = 0; t < NT; ++t)
                pb[t] = bval ? *(const uint4*)(Bp[t] + kn + schk) : zu;
        }
        #pragma unroll
        for (int t = 0; t < TAPS; ++t) {
            bf16x8 af = *(const bf16x8*)(sA + aoff[t]);
            #pragma unroll
            for (int nt = 0; nt < 4; ++nt) {
                bf16x8 bg = *(const bf16x8*)(&sB[t][(nt * 16 + frow) * 40 + fq * 8]);
                accC[nt] = __builtin_amdgcn_mfma_f32_16x16x32_bf16(af, bg, accC[nt], 0, 0, 0);
            }
        }
        if constexpr (HASWD) {
            bf16x8 af = *(const bf16x8*)(sA + aoff[TAPS]);
            #pragma unroll
            for (int nt = 0; nt < 4; ++nt) {
                bf16x8 bg = *(const bf16x8*)(&sB[TAPS][(nt * 16 + frow) * 40 + fq * 8]);
                accR[nt] = __builtin_amdgcn_mfma_f32_16x16x32_bf16(af, bg, accR[nt], 0, 0, 0);
            }
        }
    }

    if (mode == 0) {
        #pragma unroll
        for (int nt = 0; nt < 4; ++nt) {
            int col = n0 + nt * 16 + frow;
            if (col >= N) continue;
            float bv = bias ? bias[col] : 0.f;
            #pragma unroll
            for (int r = 0; r < 4; ++r) {
                int row = m0 + wv * 16 + fq * 4 + r;
                if (row >= M) continue;
                float v = accC[nt][r] + bv;
                if (relu) v = fmaxf(v, 0.f);
                if (outb) outb[(size_t)row * out_stride + col] = __float2bfloat16(clamp256(v));
                else      outf[(size_t)row * out_stride + col] = sane(v);
            }
        }
    } else if (mode == 3) {
        bf* po = outb + (size_t)blockIdx.z * M * out_stride;
        #pragma unroll
        for (int nt = 0; nt < 4; ++nt) {
            int col = n0 + nt * 16 + frow;
            if (col >= N) continue;
            #pragma unroll
            for (int r = 0; r < 4; ++r) {
                int row = m0 + wv * 16 + fq * 4 + r;
                if (row >= M) continue;
                po[(size_t)row * out_stride + col] = __float2bfloat16(accC[nt][r]);
            }
        }
    } else if (mode == 5) {
        if constexpr (HASWD) {
            bf* out2 = (bf*)res;
            int orow_[4];
            #pragma unroll
            for (int r = 0; r < 4; ++r) {
                int row = m0 + wv * 16 + fq * 4 + r;
                orow_[r] = relu ? ((row / nn) * 32 + (row % nn)) : row;
            }
            #pragma unroll
            for (int nt = 0; nt < 4; ++nt) {
                int col = n0 + nt * 16 + frow;
                if (col >= N) continue;
                float bv = bias[col], bd = biasd[col];
                #pragma unroll
                for (int r = 0; r < 4; ++r) {
                    int row = m0 + wv * 16 + fq * 4 + r;
                    if (row >= M) continue;
                    outb[(size_t)row * out_stride + col] = __float2bfloat16(clamp256(accC[nt][r] + bv));
                    out2[(size_t)orow_[r] * res_stride + col] = __float2bfloat16(clamp256(accR[nt][r] + bd));
                }
            }
        }
    } else {  // mode 2
        float bvc[4], bdc[4];
        #pragma unroll
        for (int nt = 0; nt < 4; ++nt) {
            int col = n0 + nt * 16 + frow;
            bvc[nt] = bias[col];
            bdc[nt] = (HASWD && biasd) ? biasd[col] : 0.f;
        }
        float s[4], s2[4];
        #pragma unroll
        for (int nt = 0; nt < 4; ++nt) { s[nt] = 0.f; s2[nt] = 0.f; }
        #pragma unroll
        for (int nt = 0; nt < 4; ++nt)
            #pragma unroll
            for (int r = 0; r < 4; ++r) {
                int row = wv * 16 + fq * 4 + r;
                int l = row & 31;
                float v = sane(accC[nt][r] + bvc[nt]);
                if (l < nn) { s[nt] += v; s2[nt] += v * v; }
            }
        #pragma unroll
        for (int nt = 0; nt < 4; ++nt) {
            s[nt]  += __shfl_xor(s[nt], 16);  s[nt]  += __shfl_xor(s[nt], 32);
            s2[nt] += __shfl_xor(s2[nt], 16); s2[nt] += __shfl_xor(s2[nt], 32);
        }
        if (fq == 0) {
            #pragma unroll
            for (int nt = 0; nt < 4; ++nt) {
                sS[wv][nt * 16 + frow]  = s[nt];
                sS2[wv][nt * 16 + frow] = s2[nt];
            }
        }
        __syncthreads();
        const int gi = wv >> 1;
        const float inv = 1.f / (float)nn;
        #pragma unroll
        for (int nt = 0; nt < 4; ++nt) {
            int c = nt * 16 + frow;
            int colg = n0 + c;
            float S  = sS[2 * gi][c]  + sS[2 * gi + 1][c];
            float S2 = sS2[2 * gi][c] + sS2[2 * gi + 1][c];
            float mu = S * inv;
            float var = S2 * inv - mu * mu;
            float rs = rsqrtf(fmaxf(var, 0.f) + 1e-5f);
            #pragma unroll
            for (int r = 0; r < 4; ++r) {
                int row = wv * 16 + fq * 4 + r;
                int l = row & 31;
                int grow = m0 + row;
                float outv = 0.f;
                if (l < nn) {
                    float v = (sane(accC[nt][r] + bvc[nt]) - mu) * rs * lnw[l] + lnb[l];
                    v = fmaxf(v, 0.f);
                    float rr;
                    if constexpr (HASWD) rr = sane(accR[nt][r] + bdc[nt]);
                    else rr = __bfloat162float(res[(size_t)grow * res_stride + colg]);
                    outv = clamp256(v + rr);
                }
                outb[(size_t)grow * out_stride + colg] = __float2bfloat16(outv);
            }
        }
    }
}

// ---------------------------------------------------------------------------
// TCN tap-fused GEMM v4 (round-9 winner, unchanged): 256x64 macro-tile,
// DMA-staged B (pre-swizzled weights), double-buffered sA, ONE barrier/K-step.
// ---------------------------------------------------------------------------
template<int TAPS, bool HASWD>
__global__ __launch_bounds__(256, 2) void gemm_tcn(
    const bf* __restrict__ A, const bf* __restrict__ Wt, const bf* __restrict__ Wd,
    const float* __restrict__ bias, const float* __restrict__ biasd,
    const float* __restrict__ lnw, const float* __restrict__ lnb,
    const bf* __restrict__ res, int res_stride,
    bf* __restrict__ outb, int out_stride,
    int M, int N, int K, int dil, int nn)
{
    constexpr int NT = TAPS + (HASWD ? 1 : 0);
    constexpr int SA = 257 * 40;                                   // shorts per A buffer
    __shared__ __align__(16) unsigned short sA[2 * SA];            // dbuf A + zero rows
    __shared__ __align__(16) unsigned short sBall[2 * NT * 64 * 32];

    const int tid  = threadIdx.x;
    const int wv   = tid >> 6;
    const int lane = tid & 63;
    const int frow = lane & 15;
    const int fq   = lane >> 4;

    const int gx  = gridDim.x;
    const int nwg = gx * gridDim.y;
    int wg = blockIdx.y * gx + blockIdx.x;
    if ((nwg & 7) == 0) wg = (wg & 7) * (nwg >> 3) + (wg >> 3);
    const int n0 = (wg % gx) * 64;
    const int m0 = (wg / gx) * 256;

    if (tid < 40) {                                 // zero row 256 of BOTH buffers
        sA[256 * 40 + tid]      = (unsigned short)0;
        sA[SA + 256 * 40 + tid] = (unsigned short)0;
    }

    int aoff[TAPS][4];
    #pragma unroll
    for (int mr = 0; mr < 4; ++mr) {
        int token = wv * 64 + mr * 16 + frow;
        int b5 = token >> 5, l = token & 31;
        #pragma unroll
        for (int t = 0; t < TAPS; ++t) {
            int ls = l + (t - TAPS / 2) * dil;
            int ar = ((unsigned)ls < 32u) ? (b5 * 32 + ls) : 256;
            aoff[t][mr] = ar * 40 + fq * 8;
        }
    }
    const int bco = (fq ^ ((frow >> 1) & 3)) << 3;

    const int srow = tid >> 2;
    const int chS  = (tid & 3) << 3;
    const bf* Ap = A + (size_t)(m0 + srow) * K + chS;

    const bf* bsrc[4];
    {
        int lr = lane >> 2, lc = lane & 3;
        #pragma unroll
        for (int i = 0; i < 4; ++i) {
            int colb = n0 + i * 16 + lr;
            const bf* Wb;
            if (HASWD && wv == TAPS) Wb = Wd + (size_t)colb * K;
            else if (wv < TAPS)      Wb = Wt + ((size_t)wv * N + colb) * K;
            else                     Wb = Wt + (size_t)colb * K;
            bsrc[i] = Wb + lc * 8;
        }
    }

    f32x4 accC[4][4], accR[4][4];
    #pragma unroll
    for (int i = 0; i < 4; ++i)
        #pragma unroll
        for (int j = 0; j < 4; ++j) { accC[i][j] = 0.f; if (HASWD) accR[i][j] = 0.f; }

    #define ISSUE_B(BUFB, KBS)                                                      \
        if (wv < NT) {                                                              \
            unsigned short* bas = sBall + ((size_t)((BUFB) * NT + wv) * 64) * 32;   \
            _Pragma("unroll")                                                       \
            for (int i = 0; i < 4; ++i) {                                           \
                __builtin_amdgcn_global_load_lds(                                   \
                    (const __attribute__((address_space(1))) void*)(bsrc[i] + (KBS)), \
                    (__attribute__((address_space(3))) void*)(bas + i * 512),       \
                    16, 0, 0);                                                      \
            }                                                                       \
        }

    // prologue: stage step 0 (A regs -> sA[0]; B via DMA -> sB[0])
    uint4 pa[4];
    #pragma unroll
    for (int i = 0; i < 4; ++i) pa[i] = *(const uint4*)(Ap + (size_t)i * 64 * K);
    ISSUE_B(0, 0);
    #pragma unroll
    for (int i = 0; i < 4; ++i)
        *(uint4*)(sA + (srow + i * 64) * 40 + chS) = pa[i];
    __syncthreads();                               // step-0 A writes + B DMA done

    int buf = 0;
    for (int kb = 0; kb < K; kb += 32) {
        int kn = kb + 32;
        if (kn < K) {                              // issue next-step loads EARLY
            #pragma unroll
            for (int i = 0; i < 4; ++i)
                pa[i] = *(const uint4*)(Ap + (size_t)i * 64 * K + kn);
            ISSUE_B(buf ^ 1, kn);
        }
        const unsigned short* sAb = sA + (size_t)buf * SA;
        const unsigned short* sBb = sBall + (size_t)buf * NT * 2048;
        bf16x8 aMid[4];
        #pragma unroll
        for (int mr = 0; mr < 4; ++mr)
            aMid[mr] = *(const bf16x8*)(sAb + aoff[TAPS / 2][mr]);
        #pragma unroll
        for (int t = 0; t < TAPS; ++t) {
            bf16x8 af[4];
            #pragma unroll
            for (int mr = 0; mr < 4; ++mr)
                af[mr] = (t == TAPS / 2) ? aMid[mr]
                                         : *(const bf16x8*)(sAb + aoff[t][mr]);
            #pragma unroll
            for (int nt = 0; nt < 4; ++nt) {
                bf16x8 bg = *(const bf16x8*)(sBb + (size_t)t * 2048 + (nt * 16 + frow) * 32 + bco);
                #pragma unroll
                for (int mr = 0; mr < 4; ++mr)
                    accC[mr][nt] = __builtin_amdgcn_mfma_f32_16x16x32_bf16(af[mr], bg, accC[mr][nt], 0, 0, 0);
            }
        }
        if constexpr (HASWD) {
            #pragma unroll
            for (int nt = 0; nt < 4; ++nt) {
                bf16x8 bg = *(const bf16x8*)(sBb + (size_t)TAPS * 2048 + (nt * 16 + frow) * 32 + bco);
                #pragma unroll
                for (int mr = 0; mr < 4; ++mr)
                    accR[mr][nt] = __builtin_amdgcn_mfma_f32_16x16x32_bf16(aMid[mr], bg, accR[mr][nt], 0, 0, 0);
            }
        }
        if (kn < K) {                              // pa landed under the MFMAs
            unsigned short* sAn = sA + (size_t)(buf ^ 1) * SA;
            #pragma unroll
            for (int i = 0; i < 4; ++i)
                *(uint4*)(sAn + (srow + i * 64) * 40 + chS) = pa[i];
        }
        __syncthreads();                           // ONE barrier per K-step
        buf ^= 1;
    }
    #undef ISSUE_B

    float bvc[4], bdc[4];
    #pragma unroll
    for (int nt = 0; nt < 4; ++nt) {
        int col = n0 + nt * 16 + frow;
        bvc[nt] = bias[col];
        bdc[nt] = HASWD ? biasd[col] : 0.f;
    }
    float S[2][4], Q[2][4];
    #pragma unroll
    for (int h = 0; h < 2; ++h)
        #pragma unroll
        for (int nt = 0; nt < 4; ++nt) { S[h][nt] = 0.f; Q[h][nt] = 0.f; }
    #pragma unroll
    for (int mr = 0; mr < 4; ++mr) {
        const int h = mr >> 1;
        #pragma unroll
        for (int nt = 0; nt < 4; ++nt)
            #pragma unroll
            for (int r = 0; r < 4; ++r) {
                int l = (mr & 1) * 16 + fq * 4 + r;
                if (l < nn) {
                    float v = sane(accC[mr][nt][r] + bvc[nt]);
                    S[h][nt] += v; Q[h][nt] += v * v;
                }
            }
    }
    const float inv = 1.f / (float)nn;
    float mu[2][4], rsg[2][4];
    #pragma unroll
    for (int h = 0; h < 2; ++h)
        #pragma unroll
        for (int nt = 0; nt < 4; ++nt) {
            float s = S[h][nt], q = Q[h][nt];
            s += __shfl_xor(s, 16); s += __shfl_xor(s, 32);
            q += __shfl_xor(q, 16); q += __shfl_xor(q, 32);
            float m = s * inv;
            float var = q * inv - m * m;
            mu[h][nt]  = m;
            rsg[h][nt] = rsqrtf(fmaxf(var, 0.f) + 1e-5f);
        }
    float lw[2][4], lb2[2][4];
    #pragma unroll
    for (int p = 0; p < 2; ++p)
        #pragma unroll
        for (int r = 0; r < 4; ++r) {
            int l = p * 16 + fq * 4 + r;
            bool ok = l < nn;
            lw[p][r]  = ok ? lnw[l] : 0.f;
            lb2[p][r] = ok ? lnb[l] : 0.f;
        }
    #pragma unroll
    for (int nt = 0; nt < 4; ++nt) {
        const int colg = n0 + nt * 16 + frow;
        #pragma unroll
        for (int mr = 0; mr < 4; ++mr) {
            const int h = mr >> 1, p = mr & 1;
            #pragma unroll
            for (int r = 0; r < 4; ++r) {
                int l = p * 16 + fq * 4 + r;
                int grow = m0 + wv * 64 + mr * 16 + fq * 4 + r;
                float outv = 0.f;
                if (l < nn) {
                    float v = (sane(accC[mr][nt][r] + bvc[nt]) - mu[h][nt]) * rsg[h][nt] * lw[p][r] + lb2[p][r];
                    v = fmaxf(v, 0.f);
                    float rr;
                    if constexpr (HASWD) rr = sane(accR[mr][nt][r] + bdc[nt]);
                    else rr = __bfloat162float(res[(size_t)grow * res_stride + colg]);
                    outv = clamp256(v + rr);
                }
                outb[(size_t)grow * out_stride + colg] = __float2bfloat16(outv);
            }
        }
    }
}

// ---------------------------------------------------------------------------
// Fused per-graph GAT v6. CONV=1: fuses the INPUT TRANSFORMS (xl = x@Wl^T+bl,
// xr = x@Wr^T+br; mini-GEMM per block, B-frags from prep-baked WlrF in L2,
// x staged into a 4KB XOR-swizzled scratch OVERLAID on sExp) AND TCN block 0.
// XR/H stored at stride SHP (=264) so C-writes are bank-spread.
// LDS 40264 B -> 4 blocks/CU. CONV=0 fallback: stages xl/xr from global.
// ---------------------------------------------------------------------------
#define MAXNE 270
#define XLS   260   // padded XL row stride (channels)
#define SHP   264   // padded XR/H row stride (channels)
template<int CONV>
__global__ __launch_bounds__(256, 4) void gat_fused4(
    const int* __restrict__ ei, const bf* __restrict__ xlb, const bf* __restrict__ xrb,
    const bf* __restrict__ Wlr, const float* __restrict__ gbl, const float* __restrict__ gbr,
    const float* __restrict__ att, const float* __restrict__ gbias,
    const bf* __restrict__ Wf, const float* __restrict__ cbias,
    const float* __restrict__ lnw, const float* __restrict__ lnb,
    bf* __restrict__ yout, float* __restrict__ dalpha, float* __restrict__ dei,
    int E0, int ET, int EPG, int nn)
{
    __shared__ __align__(16) __bf16 sXL[32 * XLS];   // 16.25 KB (padded rows)
    __shared__ __align__(16) __bf16 sHX[33 * SHP];   // 17.0 KB: XR then H (stride SHP)
    __shared__ __align__(16) float sExp[MAXNE * 4];  // 4.2 KB; phase0: x scratch (CONV)
    __shared__ int   sSD[MAXNE];                     // src | dst<<16
    __shared__ unsigned short sList[MAXNE];
    __shared__ int   sCnt[32];
    __shared__ int   sOff[33];

    const int g = blockIdx.x, tid = threadIdx.x, wv = tid >> 6, lane = tid & 63;
    if (EPG + nn > MAXNE) return;
    const int NE = EPG + nn;
    const int frow = lane & 15;
    const int fq   = lane >> 4;

    // Phase 0a: edges + self loops; stage inputs; zero H row 32
    for (int k = tid; k < EPG; k += 256) {
        int s = ei[(size_t)g * EPG + k] - g * nn;
        int d = ei[(size_t)E0 + (size_t)g * EPG + k] - g * nn;
        s = min(max(s, 0), nn - 1);
        d = min(max(d, 0), nn - 1);
        sSD[k] = s | (d << 16);
    }
    for (int k = EPG + tid; k < NE; k += 256) {
        int node = k - EPG;
        sSD[k] = node | (node << 16);
    }
    if constexpr (CONV) {
        // stage x (bf16, [nn][64]) into XOR-swizzled scratch over sExp
        unsigned short* sXg = (unsigned short*)sExp;
        const uint4* gx = (const uint4*)(xlb + (size_t)g * nn * 64);   // xlb := xb
        for (int k = tid; k < nn * 8; k += 256) {
            int node = k >> 3, k8 = k & 7;
            *(uint4*)(sXg + node * 64 + ((k8 ^ (node & 7)) << 3)) = gx[k];
        }
        const uint4 zu = make_uint4(0u, 0u, 0u, 0u);
        for (int k = nn * 8 + tid; k < 32 * 8; k += 256) {
            int node = k >> 3, k8 = k & 7;
            *(uint4*)(sXg + node * 64 + ((k8 ^ (node & 7)) << 3)) = zu;
        }
        __bf16 z = (__bf16)0.f;
        for (int k = tid; k < SHP; k += 256) sHX[32 * SHP + k] = z;
    } else {
        const uint4* gxl = (const uint4*)(xlb + (size_t)g * nn * 256);
        const uint4* gxr = (const uint4*)(xrb + (size_t)g * nn * 256);
        for (int k = tid; k < nn * 32; k += 256) {
            int node = k >> 5, c8 = k & 31;
            *(uint4*)(sXL + node * XLS + c8 * 8) = gxl[k];
            *(uint4*)(sHX + node * SHP + c8 * 8) = gxr[k];
        }
    }
    if (tid < 32) sCnt[tid] = 0;
    __syncthreads();

    // Phase 0b: histogram + (CONV) mini-GEMM producing XL / XR
    for (int k = tid; k < NE; k += 256) atomicAdd(&sCnt[sSD[k] >> 16], 1);
    if constexpr (CONV) {
        const unsigned short* sXg = (const unsigned short*)sExp;
        bf16x8 axf[2][2];
        #pragma unroll
        for (int mr = 0; mr < 2; ++mr)
            #pragma unroll
            for (int kc = 0; kc < 2; ++kc) {
                int row = mr * 16 + frow;
                axf[mr][kc] = *(const bf16x8*)(sXg + row * 64 + (((kc * 4 + fq) ^ (row & 7)) << 3));
            }
        const int colw = wv * 64;
        #pragma unroll
        for (int out = 0; out < 2; ++out) {
            f32x4 ga[2][4];
            #pragma unroll
            for (int mr = 0; mr < 2; ++mr)
                #pragma unroll
                for (int ct = 0; ct < 4; ++ct) ga[mr][ct] = 0.f;
            #pragma unroll
            for (int kc = 0; kc < 2; ++kc)
                #pragma unroll
                for (int ct = 0; ct < 4; ++ct) {
                    const __bf16* bp = (const __bf16*)Wlr + (size_t)out * 16384 +
                        ((((size_t)(((colw >> 4) + ct) * 2 + kc) * 16 + frow) * 4 + fq) * 8);
                    bf16x8 bg = *(const bf16x8*)bp;
                    ga[0][ct] = __builtin_amdgcn_mfma_f32_16x16x32_bf16(axf[0][kc], bg, ga[0][ct], 0, 0, 0);
                    ga[1][ct] = __builtin_amdgcn_mfma_f32_16x16x32_bf16(axf[1][kc], bg, ga[1][ct], 0, 0, 0);
                }
            const float* bb = out ? gbr : gbl;
            #pragma unroll
            for (int ct = 0; ct < 4; ++ct) {
                int col = colw + ct * 16 + frow;
                float b = bb[col];
                #pragma unroll
                for (int mr = 0; mr < 2; ++mr)
                    #pragma unroll
                    for (int r = 0; r < 4; ++r) {
                        int row = mr * 16 + fq * 4 + r;
                        float v = clamp256(ga[mr][ct][r] + b);
                        if (out == 0) sXL[row * XLS + col] = (__bf16)v;
                        else          sHX[row * SHP + col] = (__bf16)v;
                    }
            }
        }
    }
    __syncthreads();
    if (tid < 32) {
        int acc = 0, last = 0;
        #pragma unroll
        for (int j = 0; j < 32; ++j) {
            int c = sCnt[j];
            if (j < tid) acc += c;
            if (j == 31) last = c;
        }
        sOff[tid] = acc;
        if (tid == 31) sOff[32] = acc + last;
        sCnt[tid] = 0;
    }
    __syncthreads();
    for (int k = tid; k < NE; k += 256) {
        int d = sSD[k] >> 16;
        int p = atomicAdd(&sCnt[d], 1);
        sList[sOff[d] + p] = (unsigned short)k;
    }

    // ei echo
    for (int k = tid; k < NE; k += 256) {
        int s, d; size_t eg;
        if (k < EPG) {
            int sd = sSD[k];
            s = g * nn + (sd & 0xffff); d = g * nn + (sd >> 16);
            eg = (size_t)g * EPG + k;
        }
        else { int node = g * nn + (k - EPG); s = d = node; eg = (size_t)E0 + (size_t)g * nn + (k - EPG); }
        dei[eg] = (float)s;
        dei[(size_t)ET + eg] = (float)d;
    }
    __syncthreads();

    // Phase 1: wave-per-edge scores (XR at stride SHP)
    const float4 attv = *(const float4*)(att + lane * 4);
    const int h4 = lane >> 4;
    for (int i = wv; i < NE; i += 4) {
        int sd = sSD[i];
        int srcl = sd & 0xffff, dstl = sd >> 16;
        bf16x4 a = *(const bf16x4*)(sXL + srcl * XLS + lane * 4);
        bf16x4 b = *(const bf16x4*)(sHX + dstl * SHP + lane * 4);
        float p = 0.f;
        {
            float v0 = (float)a[0] + (float)b[0]; v0 = v0 > 0.f ? v0 : 0.2f * v0; p += v0 * attv.x;
            float v1 = (float)a[1] + (float)b[1]; v1 = v1 > 0.f ? v1 : 0.2f * v1; p += v1 * attv.y;
            float v2 = (float)a[2] + (float)b[2]; v2 = v2 > 0.f ? v2 : 0.2f * v2; p += v2 * attv.z;
            float v3 = (float)a[3] + (float)b[3]; v3 = v3 > 0.f ? v3 : 0.2f * v3; p += v3 * attv.w;
        }
        p += __shfl_xor(p, 1); p += __shfl_xor(p, 2);
        p += __shfl_xor(p, 4); p += __shfl_xor(p, 8);
        if ((lane & 15) == 0)
            sExp[i * 4 + h4] = __expf(fminf(fmaxf(p, -60.f), 60.f));
    }
    __syncthreads();

    // Phase 2: 8-lane group per dst node; lane owns 32 channels.
    {
        const int grp  = wv * 8 + (lane >> 3);
        const int s8   = lane & 7;
        const int chb  = s8 * 32;
        const int head = s8 >> 1;
        bf* hrow = yout + ((size_t)g * 32 + grp) * 256 + chb;   // !CONV only

        if (grp < nn) {
            const int beg = sOff[grp], end = sOff[grp + 1];
            float den = 0.f;
            f32x4 acc[8];
            #pragma unroll
            for (int k2 = 0; k2 < 8; ++k2) acc[k2] = 0.f;

            for (int q = beg; q < end; ++q) {
                int e = sList[q];
                float ev = sExp[e * 4 + head];
                den += ev;
                const __bf16* xp = sXL + (sSD[e] & 0xffff) * XLS + chb;
                #pragma unroll
                for (int k2 = 0; k2 < 4; ++k2) {
                    bf16x8 xa = *(const bf16x8*)(xp + k2 * 8);
                    #pragma unroll
                    for (int j = 0; j < 4; ++j)
                        acc[k2 * 2][j]     += ev * (float)xa[j];
                    #pragma unroll
                    for (int j = 0; j < 4; ++j)
                        acc[k2 * 2 + 1][j] += ev * (float)xa[4 + j];
                }
            }
            const float rden = 1.f / fmaxf(den, 1e-30f);

            if (!(s8 & 1)) {
                for (int q = beg; q < end; ++q) {
                    int e = sList[q];
                    float al = fminf(fmaxf(sExp[e * 4 + head] * rden, 0.f), 1.f);
                    size_t eg = (e < EPG) ? ((size_t)g * EPG + e)
                                          : ((size_t)E0 + (size_t)g * nn + (e - EPG));
                    dalpha[eg * 4 + head] = al;
                }
            }

            #pragma unroll
            for (int k2 = 0; k2 < 8; ++k2) {
                float4 gbv = *(const float4*)(gbias + chb + k2 * 4);
                bf16x4 o;
                o[0] = (__bf16)clamp256(fmaxf(acc[k2][0] * rden + gbv.x, 0.f));
                o[1] = (__bf16)clamp256(fmaxf(acc[k2][1] * rden + gbv.y, 0.f));
                o[2] = (__bf16)clamp256(fmaxf(acc[k2][2] * rden + gbv.z, 0.f));
                o[3] = (__bf16)clamp256(fmaxf(acc[k2][3] * rden + gbv.w, 0.f));
                if constexpr (CONV) *(bf16x4*)(sHX + grp * SHP + chb + k2 * 4) = o;
                else                *(bf16x4*)(hrow + k2 * 4) = o;
            }
        } else {
            bf16x4 z; z[0] = (__bf16)0.f; z[1] = (__bf16)0.f; z[2] = (__bf16)0.f; z[3] = (__bf16)0.f;
            #pragma unroll
            for (int k2 = 0; k2 < 8; ++k2) {
                if constexpr (CONV) *(bf16x4*)(sHX + grp * SHP + chb + k2 * 4) = z;
                else                *(bf16x4*)(hrow + k2 * 4) = z;
            }
        }
    }

    // Phase 3 (CONV): y0 = relu(LN(conv3(h))) + h, per-wave 64 cols via MFMA
    if constexpr (CONV) {
        __syncthreads();
        const int colw = wv * 64;
        f32x4 c0[2][4];
        #pragma unroll
        for (int i = 0; i < 2; ++i)
            #pragma unroll
            for (int j = 0; j < 4; ++j) c0[i][j] = 0.f;

        #pragma unroll
        for (int kc = 0; kc < 8; ++kc) {
            bf16x8 af[3][2];
            #pragma unroll
            for (int t = 0; t < 3; ++t)
                #pragma unroll
                for (int mr = 0; mr < 2; ++mr) {
                    int l = mr * 16 + frow + t - 1;
                    int ar = ((unsigned)l < 32u) ? l : 32;
                    af[t][mr] = *(const bf16x8*)(sHX + ar * SHP + kc * 32 + fq * 8);
                }
            #pragma unroll
            for (int t = 0; t < 3; ++t) {
                bf16x8 bgs[4];
                #pragma unroll
                for (int nt = 0; nt < 4; ++nt) {
                    const __bf16* bp = (const __bf16*)Wf +
                        ((((size_t)(t * 16 + (colw >> 4) + nt) * 8 + kc) * 16 + frow) * 4 + fq) * 8;
                    bgs[nt] = *(const bf16x8*)bp;
                }
                #pragma unroll
                for (int nt = 0; nt < 4; ++nt) {
                    c0[0][nt] = __builtin_amdgcn_mfma_f32_16x16x32_bf16(af[t][0], bgs[nt], c0[0][nt], 0, 0, 0);
                    c0[1][nt] = __builtin_amdgcn_mfma_f32_16x16x32_bf16(af[t][1], bgs[nt], c0[1][nt], 0, 0, 0);
                }
            }
        }

        float bv[4];
        #pragma unroll
        for (int nt = 0; nt < 4; ++nt) bv[nt] = cbias[colw + nt * 16 + frow];
        float S[4], Q[4];
        #pragma unroll
        for (int nt = 0; nt < 4; ++nt) { S[nt] = 0.f; Q[nt] = 0.f; }
        #pragma unroll
        for (int mr = 0; mr < 2; ++mr)
            #pragma unroll
            for (int nt = 0; nt < 4; ++nt)
                #pragma unroll
                for (int r = 0; r < 4; ++r) {
                    int l = mr * 16 + fq * 4 + r;
                    if (l < nn) {
                        float v = sane(c0[mr][nt][r] + bv[nt]);
                        S[nt] += v; Q[nt] += v * v;
                    }
                }
        const float inv = 1.f / (float)nn;
        float mu[4], rsg[4];
        #pragma unroll
        for (int nt = 0; nt < 4; ++nt) {
            float s = S[nt], q = Q[nt];
            s += __shfl_xor(s, 16); s += __shfl_xor(s, 32);
            q += __shfl_xor(q, 16); q += __shfl_xor(q, 32);
            float m = s * inv;
            float var = q * inv - m * m;
            mu[nt]  = m;
            rsg[nt] = rsqrtf(fmaxf(var, 0.f) + 1e-5f);
        }
        float lw[2][4], lb2[2][4];
        #pragma unroll
        for (int p = 0; p < 2; ++p)
            #pragma unroll
            for (int r = 0; r < 4; ++r) {
                int l = p * 16 + fq * 4 + r;
                bool ok = l < nn;
                lw[p][r]  = ok ? lnw[l] : 0.f;
                lb2[p][r] = ok ? lnb[l] : 0.f;
            }
        #pragma unroll
        for (int nt = 0; nt < 4; ++nt) {
            const int colf = colw + nt * 16 + frow;
            #pragma unroll
            for (int mr = 0; mr < 2; ++mr)
                #pragma unroll
                for (int r = 0; r < 4; ++r) {
                    int l = mr * 16 + fq * 4 + r;
                    float outv = 0.f;
                    if (l < nn) {
                        float v = (sane(c0[mr][nt][r] + bv[nt]) - mu[nt]) * rsg[nt] * lw[mr][r] + lb2[mr][r];
                        v = fmaxf(v, 0.f);
                        float rr = (float)sHX[l * SHP + colf];
                        outv = clamp256(v + rr);
                    }
                    yout[((size_t)g * 32 + l) * 256 + colf] = __float2bfloat16(outv);
                }
        }
    }
}

// ---- fused weight prep ----
struct CvtSegs { const float* in[7]; bf* out[7]; int n[7]; };
__global__ void prep_cvt(CvtSegs s, int total)
{
    int idx = blockIdx.x * 256 + threadIdx.x;
    if (idx >= total) return;
    #pragma unroll
    for (int i = 0; i < 7; ++i) {
        if (idx < s.n[i]) { s.out[i][idx] = __float2bfloat16(s.in[i][idx]); return; }
        idx -= s.n[i];
    }
}
// taps, optionally swizzled for gemm_tcn's global_load_lds path
struct TapSegs { const float* w[3]; bf* o[3]; int cc[3]; int kk[3]; int swz[3]; };
__global__ void prep_taps3(TapSegs s, int total)
{
    int idx = blockIdx.x * 256 + threadIdx.x;
    if (idx >= total) return;
    #pragma unroll
    for (int i = 0; i < 3; ++i) {
        if (idx < s.cc[i]) {
            unsigned K = (unsigned)s.kk[i];
            unsigned co = (unsigned)idx / K, ci = (unsigned)idx % K;
            int dst = co * K + (s.swz[i] ? swzk(ci, co) : ci);
            #pragma unroll
            for (int k = 0; k < 3; ++k)
                s.o[i][(size_t)k * s.cc[i] + dst] = __float2bfloat16(s.w[i][(size_t)idx * 3 + k]);
            return;
        }
        idx -= s.cc[i];
    }
}
// downsample weights, optionally swizzled
__global__ void prep_wswz(const float* __restrict__ w, bf* __restrict__ o,
                          int total, int K, int swz)
{
    int idx = blockIdx.x * 256 + threadIdx.x;
    if (idx >= total) return;
    int co = idx / K, ci = idx % K;
    o[(size_t)co * K + (swz ? swzk(ci, co) : ci)] = __float2bfloat16(w[idx]);
}
// conv0 weights -> MFMA-fragment-contiguous layout (coalesced 1KB wave loads)
__global__ void prep_bfrag(const float* __restrict__ w, bf* __restrict__ o, int HC)
{
    int idx = blockIdx.x * 256 + threadIdx.x;
    if (idx >= HC * HC) return;
    int co = idx / HC, ci = idx % HC;
    int cg = co >> 4, fr = co & 15, kc = ci >> 5, fq = (ci >> 3) & 3, w8 = ci & 7;
    int NCg = HC >> 4, NKc = HC >> 5;
    #pragma unroll
    for (int t = 0; t < 3; ++t) {
        size_t dst = (((((size_t)t * NCg + cg) * NKc + kc) * 16 + fr) * 4 + fq) * 8 + w8;
        o[dst] = __float2bfloat16(w[(size_t)idx * 3 + t]);
    }
}
// GAT Wl/Wr [HC][FI] f32 -> MFMA-fragment layout [2][cg][kc][16][4][8] bf16
__global__ void prep_gwfrag(const float* __restrict__ wl, const float* __restrict__ wr,
                            bf* __restrict__ o, int HC, int FI)
{
    int idx = blockIdx.x * 256 + threadIdx.x;
    int tot = HC * FI;
    if (idx >= 2 * tot) return;
    const float* w = (idx < tot) ? wl : wr;
    int j = (idx < tot) ? idx : idx - tot;
    int col = j / FI, k = j % FI;
    int cg = col >> 4, fr = col & 15, kc = k >> 5, fq = (k >> 3) & 3, w8 = k & 7;
    size_t dst = (size_t)((idx < tot) ? 0 : 1) * tot +
        ((((size_t)(cg * (FI >> 5) + kc) * 16 + fr) * 4 + fq) * 8 + w8);
    o[dst] = __float2bfloat16(w[j]);
}

// fc1_w f32 [F1][ci*nn+l] -> bf16 W1t [F1][l*HC+ci], l padded to 32
__global__ void prep_fc1(const float* __restrict__ w, bf* __restrict__ o, int F1, int nn, int HC)
{
    int idx = blockIdx.x * 256 + threadIdx.x;
    int kw = 32 * HC;
    if (idx >= F1 * kw) return;
    int co = idx / kw, r = idx % kw, l = r / HC, ci = r % HC;
    float hv = 0.f;
    if (l < nn) hv = w[(size_t)co * (HC * nn) + ci * nn + l];
    o[idx] = __float2bfloat16(hv);
}

// fc1 split-K reduce: z1 = bf16(relu(sum_z partials + bias))
__global__ void fc1red(const bf* __restrict__ zp, const float* __restrict__ bias,
                       bf* __restrict__ o, int MN, int N, int S)
{
    int idx = blockIdx.x * 256 + threadIdx.x;
    if (idx >= MN) return;
    float s = 0.f;
    for (int z = 0; z < S; ++z) s += __bfloat162float(zp[(size_t)z * MN + idx]);
    o[idx] = __float2bfloat16(clamp256(fmaxf(s + bias[idx % N], 0.f)));
}

extern "C" void kernel_launch(void* const* d_in, const int* in_sizes, int n_in,
                              void* d_out, int out_size, void* d_ws, size_t ws_size,
                              hipStream_t stream)
{
    (void)n_in; (void)ws_size;
    const float* x   = (const float*)d_in[0];
    const float* Wl  = (const float*)d_in[1];  const float* bl  = (const float*)d_in[2];
    const float* Wr  = (const float*)d_in[3];  const float* br  = (const float*)d_in[4];
    const float* att = (const float*)d_in[5];  const float* gb  = (const float*)d_in[6];
    const float* t0w = (const float*)d_in[7];  const float* t0b = (const float*)d_in[8];
    const float* l0w = (const float*)d_in[9];  const float* l0b = (const float*)d_in[10];
    const float* t1w = (const float*)d_in[11]; const float* t1b = (const float*)d_in[12];
    const float* l1w = (const float*)d_in[13]; const float* l1b = (const float*)d_in[14];
    const float* d1w = (const float*)d_in[15]; const float* d1b = (const float*)d_in[16];
    const float* t2w = (const float*)d_in[17]; const float* t2b = (const float*)d_in[18];
    const float* l2w = (const float*)d_in[19]; const float* l2b = (const float*)d_in[20];
    const float* d2w = (const float*)d_in[21]; const float* d2b = (const float*)d_in[22];
    const float* f1w = (const float*)d_in[23]; const float* f1b = (const float*)d_in[24];
    const float* f2w = (const float*)d_in[25]; const float* f2b = (const float*)d_in[26];
    const float* f3w = (const float*)d_in[27]; const float* f3b = (const float*)d_in[28];
    const int*   ei  = (const int*)d_in[29];

    const int HC   = in_sizes[6];                        // 256
    const int F_IN = in_sizes[1] / (HC > 0 ? HC : 1);    // 64
    const int NN   = in_sizes[0] / (F_IN > 0 ? F_IN : 1);// 30720
    const int E0   = in_sizes[29] / 2;                   // 245760
    const int ET   = E0 + NN;                            // 276480
    int nn = in_sizes[9];  nn = nn < 1 ? 1 : (nn > 32 ? 32 : nn);  // 30
    const int NG   = NN / nn;                            // 1024
    const int EPG  = NG > 0 ? E0 / NG : 0;               // 240
    const int C1   = in_sizes[12];                       // 512
    const int C2   = in_sizes[18];                       // 256
    const int F1   = in_sizes[24];                       // 512
    const int F2   = in_sizes[26];                       // 256
    const int F3   = in_sizes[28];                       // 144
    const int NG2  = (NG + 1) / 2;

    float* dout   = (float*)d_out;
    float* dei    = dout + ((size_t)out_size - 2 * (size_t)ET);
    float* dalpha = dei - (size_t)ET * 4;

    // ---- path eligibility ----
    const bool fused0 = (HC == 256) && (F_IN == 64) && (nn >= 1) && (nn <= 32)
                        && (EPG + nn <= MAXNE) && ((NN % 64) == 0);
    const int  gcA = NG2, gcB = NG - NG2;
    const bool fastc = ((gcA * 32) % 256 == 0) && ((gcB * 32) % 256 == 0)
                       && (C1 % 64 == 0) && (C2 % 64 == 0)
                       && (HC % 32 == 0) && (C1 % 32 == 0);

    // ---- workspace map (42 MB) ----
    char* ws = (char*)d_ws;
    const size_t MB = 1ull << 20;
    bf*    xb   = (bf*)(ws);
    bf*    WkA  = (bf*)(ws + 4 * MB);
    bf*    WkB  = WkA + (size_t)3 * HC * HC;
    bf*    WkC  = WkB + (size_t)3 * C1 * HC;
    bf*    Wlb  = WkC + (size_t)3 * C2 * C1;
    bf*    Wrb  = Wlb + (size_t)HC * F_IN;
    bf*    f2wb = Wrb + (size_t)HC * F_IN;
    bf*    f3wb = f2wb + (size_t)F2 * F1;
    bf*    d1wb = f3wb + (size_t)F3 * F2;
    bf*    d2wb = d1wb + (size_t)C1 * HC;
    bf*    WkAf = d2wb + (size_t)C2 * C1;                // frag-layout conv0 weights
    bf*    WlrF = WkAf + (size_t)3 * HC * HC;            // frag-layout Wl/Wr (64KB)
    char*  S0   = ws + (size_t)(7.5 * MB);
    char*  S1   = ws + 25 * MB;

    bf*    xrb  = (bf*)S0;                               // fallback only
    bf*    hbuf = (bf*)S0;                               // fallback GAT output
    bf*    xlb  = (bf*)S1;                               // fallback only
    bf*    y0   = fused0 ? (bf*)S0 : (bf*)S1;
    bf*    y1c  = fused0 ? (bf*)S1 : (bf*)S0;
    char*  fcS  = fused0 ? S1 : S0;                      // FC staging region
    bf*    W1t  = (bf*)fcS;                              // 8.4 MB
    bf*    z1p  = (bf*)(fcS + (size_t)(8.5 * MB));       // 8 MB
    bf*    z1   = (bf*)(ws);                             // 1 MB (over dead xb)
    bf*    z2   = (bf*)(ws + 2 * MB);                    // 0.5 MB

    // ---- fused weight prep ----
    {
        CvtSegs cs;
        cs.in[0] = x;   cs.out[0] = xb;   cs.n[0] = NN * F_IN;
        cs.in[1] = Wl;  cs.out[1] = Wlb;  cs.n[1] = HC * F_IN;
        cs.in[2] = Wr;  cs.out[2] = Wrb;  cs.n[2] = HC * F_IN;
        cs.in[3] = f2w; cs.out[3] = f2wb; cs.n[3] = F2 * F1;
        cs.in[4] = f3w; cs.out[4] = f3wb; cs.n[4] = F3 * F2;
        cs.in[5] = nullptr; cs.out[5] = nullptr; cs.n[5] = 0;
        cs.in[6] = nullptr; cs.out[6] = nullptr; cs.n[6] = 0;
        int tot = 0; for (int i = 0; i < 5; ++i) tot += cs.n[i];
        prep_cvt<<<(tot + 255) / 256, 256, 0, stream>>>(cs, tot);
        TapSegs ts;
        ts.w[0] = t0w; ts.o[0] = WkA; ts.cc[0] = HC * HC; ts.kk[0] = HC; ts.swz[0] = 0;
        ts.w[1] = t1w; ts.o[1] = WkB; ts.cc[1] = C1 * HC; ts.kk[1] = HC; ts.swz[1] = fastc ? 1 : 0;
        ts.w[2] = t2w; ts.o[2] = WkC; ts.cc[2] = C2 * C1; ts.kk[2] = C1; ts.swz[2] = fastc ? 1 : 0;
        int tt = ts.cc[0] + ts.cc[1] + ts.cc[2];
        prep_taps3<<<(tt + 255) / 256, 256, 0, stream>>>(ts, tt);
        prep_wswz<<<(C1 * HC + 255) / 256, 256, 0, stream>>>(d1w, d1wb, C1 * HC, HC, fastc ? 1 : 0);
        prep_wswz<<<(C2 * C1 + 255) / 256, 256, 0, stream>>>(d2w, d2wb, C2 * C1, C1, fastc ? 1 : 0);
        if (fused0) {
            prep_bfrag<<<(HC * HC + 255) / 256, 256, 0, stream>>>(t0w, WkAf, HC);
            prep_gwfrag<<<(2 * HC * F_IN + 255) / 256, 256, 0, stream>>>(Wl, Wr, WlrF, HC, F_IN);
        }
    }

    // ---- GAT (+ input transforms + TCN block 0 when fused0) ----
    if (fused0) {
        gat_fused4<1><<<NG, 256, 0, stream>>>(ei, xb, nullptr, WlrF, bl, br,
                                              att, gb, WkAf, t0b, l0w, l0b,
                                              y0, dalpha, dei, E0, ET, EPG, nn);
    } else {
        gemm_tf<1, true><<<dim3((HC + 63) / 64, (NN + 63) / 64), 256, 0, stream>>>(
            xb, Wlb, Wrb, bl, br, nullptr, nullptr, (const bf*)xrb, HC,
            xlb, nullptr, HC, NN, HC, F_IN, 1, 5, 0, 0, nn, F_IN);
        gat_fused4<0><<<NG, 256, 0, stream>>>(ei, xlb, xrb, nullptr, nullptr, nullptr,
                                              att, gb, nullptr, nullptr, nullptr, nullptr,
                                              hbuf, dalpha, dei, E0, ET, EPG, nn);
        gemm_tf<3, false><<<dim3((HC + 63) / 64, NG * 32 / 64), 256, 0, stream>>>(
            hbuf, WkA, nullptr, t0b, nullptr, l0w, l0b, hbuf, HC,
            y0, nullptr, HC, NG * 32, HC, HC, 1, 2, 0, 1, nn, HC);
    }

    // ---- TCN blocks 1 & 2, two graph-chunks ----
    for (int c = 0; c < 2; ++c) {
        int g0 = c * NG2;
        int gc = (c == 0) ? NG2 : (NG - NG2);
        if (gc <= 0) continue;
        const bf* y0c = y0 + (size_t)g0 * 32 * HC;
        bf*       y2c = y0 + (size_t)g0 * 32 * HC;
        if (fastc) {
            gemm_tcn<3, true><<<dim3(C1 / 64, gc * 32 / 256), 256, 0, stream>>>(
                y0c, WkB, d1wb, t1b, d1b, l1w, l1b, nullptr, 0,
                y1c, C1, gc * 32, C1, HC, 2, nn);
            gemm_tcn<3, true><<<dim3(C2 / 64, gc * 32 / 256), 256, 0, stream>>>(
                y1c, WkC, d2wb, t2b, d2b, l2w, l2b, nullptr, 0,
                y2c, C2, gc * 32, C2, C1, 4, nn);
        } else {
            gemm_tf<3, true><<<dim3((C1 + 63) / 64, gc * 32 / 64), 256, 0, stream>>>(
                y0c, WkB, d1wb, t1b, d1b, l1w, l1b, nullptr, 0,
                y1c, nullptr, C1, gc * 32, C1, HC, 2, 2, 0, 1, nn, HC);
            gemm_tf<3, true><<<dim3((C2 + 63) / 64, gc * 32 / 64), 256, 0, stream>>>(
                y1c, WkC, d2wb, t2b, d2b, l2w, l2b, nullptr, 0,
                y2c, nullptr, C2, gc * 32, C2, C1, 4, 2, 0, 1, nn, C1);
        }
    }

    // ---- FC head ----
    prep_fc1<<<(F1 * 32 * HC + 255) / 256, 256, 0, stream>>>(f1w, W1t, F1, nn, HC);
    gemm_tf<1, false><<<dim3((F1 + 63) / 64, (NG + 63) / 64, 8), 256, 0, stream>>>(
        y0, W1t, nullptr, nullptr, nullptr, nullptr, nullptr, nullptr, 0,
        z1p, nullptr, F1, NG, F1, 32 * HC, 1, 3, 0, 0, nn, 4 * HC);
    fc1red<<<(NG * F1 + 255) / 256, 256, 0, stream>>>(z1p, f1b, z1, NG * F1, F1, 8);

    gemm_tf<1, false><<<dim3((F2 + 63) / 64, (NG + 63) / 64), 256, 0, stream>>>(
        z1, f2wb, nullptr, f2b, nullptr, nullptr, nullptr, nullptr, 0,
        z2, nullptr, F2, NG, F2, F1, 1, 0, 1, 0, nn, F1);
    gemm_tf<1, false><<<dim3((F3 + 63) / 64, (NG + 63) / 64), 256, 0, stream>>>(
        z2, f3wb, nullptr, f3b, nullptr, nullptr, nullptr, nullptr, 0,
        nullptr, dout, F3, NG, F3, F2, 1, 0, 0, 0, nn, F2);
}

// Round 11
// 410.423 us; speedup vs baseline: 1.3038x; 1.0331x over previous
//
#include <hip/hip_runtime.h>
#include <hip/hip_bf16.h>

typedef __bf16  bf16x8 __attribute__((ext_vector_type(8)));
typedef __bf16  bf16x4 __attribute__((ext_vector_type(4)));
typedef float   f32x4  __attribute__((ext_vector_type(4)));
typedef __hip_bfloat16 bf;

__device__ __forceinline__ float clamp256(float v) {
    return fminf(fmaxf(v, -256.f), 256.f);
}
__device__ __forceinline__ float sane(float v) {
    return fminf(fmaxf(v, -1e4f), 1e4f);
}
// 16B-chunk XOR swizzle baked into weight layout: spreads B-tile rows over
// 8 LDS bank-groups (2-way = free) while keeping global_load_lds linear.
__device__ __forceinline__ int swzk(int k, int col) {
    return (k & ~31) | ((((k >> 3) & 3) ^ ((col >> 1) & 3)) << 3) | (k & 7);
}

// ---------------------------------------------------------------------------
// Tap-fused, register-prefetch 64x64 bf16 MFMA GEMM (fallback GAT + FC head).
// mode 0: store (+bias,relu) -> outb bf16 or outf f32
// mode 2: register-resident LayerNorm(nn)+relu+residual (accR/Wd or res[])
// mode 3: split-K bf16 partials: outb[z*M*ostride + row*ostride + col]
// mode 5: dual output (HASWD): outb=accC+bias, res(cast bf*)=accR+biasd
// NOTE: expects UNSWIZZLED weights.
// ---------------------------------------------------------------------------
template<int TAPS, bool HASWD>
__global__ __launch_bounds__(256) void gemm_tf(
    const bf* __restrict__ A, const bf* __restrict__ Wt, const bf* __restrict__ Wd,
    const float* __restrict__ bias, const float* __restrict__ biasd,
    const float* __restrict__ lnw, const float* __restrict__ lnb,
    const bf* __restrict__ res, int res_stride,
    bf* __restrict__ outb, float* __restrict__ outf, int out_stride,
    int M, int N, int K, int dil, int mode, int relu, int padded, int nn, int kLen)
{
    constexpr int NT = TAPS + (HASWD ? 1 : 0);
    __shared__ __align__(16) unsigned short sA[66 * 40];      // 64 rows + zero row 64
    __shared__ __align__(16) unsigned short sB[NT][64 * 40];
    __shared__ float sS[4][64], sS2[4][64];

    const int tid  = threadIdx.x;
    const int wv   = tid >> 6;
    const int lane = tid & 63;
    const int m0   = blockIdx.y * 64;
    const int n0   = blockIdx.x * 64;
    const int frow = lane & 15;
    const int fq   = lane >> 4;
    const int kOff = blockIdx.z * kLen;
    const int kEnd = (kOff + kLen < K) ? (kOff + kLen) : K;

    if (tid < 40) sA[64 * 40 + tid] = (unsigned short)0;

    int aoff[NT];
    {
        int token = wv * 16 + frow;
        int b = token >> 5, l = token & 31;
        #pragma unroll
        for (int t = 0; t < NT; ++t) {
            int s = (t < TAPS) ? (t - TAPS / 2) * dil : 0;
            int ar;
            if (padded) {
                int ls = l + s;
                ar = ((unsigned)ls < 32u) ? (b * 32 + ls) : 64;
            } else {
                ar = token;
            }
            aoff[t] = ar * 40 + fq * 8;
        }
    }

    const int srow = tid >> 2;
    const int schk = (tid & 3) << 3;
    int raG = m0 + srow;
    if (!padded && raG >= M) raG = -1;
    const int rbG  = n0 + srow;
    const bool bval = rbG < N;
    const bf* Ap = (raG >= 0) ? (A + (size_t)raG * K) : nullptr;
    const bf* Bp[NT];
    #pragma unroll
    for (int t = 0; t < NT; ++t)
        Bp[t] = (HASWD && t == TAPS) ? (Wd + (size_t)rbG * K)
                                     : (Wt + ((size_t)t * N + rbG) * K);

    f32x4 accC[4], accR[4];
    #pragma unroll
    for (int i = 0; i < 4; ++i) { accC[i] = 0.f; accR[i] = 0.f; }

    const uint4 zu = make_uint4(0u, 0u, 0u, 0u);
    uint4 pa, pb[NT];
    pa = Ap ? *(const uint4*)(Ap + kOff + schk) : zu;
    #pragma unroll
    for (int t = 0; t < NT; ++t)
        pb[t] = bval ? *(const uint4*)(Bp[t] + kOff + schk) : zu;

    for (int kb = kOff; kb < kEnd; kb += 32) {
        __syncthreads();
        *(uint4*)(sA + srow * 40 + schk) = pa;
        #pragma unroll
        for (int t = 0; t < NT; ++t)
            *(uint4*)(&sB[t][srow * 40 + schk]) = pb[t];
        __syncthreads();
        int kn = kb + 32;
        if (kn < kEnd) {
            pa = Ap ? *(const uint4*)(Ap + kn + schk) : zu;
            #pragma unroll
            for (int t = 0; t < NT; ++t)
                pb[t] = bval ? *(const uint4*)(Bp[t] + kn + schk) : zu;
        }
        #pragma unroll
        for (int t = 0; t < TAPS; ++t) {
            bf16x8 af = *(const bf16x8*)(sA + aoff[t]);
            #pragma unroll
            for (int nt = 0; nt < 4; ++nt) {
                bf16x8 bg = *(const bf16x8*)(&sB[t][(nt * 16 + frow) * 40 + fq * 8]);
                accC[nt] = __builtin_amdgcn_mfma_f32_16x16x32_bf16(af, bg, accC[nt], 0, 0, 0);
            }
        }
        if constexpr (HASWD) {
            bf16x8 af = *(const bf16x8*)(sA + aoff[TAPS]);
            #pragma unroll
            for (int nt = 0; nt < 4; ++nt) {
                bf16x8 bg = *(const bf16x8*)(&sB[TAPS][(nt * 16 + frow) * 40 + fq * 8]);
                accR[nt] = __builtin_amdgcn_mfma_f32_16x16x32_bf16(af, bg, accR[nt], 0, 0, 0);
            }
        }
    }

    if (mode == 0) {
        #pragma unroll
        for (int nt = 0; nt < 4; ++nt) {
            int col = n0 + nt * 16 + frow;
            if (col >= N) continue;
            float bv = bias ? bias[col] : 0.f;
            #pragma unroll
            for (int r = 0; r < 4; ++r) {
                int row = m0 + wv * 16 + fq * 4 + r;
                if (row >= M) continue;
                float v = accC[nt][r] + bv;
                if (relu) v = fmaxf(v, 0.f);
                if (outb) outb[(size_t)row * out_stride + col] = __float2bfloat16(clamp256(v));
                else      outf[(size_t)row * out_stride + col] = sane(v);
            }
        }
    } else if (mode == 3) {
        bf* po = outb + (size_t)blockIdx.z * M * out_stride;
        #pragma unroll
        for (int nt = 0; nt < 4; ++nt) {
            int col = n0 + nt * 16 + frow;
            if (col >= N) continue;
            #pragma unroll
            for (int r = 0; r < 4; ++r) {
                int row = m0 + wv * 16 + fq * 4 + r;
                if (row >= M) continue;
                po[(size_t)row * out_stride + col] = __float2bfloat16(accC[nt][r]);
            }
        }
    } else if (mode == 5) {
        if constexpr (HASWD) {
            bf* out2 = (bf*)res;
            int orow_[4];
            #pragma unroll
            for (int r = 0; r < 4; ++r) {
                int row = m0 + wv * 16 + fq * 4 + r;
                orow_[r] = relu ? ((row / nn) * 32 + (row % nn)) : row;
            }
            #pragma unroll
            for (int nt = 0; nt < 4; ++nt) {
                int col = n0 + nt * 16 + frow;
                if (col >= N) continue;
                float bv = bias[col], bd = biasd[col];
                #pragma unroll
                for (int r = 0; r < 4; ++r) {
                    int row = m0 + wv * 16 + fq * 4 + r;
                    if (row >= M) continue;
                    outb[(size_t)row * out_stride + col] = __float2bfloat16(clamp256(accC[nt][r] + bv));
                    out2[(size_t)orow_[r] * res_stride + col] = __float2bfloat16(clamp256(accR[nt][r] + bd));
                }
            }
        }
    } else {  // mode 2
        float bvc[4], bdc[4];
        #pragma unroll
        for (int nt = 0; nt < 4; ++nt) {
            int col = n0 + nt * 16 + frow;
            bvc[nt] = bias[col];
            bdc[nt] = (HASWD && biasd) ? biasd[col] : 0.f;
        }
        float s[4], s2[4];
        #pragma unroll
        for (int nt = 0; nt < 4; ++nt) { s[nt] = 0.f; s2[nt] = 0.f; }
        #pragma unroll
        for (int nt = 0; nt < 4; ++nt)
            #pragma unroll
            for (int r = 0; r < 4; ++r) {
                int row = wv * 16 + fq * 4 + r;
                int l = row & 31;
                float v = sane(accC[nt][r] + bvc[nt]);
                if (l < nn) { s[nt] += v; s2[nt] += v * v; }
            }
        #pragma unroll
        for (int nt = 0; nt < 4; ++nt) {
            s[nt]  += __shfl_xor(s[nt], 16);  s[nt]  += __shfl_xor(s[nt], 32);
            s2[nt] += __shfl_xor(s2[nt], 16); s2[nt] += __shfl_xor(s2[nt], 32);
        }
        if (fq == 0) {
            #pragma unroll
            for (int nt = 0; nt < 4; ++nt) {
                sS[wv][nt * 16 + frow]  = s[nt];
                sS2[wv][nt * 16 + frow] = s2[nt];
            }
        }
        __syncthreads();
        const int gi = wv >> 1;
        const float inv = 1.f / (float)nn;
        #pragma unroll
        for (int nt = 0; nt < 4; ++nt) {
            int c = nt * 16 + frow;
            int colg = n0 + c;
            float S  = sS[2 * gi][c]  + sS[2 * gi + 1][c];
            float S2 = sS2[2 * gi][c] + sS2[2 * gi + 1][c];
            float mu = S * inv;
            float var = S2 * inv - mu * mu;
            float rs = rsqrtf(fmaxf(var, 0.f) + 1e-5f);
            #pragma unroll
            for (int r = 0; r < 4; ++r) {
                int row = wv * 16 + fq * 4 + r;
                int l = row & 31;
                int grow = m0 + row;
                float outv = 0.f;
                if (l < nn) {
                    float v = (sane(accC[nt][r] + bvc[nt]) - mu) * rs * lnw[l] + lnb[l];
                    v = fmaxf(v, 0.f);
                    float rr;
                    if constexpr (HASWD) rr = sane(accR[nt][r] + bdc[nt]);
                    else rr = __bfloat162float(res[(size_t)grow * res_stride + colg]);
                    outv = clamp256(v + rr);
                }
                outb[(size_t)grow * out_stride + colg] = __float2bfloat16(outv);
            }
        }
    }
}

// ---------------------------------------------------------------------------
// TCN tap-fused GEMM v5: (64*MR)x64 macro-tile, (16*MR)x64 per wave.
// DMA-staged B (pre-swizzled weights), double-buffered sA, ONE barrier/K-step.
// MR=4: LDS 74 KB, 2 blocks/CU (VGPR-limited anyway).
// MR=2: LDS 53 KB, 3 blocks/CU (acc halves to 64 AGPR) -> used for TCN2,
//       whose 256-row grid was only 1 block/CU (the round-10 bottleneck).
// ---------------------------------------------------------------------------
template<int TAPS, bool HASWD, int MR>
__global__ __launch_bounds__(256, (MR == 2) ? 3 : 2) void gemm_tcn(
    const bf* __restrict__ A, const bf* __restrict__ Wt, const bf* __restrict__ Wd,
    const float* __restrict__ bias, const float* __restrict__ biasd,
    const float* __restrict__ lnw, const float* __restrict__ lnb,
    const bf* __restrict__ res, int res_stride,
    bf* __restrict__ outb, int out_stride,
    int M, int N, int K, int dil, int nn)
{
    constexpr int NT = TAPS + (HASWD ? 1 : 0);
    constexpr int ROWS = 64 * MR;
    constexpr int GH = (MR >= 4) ? 2 : 1;                          // graphs per wave
    constexpr int SA = (ROWS + 1) * 40;                            // shorts per A buffer
    __shared__ __align__(16) unsigned short sA[2 * SA];            // dbuf A + zero rows
    __shared__ __align__(16) unsigned short sBall[2 * NT * 64 * 32];

    const int tid  = threadIdx.x;
    const int wv   = tid >> 6;
    const int lane = tid & 63;
    const int frow = lane & 15;
    const int fq   = lane >> 4;

    const int gx  = gridDim.x;
    const int nwg = gx * gridDim.y;
    int wg = blockIdx.y * gx + blockIdx.x;
    if ((nwg & 7) == 0) wg = (wg & 7) * (nwg >> 3) + (wg >> 3);
    const int n0 = (wg % gx) * 64;
    const int m0 = (wg / gx) * ROWS;

    if (tid < 40) {                                 // zero row ROWS of BOTH buffers
        sA[ROWS * 40 + tid]      = (unsigned short)0;
        sA[SA + ROWS * 40 + tid] = (unsigned short)0;
    }

    int aoff[TAPS][MR];
    #pragma unroll
    for (int mr = 0; mr < MR; ++mr) {
        int token = wv * (16 * MR) + mr * 16 + frow;
        int b5 = token >> 5, l = token & 31;
        #pragma unroll
        for (int t = 0; t < TAPS; ++t) {
            int ls = l + (t - TAPS / 2) * dil;
            int ar = ((unsigned)ls < 32u) ? (b5 * 32 + ls) : ROWS;
            aoff[t][mr] = ar * 40 + fq * 8;
        }
    }
    const int bco = (fq ^ ((frow >> 1) & 3)) << 3;

    const int srow = tid >> 2;
    const int chS  = (tid & 3) << 3;
    const bf* Ap = A + (size_t)(m0 + srow) * K + chS;

    const bf* bsrc[4];
    {
        int lr = lane >> 2, lc = lane & 3;
        #pragma unroll
        for (int i = 0; i < 4; ++i) {
            int colb = n0 + i * 16 + lr;
            const bf* Wb;
            if (HASWD && wv == TAPS) Wb = Wd + (size_t)colb * K;
            else if (wv < TAPS)      Wb = Wt + ((size_t)wv * N + colb) * K;
            else                     Wb = Wt + (size_t)colb * K;
            bsrc[i] = Wb + lc * 8;
        }
    }

    f32x4 accC[MR][4], accR[MR][4];
    #pragma unroll
    for (int i = 0; i < MR; ++i)
        #pragma unroll
        for (int j = 0; j < 4; ++j) { accC[i][j] = 0.f; if (HASWD) accR[i][j] = 0.f; }

    #define ISSUE_B(BUFB, KBS)                                                      \
        if (wv < NT) {                                                              \
            unsigned short* bas = sBall + ((size_t)((BUFB) * NT + wv) * 64) * 32;   \
            _Pragma("unroll")                                                       \
            for (int i = 0; i < 4; ++i) {                                           \
                __builtin_amdgcn_global_load_lds(                                   \
                    (const __attribute__((address_space(1))) void*)(bsrc[i] + (KBS)), \
                    (__attribute__((address_space(3))) void*)(bas + i * 512),       \
                    16, 0, 0);                                                      \
            }                                                                       \
        }

    // prologue: stage step 0 (A regs -> sA[0]; B via DMA -> sB[0])
    uint4 pa[MR];
    #pragma unroll
    for (int i = 0; i < MR; ++i) pa[i] = *(const uint4*)(Ap + (size_t)i * 64 * K);
    ISSUE_B(0, 0);
    #pragma unroll
    for (int i = 0; i < MR; ++i)
        *(uint4*)(sA + (srow + i * 64) * 40 + chS) = pa[i];
    __syncthreads();                               // step-0 A writes + B DMA done

    int buf = 0;
    for (int kb = 0; kb < K; kb += 32) {
        int kn = kb + 32;
        if (kn < K) {                              // issue next-step loads EARLY
            #pragma unroll
            for (int i = 0; i < MR; ++i)
                pa[i] = *(const uint4*)(Ap + (size_t)i * 64 * K + kn);
            ISSUE_B(buf ^ 1, kn);
        }
        const unsigned short* sAb = sA + (size_t)buf * SA;
        const unsigned short* sBb = sBall + (size_t)buf * NT * 2048;
        bf16x8 aMid[MR];
        #pragma unroll
        for (int mr = 0; mr < MR; ++mr)
            aMid[mr] = *(const bf16x8*)(sAb + aoff[TAPS / 2][mr]);
        #pragma unroll
        for (int t = 0; t < TAPS; ++t) {
            bf16x8 af[MR];
            #pragma unroll
            for (int mr = 0; mr < MR; ++mr)
                af[mr] = (t == TAPS / 2) ? aMid[mr]
                                         : *(const bf16x8*)(sAb + aoff[t][mr]);
            #pragma unroll
            for (int nt = 0; nt < 4; ++nt) {
                bf16x8 bg = *(const bf16x8*)(sBb + (size_t)t * 2048 + (nt * 16 + frow) * 32 + bco);
                #pragma unroll
                for (int mr = 0; mr < MR; ++mr)
                    accC[mr][nt] = __builtin_amdgcn_mfma_f32_16x16x32_bf16(af[mr], bg, accC[mr][nt], 0, 0, 0);
            }
        }
        if constexpr (HASWD) {
            #pragma unroll
            for (int nt = 0; nt < 4; ++nt) {
                bf16x8 bg = *(const bf16x8*)(sBb + (size_t)TAPS * 2048 + (nt * 16 + frow) * 32 + bco);
                #pragma unroll
                for (int mr = 0; mr < MR; ++mr)
                    accR[mr][nt] = __builtin_amdgcn_mfma_f32_16x16x32_bf16(aMid[mr], bg, accR[mr][nt], 0, 0, 0);
            }
        }
        if (kn < K) {                              // pa landed under the MFMAs
            unsigned short* sAn = sA + (size_t)(buf ^ 1) * SA;
            #pragma unroll
            for (int i = 0; i < MR; ++i)
                *(uint4*)(sAn + (srow + i * 64) * 40 + chS) = pa[i];
        }
        __syncthreads();                           // ONE barrier per K-step
        buf ^= 1;
    }
    #undef ISSUE_B

    float bvc[4], bdc[4];
    #pragma unroll
    for (int nt = 0; nt < 4; ++nt) {
        int col = n0 + nt * 16 + frow;
        bvc[nt] = bias[col];
        bdc[nt] = HASWD ? biasd[col] : 0.f;
    }
    float S[GH][4], Q[GH][4];
    #pragma unroll
    for (int h = 0; h < GH; ++h)
        #pragma unroll
        for (int nt = 0; nt < 4; ++nt) { S[h][nt] = 0.f; Q[h][nt] = 0.f; }
    #pragma unroll
    for (int mr = 0; mr < MR; ++mr) {
        const int h = mr >> 1;
        #pragma unroll
        for (int nt = 0; nt < 4; ++nt)
            #pragma unroll
            for (int r = 0; r < 4; ++r) {
                int l = (mr & 1) * 16 + fq * 4 + r;
                if (l < nn) {
                    float v = sane(accC[mr][nt][r] + bvc[nt]);
                    S[h][nt] += v; Q[h][nt] += v * v;
                }
            }
    }
    const float inv = 1.f / (float)nn;
    float mu[GH][4], rsg[GH][4];
    #pragma unroll
    for (int h = 0; h < GH; ++h)
        #pragma unroll
        for (int nt = 0; nt < 4; ++nt) {
            float s = S[h][nt], q = Q[h][nt];
            s += __shfl_xor(s, 16); s += __shfl_xor(s, 32);
            q += __shfl_xor(q, 16); q += __shfl_xor(q, 32);
            float m = s * inv;
            float var = q * inv - m * m;
            mu[h][nt]  = m;
            rsg[h][nt] = rsqrtf(fmaxf(var, 0.f) + 1e-5f);
        }
    float lw[2][4], lb2[2][4];
    #pragma unroll
    for (int p = 0; p < 2; ++p)
        #pragma unroll
        for (int r = 0; r < 4; ++r) {
            int l = p * 16 + fq * 4 + r;
            bool ok = l < nn;
            lw[p][r]  = ok ? lnw[l] : 0.f;
            lb2[p][r] = ok ? lnb[l] : 0.f;
        }
    #pragma unroll
    for (int nt = 0; nt < 4; ++nt) {
        const int colg = n0 + nt * 16 + frow;
        #pragma unroll
        for (int mr = 0; mr < MR; ++mr) {
            const int h = mr >> 1, p = mr & 1;
            #pragma unroll
            for (int r = 0; r < 4; ++r) {
                int l = p * 16 + fq * 4 + r;
                int grow = m0 + wv * (16 * MR) + mr * 16 + fq * 4 + r;
                float outv = 0.f;
                if (l < nn) {
                    float v = (sane(accC[mr][nt][r] + bvc[nt]) - mu[h][nt]) * rsg[h][nt] * lw[p][r] + lb2[p][r];
                    v = fmaxf(v, 0.f);
                    float rr;
                    if constexpr (HASWD) rr = sane(accR[mr][nt][r] + bdc[nt]);
                    else rr = __bfloat162float(res[(size_t)grow * res_stride + colg]);
                    outv = clamp256(v + rr);
                }
                outb[(size_t)grow * out_stride + colg] = __float2bfloat16(outv);
            }
        }
    }
}

// ---------------------------------------------------------------------------
// Fused per-graph GAT v6.1. CONV=1: fuses input transforms + TCN block 0.
// Alpha echo: dens stored to sDen, then a COALESCED per-edge pass (16B/thread,
// consecutive eg) after the phase-2 barrier (was a divergent per-group walk).
// LDS 40776 B -> 4 blocks/CU.
// ---------------------------------------------------------------------------
#define MAXNE 270
#define XLS   260   // padded XL row stride (channels)
#define SHP   264   // padded XR/H row stride (channels)
template<int CONV>
__global__ __launch_bounds__(256, 4) void gat_fused4(
    const int* __restrict__ ei, const bf* __restrict__ xlb, const bf* __restrict__ xrb,
    const bf* __restrict__ Wlr, const float* __restrict__ gbl, const float* __restrict__ gbr,
    const float* __restrict__ att, const float* __restrict__ gbias,
    const bf* __restrict__ Wf, const float* __restrict__ cbias,
    const float* __restrict__ lnw, const float* __restrict__ lnb,
    bf* __restrict__ yout, float* __restrict__ dalpha, float* __restrict__ dei,
    int E0, int ET, int EPG, int nn)
{
    __shared__ __align__(16) __bf16 sXL[32 * XLS];   // 16.25 KB (padded rows)
    __shared__ __align__(16) __bf16 sHX[33 * SHP];   // 17.0 KB: XR then H (stride SHP)
    __shared__ __align__(16) float sExp[MAXNE * 4];  // 4.2 KB; phase0: x scratch (CONV)
    __shared__ int   sSD[MAXNE];                     // src | dst<<16
    __shared__ unsigned short sList[MAXNE];
    __shared__ float sDen[128];                      // [dst*4 + head]
    __shared__ int   sCnt[32];
    __shared__ int   sOff[33];

    const int g = blockIdx.x, tid = threadIdx.x, wv = tid >> 6, lane = tid & 63;
    if (EPG + nn > MAXNE) return;
    const int NE = EPG + nn;
    const int frow = lane & 15;
    const int fq   = lane >> 4;

    // Phase 0a: edges + self loops; stage inputs; zero H row 32
    for (int k = tid; k < EPG; k += 256) {
        int s = ei[(size_t)g * EPG + k] - g * nn;
        int d = ei[(size_t)E0 + (size_t)g * EPG + k] - g * nn;
        s = min(max(s, 0), nn - 1);
        d = min(max(d, 0), nn - 1);
        sSD[k] = s | (d << 16);
    }
    for (int k = EPG + tid; k < NE; k += 256) {
        int node = k - EPG;
        sSD[k] = node | (node << 16);
    }
    if constexpr (CONV) {
        // stage x (bf16, [nn][64]) into XOR-swizzled scratch over sExp
        unsigned short* sXg = (unsigned short*)sExp;
        const uint4* gx = (const uint4*)(xlb + (size_t)g * nn * 64);   // xlb := xb
        for (int k = tid; k < nn * 8; k += 256) {
            int node = k >> 3, k8 = k & 7;
            *(uint4*)(sXg + node * 64 + ((k8 ^ (node & 7)) << 3)) = gx[k];
        }
        const uint4 zu = make_uint4(0u, 0u, 0u, 0u);
        for (int k = nn * 8 + tid; k < 32 * 8; k += 256) {
            int node = k >> 3, k8 = k & 7;
            *(uint4*)(sXg + node * 64 + ((k8 ^ (node & 7)) << 3)) = zu;
        }
        __bf16 z = (__bf16)0.f;
        for (int k = tid; k < SHP; k += 256) sHX[32 * SHP + k] = z;
    } else {
        const uint4* gxl = (const uint4*)(xlb + (size_t)g * nn * 256);
        const uint4* gxr = (const uint4*)(xrb + (size_t)g * nn * 256);
        for (int k = tid; k < nn * 32; k += 256) {
            int node = k >> 5, c8 = k & 31;
            *(uint4*)(sXL + node * XLS + c8 * 8) = gxl[k];
            *(uint4*)(sHX + node * SHP + c8 * 8) = gxr[k];
        }
    }
    if (tid < 32) sCnt[tid] = 0;
    __syncthreads();

    // Phase 0b: histogram + (CONV) mini-GEMM producing XL / XR
    for (int k = tid; k < NE; k += 256) atomicAdd(&sCnt[sSD[k] >> 16], 1);
    if constexpr (CONV) {
        const unsigned short* sXg = (const unsigned short*)sExp;
        bf16x8 axf[2][2];
        #pragma unroll
        for (int mr = 0; mr < 2; ++mr)
            #pragma unroll
            for (int kc = 0; kc < 2; ++kc) {
                int row = mr * 16 + frow;
                axf[mr][kc] = *(const bf16x8*)(sXg + row * 64 + (((kc * 4 + fq) ^ (row & 7)) << 3));
            }
        const int colw = wv * 64;
        #pragma unroll
        for (int out = 0; out < 2; ++out) {
            f32x4 ga[2][4];
            #pragma unroll
            for (int mr = 0; mr < 2; ++mr)
                #pragma unroll
                for (int ct = 0; ct < 4; ++ct) ga[mr][ct] = 0.f;
            #pragma unroll
            for (int kc = 0; kc < 2; ++kc)
                #pragma unroll
                for (int ct = 0; ct < 4; ++ct) {
                    const __bf16* bp = (const __bf16*)Wlr + (size_t)out * 16384 +
                        ((((size_t)(((colw >> 4) + ct) * 2 + kc) * 16 + frow) * 4 + fq) * 8);
                    bf16x8 bg = *(const bf16x8*)bp;
                    ga[0][ct] = __builtin_amdgcn_mfma_f32_16x16x32_bf16(axf[0][kc], bg, ga[0][ct], 0, 0, 0);
                    ga[1][ct] = __builtin_amdgcn_mfma_f32_16x16x32_bf16(axf[1][kc], bg, ga[1][ct], 0, 0, 0);
                }
            const float* bb = out ? gbr : gbl;
            #pragma unroll
            for (int ct = 0; ct < 4; ++ct) {
                int col = colw + ct * 16 + frow;
                float b = bb[col];
                #pragma unroll
                for (int mr = 0; mr < 2; ++mr)
                    #pragma unroll
                    for (int r = 0; r < 4; ++r) {
                        int row = mr * 16 + fq * 4 + r;
                        float v = clamp256(ga[mr][ct][r] + b);
                        if (out == 0) sXL[row * XLS + col] = (__bf16)v;
                        else          sHX[row * SHP + col] = (__bf16)v;
                    }
            }
        }
    }
    __syncthreads();
    if (tid < 32) {
        int acc = 0, last = 0;
        #pragma unroll
        for (int j = 0; j < 32; ++j) {
            int c = sCnt[j];
            if (j < tid) acc += c;
            if (j == 31) last = c;
        }
        sOff[tid] = acc;
        if (tid == 31) sOff[32] = acc + last;
        sCnt[tid] = 0;
    }
    __syncthreads();
    for (int k = tid; k < NE; k += 256) {
        int d = sSD[k] >> 16;
        int p = atomicAdd(&sCnt[d], 1);
        sList[sOff[d] + p] = (unsigned short)k;
    }

    // ei echo
    for (int k = tid; k < NE; k += 256) {
        int s, d; size_t eg;
        if (k < EPG) {
            int sd = sSD[k];
            s = g * nn + (sd & 0xffff); d = g * nn + (sd >> 16);
            eg = (size_t)g * EPG + k;
        }
        else { int node = g * nn + (k - EPG); s = d = node; eg = (size_t)E0 + (size_t)g * nn + (k - EPG); }
        dei[eg] = (float)s;
        dei[(size_t)ET + eg] = (float)d;
    }
    __syncthreads();

    // Phase 1: wave-per-edge scores (XR at stride SHP)
    const float4 attv = *(const float4*)(att + lane * 4);
    const int h4 = lane >> 4;
    for (int i = wv; i < NE; i += 4) {
        int sd = sSD[i];
        int srcl = sd & 0xffff, dstl = sd >> 16;
        bf16x4 a = *(const bf16x4*)(sXL + srcl * XLS + lane * 4);
        bf16x4 b = *(const bf16x4*)(sHX + dstl * SHP + lane * 4);
        float p = 0.f;
        {
            float v0 = (float)a[0] + (float)b[0]; v0 = v0 > 0.f ? v0 : 0.2f * v0; p += v0 * attv.x;
            float v1 = (float)a[1] + (float)b[1]; v1 = v1 > 0.f ? v1 : 0.2f * v1; p += v1 * attv.y;
            float v2 = (float)a[2] + (float)b[2]; v2 = v2 > 0.f ? v2 : 0.2f * v2; p += v2 * attv.z;
            float v3 = (float)a[3] + (float)b[3]; v3 = v3 > 0.f ? v3 : 0.2f * v3; p += v3 * attv.w;
        }
        p += __shfl_xor(p, 1); p += __shfl_xor(p, 2);
        p += __shfl_xor(p, 4); p += __shfl_xor(p, 8);
        if ((lane & 15) == 0)
            sExp[i * 4 + h4] = __expf(fminf(fmaxf(p, -60.f), 60.f));
    }
    __syncthreads();

    // Phase 2: 8-lane group per dst node; lane owns 32 channels.
    {
        const int grp  = wv * 8 + (lane >> 3);
        const int s8   = lane & 7;
        const int chb  = s8 * 32;
        const int head = s8 >> 1;
        bf* hrow = yout + ((size_t)g * 32 + grp) * 256 + chb;   // !CONV only

        if (grp < nn) {
            const int beg = sOff[grp], end = sOff[grp + 1];
            float den = 0.f;
            f32x4 acc[8];
            #pragma unroll
            for (int k2 = 0; k2 < 8; ++k2) acc[k2] = 0.f;

            for (int q = beg; q < end; ++q) {
                int e = sList[q];
                float ev = sExp[e * 4 + head];
                den += ev;
                const __bf16* xp = sXL + (sSD[e] & 0xffff) * XLS + chb;
                #pragma unroll
                for (int k2 = 0; k2 < 4; ++k2) {
                    bf16x8 xa = *(const bf16x8*)(xp + k2 * 8);
                    #pragma unroll
                    for (int j = 0; j < 4; ++j)
                        acc[k2 * 2][j]     += ev * (float)xa[j];
                    #pragma unroll
                    for (int j = 0; j < 4; ++j)
                        acc[k2 * 2 + 1][j] += ev * (float)xa[4 + j];
                }
            }
            if (!(s8 & 1)) sDen[grp * 4 + head] = den;
            const float rden = 1.f / fmaxf(den, 1e-30f);

            #pragma unroll
            for (int k2 = 0; k2 < 8; ++k2) {
                float4 gbv = *(const float4*)(gbias + chb + k2 * 4);
                bf16x4 o;
                o[0] = (__bf16)clamp256(fmaxf(acc[k2][0] * rden + gbv.x, 0.f));
                o[1] = (__bf16)clamp256(fmaxf(acc[k2][1] * rden + gbv.y, 0.f));
                o[2] = (__bf16)clamp256(fmaxf(acc[k2][2] * rden + gbv.z, 0.f));
                o[3] = (__bf16)clamp256(fmaxf(acc[k2][3] * rden + gbv.w, 0.f));
                if constexpr (CONV) *(bf16x4*)(sHX + grp * SHP + chb + k2 * 4) = o;
                else                *(bf16x4*)(hrow + k2 * 4) = o;
            }
        } else {
            bf16x4 z; z[0] = (__bf16)0.f; z[1] = (__bf16)0.f; z[2] = (__bf16)0.f; z[3] = (__bf16)0.f;
            #pragma unroll
            for (int k2 = 0; k2 < 8; ++k2) {
                if constexpr (CONV) *(bf16x4*)(sHX + grp * SHP + chb + k2 * 4) = z;
                else                *(bf16x4*)(hrow + k2 * 4) = z;
            }
        }
    }
    __syncthreads();   // sDen + sHX(H) complete

    // Alpha echo: coalesced per-edge pass (16B float4 per thread, eg-contiguous)
    for (int k = tid; k < NE; k += 256) {
        int d = sSD[k] >> 16;
        size_t eg = (k < EPG) ? ((size_t)g * EPG + k)
                              : ((size_t)E0 + (size_t)g * nn + (k - EPG));
        float4 al;
        al.x = fminf(fmaxf(sExp[k * 4 + 0] / fmaxf(sDen[d * 4 + 0], 1e-30f), 0.f), 1.f);
        al.y = fminf(fmaxf(sExp[k * 4 + 1] / fmaxf(sDen[d * 4 + 1], 1e-30f), 0.f), 1.f);
        al.z = fminf(fmaxf(sExp[k * 4 + 2] / fmaxf(sDen[d * 4 + 2], 1e-30f), 0.f), 1.f);
        al.w = fminf(fmaxf(sExp[k * 4 + 3] / fmaxf(sDen[d * 4 + 3], 1e-30f), 0.f), 1.f);
        *(float4*)(dalpha + eg * 4) = al;
    }

    // Phase 3 (CONV): y0 = relu(LN(conv3(h))) + h, per-wave 64 cols via MFMA
    if constexpr (CONV) {
        const int colw = wv * 64;
        f32x4 c0[2][4];
        #pragma unroll
        for (int i = 0; i < 2; ++i)
            #pragma unroll
            for (int j = 0; j < 4; ++j) c0[i][j] = 0.f;

        #pragma unroll
        for (int kc = 0; kc < 8; ++kc) {
            bf16x8 af[3][2];
            #pragma unroll
            for (int t = 0; t < 3; ++t)
                #pragma unroll
                for (int mr = 0; mr < 2; ++mr) {
                    int l = mr * 16 + frow + t - 1;
                    int ar = ((unsigned)l < 32u) ? l : 32;
                    af[t][mr] = *(const bf16x8*)(sHX + ar * SHP + kc * 32 + fq * 8);
                }
            #pragma unroll
            for (int t = 0; t < 3; ++t) {
                bf16x8 bgs[4];
                #pragma unroll
                for (int nt = 0; nt < 4; ++nt) {
                    const __bf16* bp = (const __bf16*)Wf +
                        ((((size_t)(t * 16 + (colw >> 4) + nt) * 8 + kc) * 16 + frow) * 4 + fq) * 8;
                    bgs[nt] = *(const bf16x8*)bp;
                }
                #pragma unroll
                for (int nt = 0; nt < 4; ++nt) {
                    c0[0][nt] = __builtin_amdgcn_mfma_f32_16x16x32_bf16(af[t][0], bgs[nt], c0[0][nt], 0, 0, 0);
                    c0[1][nt] = __builtin_amdgcn_mfma_f32_16x16x32_bf16(af[t][1], bgs[nt], c0[1][nt], 0, 0, 0);
                }
            }
        }

        float bv[4];
        #pragma unroll
        for (int nt = 0; nt < 4; ++nt) bv[nt] = cbias[colw + nt * 16 + frow];
        float S[4], Q[4];
        #pragma unroll
        for (int nt = 0; nt < 4; ++nt) { S[nt] = 0.f; Q[nt] = 0.f; }
        #pragma unroll
        for (int mr = 0; mr < 2; ++mr)
            #pragma unroll
            for (int nt = 0; nt < 4; ++nt)
                #pragma unroll
                for (int r = 0; r < 4; ++r) {
                    int l = mr * 16 + fq * 4 + r;
                    if (l < nn) {
                        float v = sane(c0[mr][nt][r] + bv[nt]);
                        S[nt] += v; Q[nt] += v * v;
                    }
                }
        const float inv = 1.f / (float)nn;
        float mu[4], rsg[4];
        #pragma unroll
        for (int nt = 0; nt < 4; ++nt) {
            float s = S[nt], q = Q[nt];
            s += __shfl_xor(s, 16); s += __shfl_xor(s, 32);
            q += __shfl_xor(q, 16); q += __shfl_xor(q, 32);
            float m = s * inv;
            float var = q * inv - m * m;
            mu[nt]  = m;
            rsg[nt] = rsqrtf(fmaxf(var, 0.f) + 1e-5f);
        }
        float lw[2][4], lb2[2][4];
        #pragma unroll
        for (int p = 0; p < 2; ++p)
            #pragma unroll
            for (int r = 0; r < 4; ++r) {
                int l = p * 16 + fq * 4 + r;
                bool ok = l < nn;
                lw[p][r]  = ok ? lnw[l] : 0.f;
                lb2[p][r] = ok ? lnb[l] : 0.f;
            }
        #pragma unroll
        for (int nt = 0; nt < 4; ++nt) {
            const int colf = colw + nt * 16 + frow;
            #pragma unroll
            for (int mr = 0; mr < 2; ++mr)
                #pragma unroll
                for (int r = 0; r < 4; ++r) {
                    int l = mr * 16 + fq * 4 + r;
                    float outv = 0.f;
                    if (l < nn) {
                        float v = (sane(c0[mr][nt][r] + bv[nt]) - mu[nt]) * rsg[nt] * lw[mr][r] + lb2[mr][r];
                        v = fmaxf(v, 0.f);
                        float rr = (float)sHX[l * SHP + colf];
                        outv = clamp256(v + rr);
                    }
                    yout[((size_t)g * 32 + l) * 256 + colf] = __float2bfloat16(outv);
                }
        }
    }
}

// ---- fused weight prep ----
struct CvtSegs { const float* in[7]; bf* out[7]; int n[7]; };
__global__ void prep_cvt(CvtSegs s, int total)
{
    int idx = blockIdx.x * 256 + threadIdx.x;
    if (idx >= total) return;
    #pragma unroll
    for (int i = 0; i < 7; ++i) {
        if (idx < s.n[i]) { s.out[i][idx] = __float2bfloat16(s.in[i][idx]); return; }
        idx -= s.n[i];
    }
}
// taps, optionally swizzled for gemm_tcn's global_load_lds path
struct TapSegs { const float* w[3]; bf* o[3]; int cc[3]; int kk[3]; int swz[3]; };
__global__ void prep_taps3(TapSegs s, int total)
{
    int idx = blockIdx.x * 256 + threadIdx.x;
    if (idx >= total) return;
    #pragma unroll
    for (int i = 0; i < 3; ++i) {
        if (idx < s.cc[i]) {
            unsigned K = (unsigned)s.kk[i];
            unsigned co = (unsigned)idx / K, ci = (unsigned)idx % K;
            int dst = co * K + (s.swz[i] ? swzk(ci, co) : ci);
            #pragma unroll
            for (int k = 0; k < 3; ++k)
                s.o[i][(size_t)k * s.cc[i] + dst] = __float2bfloat16(s.w[i][(size_t)idx * 3 + k]);
            return;
        }
        idx -= s.cc[i];
    }
}
// downsample weights, optionally swizzled
__global__ void prep_wswz(const float* __restrict__ w, bf* __restrict__ o,
                          int total, int K, int swz)
{
    int idx = blockIdx.x * 256 + threadIdx.x;
    if (idx >= total) return;
    int co = idx / K, ci = idx % K;
    o[(size_t)co * K + (swz ? swzk(ci, co) : ci)] = __float2bfloat16(w[idx]);
}
// conv0 weights -> MFMA-fragment-contiguous layout (coalesced 1KB wave loads)
__global__ void prep_bfrag(const float* __restrict__ w, bf* __restrict__ o, int HC)
{
    int idx = blockIdx.x * 256 + threadIdx.x;
    if (idx >= HC * HC) return;
    int co = idx / HC, ci = idx % HC;
    int cg = co >> 4, fr = co & 15, kc = ci >> 5, fq = (ci >> 3) & 3, w8 = ci & 7;
    int NCg = HC >> 4, NKc = HC >> 5;
    #pragma unroll
    for (int t = 0; t < 3; ++t) {
        size_t dst = (((((size_t)t * NCg + cg) * NKc + kc) * 16 + fr) * 4 + fq) * 8 + w8;
        o[dst] = __float2bfloat16(w[(size_t)idx * 3 + t]);
    }
}
// GAT Wl/Wr [HC][FI] f32 -> MFMA-fragment layout [2][cg][kc][16][4][8] bf16
__global__ void prep_gwfrag(const float* __restrict__ wl, const float* __restrict__ wr,
                            bf* __restrict__ o, int HC, int FI)
{
    int idx = blockIdx.x * 256 + threadIdx.x;
    int tot = HC * FI;
    if (idx >= 2 * tot) return;
    const float* w = (idx < tot) ? wl : wr;
    int j = (idx < tot) ? idx : idx - tot;
    int col = j / FI, k = j % FI;
    int cg = col >> 4, fr = col & 15, kc = k >> 5, fq = (k >> 3) & 3, w8 = k & 7;
    size_t dst = (size_t)((idx < tot) ? 0 : 1) * tot +
        ((((size_t)(cg * (FI >> 5) + kc) * 16 + fr) * 4 + fq) * 8 + w8);
    o[dst] = __float2bfloat16(w[j]);
}

// fc1_w f32 [F1][ci*nn+l] -> bf16 W1t [F1][l*HC+ci], l padded to 32
__global__ void prep_fc1(const float* __restrict__ w, bf* __restrict__ o, int F1, int nn, int HC)
{
    int idx = blockIdx.x * 256 + threadIdx.x;
    int kw = 32 * HC;
    if (idx >= F1 * kw) return;
    int co = idx / kw, r = idx % kw, l = r / HC, ci = r % HC;
    float hv = 0.f;
    if (l < nn) hv = w[(size_t)co * (HC * nn) + ci * nn + l];
    o[idx] = __float2bfloat16(hv);
}

// fc1 split-K reduce: z1 = bf16(relu(sum_z partials + bias))
__global__ void fc1red(const bf* __restrict__ zp, const float* __restrict__ bias,
                       bf* __restrict__ o, int MN, int N, int S)
{
    int idx = blockIdx.x * 256 + threadIdx.x;
    if (idx >= MN) return;
    float s = 0.f;
    for (int z = 0; z < S; ++z) s += __bfloat162float(zp[(size_t)z * MN + idx]);
    o[idx] = __float2bfloat16(clamp256(fmaxf(s + bias[idx % N], 0.f)));
}

extern "C" void kernel_launch(void* const* d_in, const int* in_sizes, int n_in,
                              void* d_out, int out_size, void* d_ws, size_t ws_size,
                              hipStream_t stream)
{
    (void)n_in; (void)ws_size;
    const float* x   = (const float*)d_in[0];
    const float* Wl  = (const float*)d_in[1];  const float* bl  = (const float*)d_in[2];
    const float* Wr  = (const float*)d_in[3];  const float* br  = (const float*)d_in[4];
    const float* att = (const float*)d_in[5];  const float* gb  = (const float*)d_in[6];
    const float* t0w = (const float*)d_in[7];  const float* t0b = (const float*)d_in[8];
    const float* l0w = (const float*)d_in[9];  const float* l0b = (const float*)d_in[10];
    const float* t1w = (const float*)d_in[11]; const float* t1b = (const float*)d_in[12];
    const float* l1w = (const float*)d_in[13]; const float* l1b = (const float*)d_in[14];
    const float* d1w = (const float*)d_in[15]; const float* d1b = (const float*)d_in[16];
    const float* t2w = (const float*)d_in[17]; const float* t2b = (const float*)d_in[18];
    const float* l2w = (const float*)d_in[19]; const float* l2b = (const float*)d_in[20];
    const float* d2w = (const float*)d_in[21]; const float* d2b = (const float*)d_in[22];
    const float* f1w = (const float*)d_in[23]; const float* f1b = (const float*)d_in[24];
    const float* f2w = (const float*)d_in[25]; const float* f2b = (const float*)d_in[26];
    const float* f3w = (const float*)d_in[27]; const float* f3b = (const float*)d_in[28];
    const int*   ei  = (const int*)d_in[29];

    const int HC   = in_sizes[6];                        // 256
    const int F_IN = in_sizes[1] / (HC > 0 ? HC : 1);    // 64
    const int NN   = in_sizes[0] / (F_IN > 0 ? F_IN : 1);// 30720
    const int E0   = in_sizes[29] / 2;                   // 245760
    const int ET   = E0 + NN;                            // 276480
    int nn = in_sizes[9];  nn = nn < 1 ? 1 : (nn > 32 ? 32 : nn);  // 30
    const int NG   = NN / nn;                            // 1024
    const int EPG  = NG > 0 ? E0 / NG : 0;               // 240
    const int C1   = in_sizes[12];                       // 512
    const int C2   = in_sizes[18];                       // 256
    const int F1   = in_sizes[24];                       // 512
    const int F2   = in_sizes[26];                       // 256
    const int F3   = in_sizes[28];                       // 144
    const int NG2  = (NG + 1) / 2;

    float* dout   = (float*)d_out;
    float* dei    = dout + ((size_t)out_size - 2 * (size_t)ET);
    float* dalpha = dei - (size_t)ET * 4;

    // ---- path eligibility ----
    const bool fused0 = (HC == 256) && (F_IN == 64) && (nn >= 1) && (nn <= 32)
                        && (EPG + nn <= MAXNE) && ((NN % 64) == 0);
    const int  gcA = NG2, gcB = NG - NG2;
    const bool fastc = ((gcA * 32) % 256 == 0) && ((gcB * 32) % 256 == 0)
                       && (C1 % 64 == 0) && (C2 % 64 == 0)
                       && (HC % 32 == 0) && (C1 % 32 == 0);

    // ---- workspace map (42 MB) ----
    char* ws = (char*)d_ws;
    const size_t MB = 1ull << 20;
    bf*    xb   = (bf*)(ws);
    bf*    WkA  = (bf*)(ws + 4 * MB);
    bf*    WkB  = WkA + (size_t)3 * HC * HC;
    bf*    WkC  = WkB + (size_t)3 * C1 * HC;
    bf*    Wlb  = WkC + (size_t)3 * C2 * C1;
    bf*    Wrb  = Wlb + (size_t)HC * F_IN;
    bf*    f2wb = Wrb + (size_t)HC * F_IN;
    bf*    f3wb = f2wb + (size_t)F2 * F1;
    bf*    d1wb = f3wb + (size_t)F3 * F2;
    bf*    d2wb = d1wb + (size_t)C1 * HC;
    bf*    WkAf = d2wb + (size_t)C2 * C1;                // frag-layout conv0 weights
    bf*    WlrF = WkAf + (size_t)3 * HC * HC;            // frag-layout Wl/Wr (64KB)
    char*  S0   = ws + (size_t)(7.5 * MB);
    char*  S1   = ws + 25 * MB;

    bf*    xrb  = (bf*)S0;                               // fallback only
    bf*    hbuf = (bf*)S0;                               // fallback GAT output
    bf*    xlb  = (bf*)S1;                               // fallback only
    bf*    y0   = fused0 ? (bf*)S0 : (bf*)S1;
    bf*    y1c  = fused0 ? (bf*)S1 : (bf*)S0;
    char*  fcS  = fused0 ? S1 : S0;                      // FC staging region
    bf*    W1t  = (bf*)fcS;                              // 8.4 MB
    bf*    z1p  = (bf*)(fcS + (size_t)(8.5 * MB));       // 8 MB
    bf*    z1   = (bf*)(ws);                             // 1 MB (over dead xb)
    bf*    z2   = (bf*)(ws + 2 * MB);                    // 0.5 MB

    // ---- fused weight prep ----
    {
        CvtSegs cs;
        cs.in[0] = x;   cs.out[0] = xb;   cs.n[0] = NN * F_IN;
        cs.in[1] = Wl;  cs.out[1] = Wlb;  cs.n[1] = HC * F_IN;
        cs.in[2] = Wr;  cs.out[2] = Wrb;  cs.n[2] = HC * F_IN;
        cs.in[3] = f2w; cs.out[3] = f2wb; cs.n[3] = F2 * F1;
        cs.in[4] = f3w; cs.out[4] = f3wb; cs.n[4] = F3 * F2;
        cs.in[5] = nullptr; cs.out[5] = nullptr; cs.n[5] = 0;
        cs.in[6] = nullptr; cs.out[6] = nullptr; cs.n[6] = 0;
        int tot = 0; for (int i = 0; i < 5; ++i) tot += cs.n[i];
        prep_cvt<<<(tot + 255) / 256, 256, 0, stream>>>(cs, tot);
        TapSegs ts;
        ts.w[0] = t0w; ts.o[0] = WkA; ts.cc[0] = HC * HC; ts.kk[0] = HC; ts.swz[0] = 0;
        ts.w[1] = t1w; ts.o[1] = WkB; ts.cc[1] = C1 * HC; ts.kk[1] = HC; ts.swz[1] = fastc ? 1 : 0;
        ts.w[2] = t2w; ts.o[2] = WkC; ts.cc[2] = C2 * C1; ts.kk[2] = C1; ts.swz[2] = fastc ? 1 : 0;
        int tt = ts.cc[0] + ts.cc[1] + ts.cc[2];
        prep_taps3<<<(tt + 255) / 256, 256, 0, stream>>>(ts, tt);
        prep_wswz<<<(C1 * HC + 255) / 256, 256, 0, stream>>>(d1w, d1wb, C1 * HC, HC, fastc ? 1 : 0);
        prep_wswz<<<(C2 * C1 + 255) / 256, 256, 0, stream>>>(d2w, d2wb, C2 * C1, C1, fastc ? 1 : 0);
        if (fused0) {
            prep_bfrag<<<(HC * HC + 255) / 256, 256, 0, stream>>>(t0w, WkAf, HC);
            prep_gwfrag<<<(2 * HC * F_IN + 255) / 256, 256, 0, stream>>>(Wl, Wr, WlrF, HC, F_IN);
        }
    }

    // ---- GAT (+ input transforms + TCN block 0 when fused0) ----
    if (fused0) {
        gat_fused4<1><<<NG, 256, 0, stream>>>(ei, xb, nullptr, WlrF, bl, br,
                                              att, gb, WkAf, t0b, l0w, l0b,
                                              y0, dalpha, dei, E0, ET, EPG, nn);
    } else {
        gemm_tf<1, true><<<dim3((HC + 63) / 64, (NN + 63) / 64), 256, 0, stream>>>(
            xb, Wlb, Wrb, bl, br, nullptr, nullptr, (const bf*)xrb, HC,
            xlb, nullptr, HC, NN, HC, F_IN, 1, 5, 0, 0, nn, F_IN);
        gat_fused4<0><<<NG, 256, 0, stream>>>(ei, xlb, xrb, nullptr, nullptr, nullptr,
                                              att, gb, nullptr, nullptr, nullptr, nullptr,
                                              hbuf, dalpha, dei, E0, ET, EPG, nn);
        gemm_tf<3, false><<<dim3((HC + 63) / 64, NG * 32 / 64), 256, 0, stream>>>(
            hbuf, WkA, nullptr, t0b, nullptr, l0w, l0b, hbuf, HC,
            y0, nullptr, HC, NG * 32, HC, HC, 1, 2, 0, 1, nn, HC);
    }

    // ---- TCN blocks 1 & 2, two graph-chunks ----
    for (int c = 0; c < 2; ++c) {
        int g0 = c * NG2;
        int gc = (c == 0) ? NG2 : (NG - NG2);
        if (gc <= 0) continue;
        const bf* y0c = y0 + (size_t)g0 * 32 * HC;
        bf*       y2c = y0 + (size_t)g0 * 32 * HC;
        if (fastc) {
            gemm_tcn<3, true, 4><<<dim3(C1 / 64, gc * 32 / 256), 256, 0, stream>>>(
                y0c, WkB, d1wb, t1b, d1b, l1w, l1b, nullptr, 0,
                y1c, C1, gc * 32, C1, HC, 2, nn);
            gemm_tcn<3, true, 2><<<dim3(C2 / 64, gc * 32 / 128), 256, 0, stream>>>(
                y1c, WkC, d2wb, t2b, d2b, l2w, l2b, nullptr, 0,
                y2c, C2, gc * 32, C2, C1, 4, nn);
        } else {
            gemm_tf<3, true><<<dim3((C1 + 63) / 64, gc * 32 / 64), 256, 0, stream>>>(
                y0c, WkB, d1wb, t1b, d1b, l1w, l1b, nullptr, 0,
                y1c, nullptr, C1, gc * 32, C1, HC, 2, 2, 0, 1, nn, HC);
            gemm_tf<3, true><<<dim3((C2 + 63) / 64, gc * 32 / 64), 256, 0, stream>>>(
                y1c, WkC, d2wb, t2b, d2b, l2w, l2b, nullptr, 0,
                y2c, nullptr, C2, gc * 32, C2, C1, 4, 2, 0, 1, nn, C1);
        }
    }

    // ---- FC head ----
    prep_fc1<<<(F1 * 32 * HC + 255) / 256, 256, 0, stream>>>(f1w, W1t, F1, nn, HC);
    gemm_tf<1, false><<<dim3((F1 + 63) / 64, (NG + 63) / 64, 8), 256, 0, stream>>>(
        y0, W1t, nullptr, nullptr, nullptr, nullptr, nullptr, nullptr, 0,
        z1p, nullptr, F1, NG, F1, 32 * HC, 1, 3, 0, 0, nn, 4 * HC);
    fc1red<<<(NG * F1 + 255) / 256, 256, 0, stream>>>(z1p, f1b, z1, NG * F1, F1, 8);

    gemm_tf<1, false><<<dim3((F2 + 63) / 64, (NG + 63) / 64), 256, 0, stream>>>(
        z1, f2wb, nullptr, f2b, nullptr, nullptr, nullptr, nullptr, 0,
        z2, nullptr, F2, NG, F2, F1, 1, 0, 1, 0, nn, F1);
    gemm_tf<1, false><<<dim3((F3 + 63) / 64, (NG + 63) / 64), 256, 0, stream>>>(
        z2, f3wb, nullptr, f3b, nullptr, nullptr, nullptr, nullptr, 0,
        nullptr, dout, F3, NG, F3, F2, 1, 0, 0, 0, nn, F2);
}